// Round 7
// baseline (124.851 us; speedup 1.0000x reference)
//
#include <hip/hip_runtime.h>
#include <hip/hip_bf16.h>
#include <math.h>
#include <stdint.h>

// Problem constants: B=4, C=512, T=2048, H=8, dh=64, G=32
#define Bb 4
#define Cc 512
#define Tt 2048
#define Hh 8

typedef __attribute__((ext_vector_type(8))) short short8;   // 8 bf16 (4 VGPR) MFMA operand
typedef __attribute__((ext_vector_type(4))) float f32x4;    // MFMA accumulator
typedef __attribute__((ext_vector_type(8))) unsigned short u16x8;

__device__ __forceinline__ unsigned short f2bf(float f) {
  __hip_bfloat16 h = __float2bfloat16(f);
  unsigned short u;
  __builtin_memcpy(&u, &h, 2);
  return u;
}
__device__ __forceinline__ float bf2f(unsigned short u) {
  union { uint32_t i; float f; } v;
  v.i = (uint32_t)u << 16;
  return v.f;
}

__device__ __forceinline__ void async16(const void* g, void* l) {
  __builtin_amdgcn_global_load_lds(
      (const __attribute__((address_space(1))) uint32_t*)g,
      (__attribute__((address_space(3))) uint32_t*)l, 16, 0, 0);
}

// ---------------------------------------------------------------------------
// K1a: partial sums for GroupNorm stats. 1024 blocks; block = 4096 floats.
// ---------------------------------------------------------------------------
__global__ __launch_bounds__(256) void gn_part(const float* __restrict__ x,
                                               float* __restrict__ part) {
  const int blk = blockIdx.x;
  const size_t base = (size_t)blk * 4096;
  const int tid = threadIdx.x;
  float s = 0.f, ss = 0.f;
#pragma unroll
  for (int k = 0; k < 4; ++k) {
    const float4 v = *(const float4*)(x + base + (size_t)(k * 256 + tid) * 4);
    s += v.x + v.y + v.z + v.w;
    ss += v.x * v.x + v.y * v.y + v.z * v.z + v.w * v.w;
  }
#pragma unroll
  for (int off = 32; off >= 1; off >>= 1) {
    s += __shfl_down(s, off);
    ss += __shfl_down(ss, off);
  }
  __shared__ float rs[4], rss[4];
  const int wid = tid >> 6;
  if ((tid & 63) == 0) { rs[wid] = s; rss[wid] = ss; }
  __syncthreads();
  if (tid == 0) {
    part[blk * 2] = rs[0] + rs[1] + rs[2] + rs[3];
    part[blk * 2 + 1] = rss[0] + rss[1] + rss[2] + rss[3];
  }
}

// K1b: finalize per-group mean/rstd (128 groups, 8 partials each).
__global__ __launch_bounds__(128) void gn_fin(const float* __restrict__ part,
                                              float* __restrict__ stats) {
  const int g = threadIdx.x;  // 0..127
  float s = 0.f, ss = 0.f;
#pragma unroll
  for (int c = 0; c < 8; ++c) {
    s += part[(g * 8 + c) * 2];
    ss += part[(g * 8 + c) * 2 + 1];
  }
  const float mean = s / 32768.f;
  const float var = ss / 32768.f - mean * mean;
  stats[g * 2] = mean;
  stats[g * 2 + 1] = rsqrtf(var + 1e-5f);
}

// ---------------------------------------------------------------------------
// K2: normalize + convert + transpose: x fp32 [b][c][t] -> hT bf16 [b][t][c].
// ---------------------------------------------------------------------------
__global__ __launch_bounds__(256) void norm_trans(const float* __restrict__ x,
                                                  const float* __restrict__ stats,
                                                  const float* __restrict__ gamma,
                                                  const float* __restrict__ beta,
                                                  unsigned short* __restrict__ hT) {
  __shared__ unsigned short Tl[64][72];
  const int tid = threadIdx.x;
  const int b = blockIdx.z, c0 = blockIdx.y * 64, t0 = blockIdx.x * 64;
  const int cl = tid >> 2, j16 = (tid & 3) * 16;
  const int c = c0 + cl;
  const int grp = c >> 4;
  const float mean = stats[((size_t)b * 32 + grp) * 2];
  const float rstd = stats[((size_t)b * 32 + grp) * 2 + 1];
  const float ga = gamma[c] * rstd;
  const float be = beta[c] - mean * ga;
  const float* src = x + ((size_t)b * Cc + c) * Tt + t0 + j16;
#pragma unroll
  for (int q = 0; q < 4; ++q) {
    const float4 v = *(const float4*)(src + q * 4);
    Tl[j16 + q * 4 + 0][cl] = f2bf(v.x * ga + be);
    Tl[j16 + q * 4 + 1][cl] = f2bf(v.y * ga + be);
    Tl[j16 + q * 4 + 2][cl] = f2bf(v.z * ga + be);
    Tl[j16 + q * 4 + 3][cl] = f2bf(v.w * ga + be);
  }
  __syncthreads();
  const int tl = tid >> 2, i16 = (tid & 3) * 16;
  unsigned short* dst = hT + ((size_t)b * Tt + t0 + tl) * Cc + c0 + i16;
  *(u16x8*)dst = *(const u16x8*)&Tl[tl][i16];
  *(u16x8*)(dst + 8) = *(const u16x8*)&Tl[tl][i16 + 8];
}

// ---------------------------------------------------------------------------
// K3: fp32 -> bf16 convert, both weight tensors in one launch.
// ---------------------------------------------------------------------------
__global__ __launch_bounds__(256) void cvt_bf16_2(const float* __restrict__ a,
                                                  unsigned short* __restrict__ oa, int n4a,
                                                  const float* __restrict__ bsrc,
                                                  unsigned short* __restrict__ ob, int n4b) {
  const int i = blockIdx.x * 256 + threadIdx.x;
  const float* in;
  unsigned short* out;
  int idx;
  if (i < n4a) {
    in = a; out = oa; idx = i;
  } else if (i < n4a + n4b) {
    in = bsrc; out = ob; idx = i - n4a;
  } else {
    return;
  }
  const float4 v = *(const float4*)(in + (size_t)idx * 4);
  ushort4 o;
  o.x = f2bf(v.x); o.y = f2bf(v.y); o.z = f2bf(v.z); o.w = f2bf(v.w);
  *(ushort4*)(out + (size_t)idx * 4) = o;
}

// ---------------------------------------------------------------------------
// K5: bf16 MFMA GEMM (m97 structure), BM x 128 tile, BK=32, 4 waves.
// MODE 0 (QKV): V rows -> channel-major bf16 qkvc; Q/K rows -> token-major
//   qkt via per-wave LDS transpose (Q pre-scaled by 0.125*log2e).
// MODE 1 (proj): fp32 out + residual.
// ---------------------------------------------------------------------------
template <int MODE, int BM>
__global__ __launch_bounds__(256) void gemm_mfma(const unsigned short* __restrict__ A,
                                                 const unsigned short* __restrict__ Bt,
                                                 const float* __restrict__ bias,
                                                 const float* __restrict__ res,
                                                 unsigned short* __restrict__ outb,
                                                 float* __restrict__ outf,
                                                 unsigned short* __restrict__ qkt,
                                                 int M) {
  constexpr int NA = BM / 32;  // A-frags per wave
  __shared__ unsigned short Al[BM * 32];
  __shared__ unsigned short Bl[128 * 32];
  __shared__ unsigned short Sc[(MODE == 0 ? 4 : 1)][32][72];  // transpose scratch
  const int tid = threadIdx.x;
  const int n0 = blockIdx.x * 128, m0 = blockIdx.y * BM;
  const size_t z = blockIdx.z;
  const int l = tid & 63, il = l & 15, g = l >> 4;
  const int w = tid >> 6;
  const int wm = (w >> 1) * (BM / 2), wn = (w & 1) * 64;

  const unsigned short* Bz = Bt + z * (size_t)Tt * Cc;
  const unsigned short* Ap = A + (size_t)(m0 + (tid >> 2)) * Cc + (tid & 3) * 8;
  const unsigned short* Bp = Bz + (size_t)(n0 + (tid >> 2)) * Cc + (tid & 3) * 8;
  char* ldsA = (char*)Al + w * 1024;
  char* ldsB = (char*)Bl + w * 1024;

  f32x4 acc[NA][4] = {};
  for (int k0 = 0; k0 < Cc; k0 += 32) {
    async16(Ap + k0, ldsA);
    if (BM == 128) async16(Ap + (size_t)64 * Cc + k0, ldsA + 4096);
    async16(Bp + k0, ldsB);
    async16(Bp + (size_t)64 * Cc + k0, ldsB + 4096);
    __syncthreads();
    short8 af[NA], bf[4];
#pragma unroll
    for (int i = 0; i < NA; ++i)
      af[i] = *(const short8*)(Al + (wm + i * 16 + il) * 32 + g * 8);
#pragma unroll
    for (int j = 0; j < 4; ++j)
      bf[j] = *(const short8*)(Bl + (wn + j * 16 + il) * 32 + g * 8);
    __builtin_amdgcn_s_setprio(1);
#pragma unroll
    for (int i = 0; i < NA; ++i)
#pragma unroll
      for (int j = 0; j < 4; ++j)
        acc[i][j] = __builtin_amdgcn_mfma_f32_16x16x32_bf16(af[i], bf[j], acc[i][j], 0, 0, 0);
    __builtin_amdgcn_s_setprio(0);
    __syncthreads();
  }

  if (MODE == 1) {
#pragma unroll
    for (int i = 0; i < NA; ++i) {
#pragma unroll
      for (int r = 0; r < 4; ++r) {
        const int m = m0 + wm + i * 16 + 4 * g + r;
        const float bv = bias[m];
#pragma unroll
        for (int j = 0; j < 4; ++j) {
          const int n = n0 + wn + j * 16 + il;
          const size_t idx = (z * (size_t)M + m) * Tt + n;
          outf[idx] = acc[i][j][r] + bv + res[idx];
        }
      }
    }
  } else {
    const int r0 = m0 + wm;
    const int sec = (r0 % 192) >> 6;  // 0=Q, 1=K, 2=V
    const int hh = r0 / 192;
    if (sec == 2) {
#pragma unroll
      for (int i = 0; i < 4; ++i) {
#pragma unroll
        for (int r = 0; r < 4; ++r) {
          const int m = r0 + i * 16 + 4 * g + r;
          const float bv = bias[m];
#pragma unroll
          for (int j = 0; j < 4; ++j) {
            const int n = n0 + wn + j * 16 + il;
            outb[(z * (size_t)M + m) * Tt + n] = f2bf(acc[i][j][r] + bv);
          }
        }
      }
    } else {
      const float qs = (sec == 0) ? 0.125f * 1.44269504f : 1.0f;
      const size_t obase = ((size_t)(z * (Hh * 2)) + hh * 2 + sec) * Tt;
#pragma unroll
      for (int hf = 0; hf < 2; ++hf) {
#pragma unroll
        for (int i = 0; i < 4; ++i) {
          const int mloc = i * 16 + 4 * g;
          const float b0 = bias[r0 + mloc + 0];
          const float b1 = bias[r0 + mloc + 1];
          const float b2 = bias[r0 + mloc + 2];
          const float b3 = bias[r0 + mloc + 3];
#pragma unroll
          for (int j2 = 0; j2 < 2; ++j2) {
            const int j = hf * 2 + j2;
            ushort4 pkk;
            pkk.x = f2bf((acc[i][j][0] + b0) * qs);
            pkk.y = f2bf((acc[i][j][1] + b1) * qs);
            pkk.z = f2bf((acc[i][j][2] + b2) * qs);
            pkk.w = f2bf((acc[i][j][3] + b3) * qs);
            *(ushort4*)&Sc[w][j2 * 16 + il][mloc] = pkk;
          }
        }
        asm volatile("s_waitcnt lgkmcnt(0)" ::: "memory");
#pragma unroll
        for (int it = 0; it < 4; ++it) {
          const int row = it * 8 + (l >> 3);
          const int mcol = (l & 7) * 8;
          const u16x8 vv = *(const u16x8*)&Sc[w][row][mcol];
          const int tg = n0 + wn + hf * 32 + row;
          *(u16x8*)(qkt + (obase + tg) * 64 + mcol) = vv;
        }
        asm volatile("s_waitcnt lgkmcnt(0)" ::: "memory");
      }
    }
  }
}

// ---------------------------------------------------------------------------
// K6: MFMA flash attention v6 — 3-buffer counted-vmcnt pipeline (T3+T4).
// stage(t+2) issued 2 iters ahead; raw s_barrier + explicit vmcnt(4) (never 0
// in steady state) so prefetch loads stay in flight across barriers.
// Per iter: [B1: vmcnt(4)+bar] -> {QK(t) ; PV(t-1)} MFMA region ->
// [B2: bar] -> stage(t+2) -> softmax(t).
// ---------------------------------------------------------------------------
__global__ __launch_bounds__(256) void attn_mfma6(const unsigned short* __restrict__ qkt,
                                                  const unsigned short* __restrict__ qkvc,
                                                  unsigned short* __restrict__ attnoT) {
  __shared__ unsigned short KVs[3][2][64 * 64];  // [buf][K/V][row*64+col], 48 KB

  const int tid = threadIdx.x;
  const int w = tid >> 6, l = tid & 63, il = l & 15, g = l >> 4;

  const int bid = blockIdx.x;
  const int swz = (bid & 7) * 128 + (bid >> 3);
  const int bh = swz >> 5, qt = swz & 31;
  const int b = bh >> 3, h = bh & 7;
  const int q0 = qt * 64;

  const unsigned short* Qb = qkt + (size_t)(bh * 2) * Tt * 64;
  const char* Kb = (const char*)(Qb + (size_t)Tt * 64);
  const char* Vb = (const char*)(qkvc + ((size_t)b * (3 * Cc) + h * 192 + 128) * Tt);

  short8 qf[2];
  {
    const unsigned short* qp = Qb + (size_t)(q0 + w * 16 + il) * 64 + g * 8;
    qf[0] = *(const short8*)qp;
    qf[1] = *(const short8*)(qp + 32);
  }

  union { uint32_t u[4]; short8 v; } ones;
  ones.u[0] = ones.u[1] = ones.u[2] = ones.u[3] = 0x3F803F80u;

  float m_run = 0.f;       // wave-uniform, log2 domain
  f32x4 acco[4] = {};      // O[q=4g+r][d=j*16+il]
  f32x4 acc_l = {};        // l[q=4g+r]
  uint32_t frP[2][4];      // P(t) as PV A-fragments (carried)

  const int srow = w * 16 + (l >> 3);
  const int scol = ((l & 7) ^ (l >> 3)) << 4;

  auto stage = [&](int buf, int s0) {
    char* kd = (char*)&KVs[buf][0][0] + w * 2048;
    char* vd = (char*)&KVs[buf][1][0] + w * 2048;
    async16(Kb + (size_t)(s0 + srow) * 128 + scol, kd);
    async16(Kb + (size_t)(s0 + srow + 8) * 128 + scol, kd + 1024);
    async16(Vb + (size_t)srow * (Tt * 2) + (size_t)s0 * 2 + scol, vd);
    async16(Vb + (size_t)(srow + 8) * (Tt * 2) + (size_t)s0 * 2 + scol, vd + 1024);
  };

  f32x4 accs[4];
  auto qk_phase = [&](int buf) {
    const float nm = -m_run;
#pragma unroll
    for (int i = 0; i < 4; ++i) {
      accs[i][0] = nm; accs[i][1] = nm; accs[i][2] = nm; accs[i][3] = nm;
    }
    const unsigned short* Kc = &KVs[buf][0][0];
#pragma unroll
    for (int ks = 0; ks < 2; ++ks) {
#pragma unroll
      for (int i = 0; i < 4; ++i) {
        const short8 kf =
            *(const short8*)(Kc + (i * 16 + il) * 64 + ((((ks << 2) + g) ^ (il & 7)) << 3));
        accs[i] = __builtin_amdgcn_mfma_f32_16x16x32_bf16(kf, qf[ks], accs[i], 0, 0, 0);
      }
    }
  };

  auto pv_phase = [&](int buf) {
    const unsigned short* Vc = &KVs[buf][1][0];
#pragma unroll
    for (int ks = 0; ks < 2; ++ks) {
      union { uint32_t u[4]; short8 v; } fu;
      fu.u[0] = frP[ks][0]; fu.u[1] = frP[ks][1];
      fu.u[2] = frP[ks][2]; fu.u[3] = frP[ks][3];
#pragma unroll
      for (int j = 0; j < 4; ++j) {
        const short8 vf =
            *(const short8*)(Vc + (j * 16 + il) * 64 + ((((ks << 2) + g) ^ (il & 7)) << 3));
        acco[j] = __builtin_amdgcn_mfma_f32_16x16x32_bf16(fu.v, vf, acco[j], 0, 0, 0);
      }
      acc_l = __builtin_amdgcn_mfma_f32_16x16x32_bf16(fu.v, ones.v, acc_l, 0, 0, 0);
    }
  };

  auto softmax_pack = [&]() {
    float pmax = fmaxf(fmaxf(fmaxf(accs[0][0], accs[0][1]), accs[0][2]), accs[0][3]);
    pmax = fmaxf(pmax, fmaxf(fmaxf(accs[1][0], accs[1][1]), fmaxf(accs[1][2], accs[1][3])));
    pmax = fmaxf(pmax, fmaxf(fmaxf(accs[2][0], accs[2][1]), fmaxf(accs[2][2], accs[2][3])));
    pmax = fmaxf(pmax, fmaxf(fmaxf(accs[3][0], accs[3][1]), fmaxf(accs[3][2], accs[3][3])));

    uint32_t pk[4][2];
    if (!__all(pmax <= 8.0f)) {
      float mx = pmax;
#pragma unroll
      for (int off = 1; off < 64; off <<= 1) mx = fmaxf(mx, __shfl_xor(mx, off));
      const float alpha = __builtin_amdgcn_exp2f(-mx);
      m_run += mx;
#pragma unroll
      for (int j = 0; j < 4; ++j) acco[j] = acco[j] * alpha;
      acc_l = acc_l * alpha;
#pragma unroll
      for (int i = 0; i < 4; ++i) {
        const float p0 = __builtin_amdgcn_exp2f(accs[i][0] - mx);
        const float p1 = __builtin_amdgcn_exp2f(accs[i][1] - mx);
        const float p2 = __builtin_amdgcn_exp2f(accs[i][2] - mx);
        const float p3 = __builtin_amdgcn_exp2f(accs[i][3] - mx);
        asm("v_cvt_pk_bf16_f32 %0, %1, %2" : "=v"(pk[i][0]) : "v"(p0), "v"(p1));
        asm("v_cvt_pk_bf16_f32 %0, %1, %2" : "=v"(pk[i][1]) : "v"(p2), "v"(p3));
      }
    } else {
#pragma unroll
      for (int i = 0; i < 4; ++i) {
        const float p0 = __builtin_amdgcn_exp2f(accs[i][0]);
        const float p1 = __builtin_amdgcn_exp2f(accs[i][1]);
        const float p2 = __builtin_amdgcn_exp2f(accs[i][2]);
        const float p3 = __builtin_amdgcn_exp2f(accs[i][3]);
        asm("v_cvt_pk_bf16_f32 %0, %1, %2" : "=v"(pk[i][0]) : "v"(p0), "v"(p1));
        asm("v_cvt_pk_bf16_f32 %0, %1, %2" : "=v"(pk[i][1]) : "v"(p2), "v"(p3));
      }
    }
#pragma unroll
    for (int ks = 0; ks < 2; ++ks) {
#pragma unroll
      for (int hh = 0; hh < 2; ++hh) {
        uint32_t a = pk[2 * ks][hh], bq = pk[2 * ks + 1][hh];
        asm("v_permlane32_swap_b32 %0, %1" : "+v"(a), "+v"(bq));
        asm("v_permlane16_swap_b32 %0, %1" : "+v"(a), "+v"(bq));
        frP[ks][hh] = a;
        frP[ks][2 + hh] = bq;
      }
    }
  };

  // ---- prologue
  stage(0, 0);
  stage(1, 64);
  asm volatile("s_waitcnt vmcnt(4)" ::: "memory");  // tile0 landed
  __builtin_amdgcn_s_barrier();
  __builtin_amdgcn_sched_barrier(0);
  stage(2, 128);  // buf2 untouched; fills while we compute tile0
  __builtin_amdgcn_s_setprio(1);
  qk_phase(0);
  __builtin_amdgcn_s_setprio(0);
  softmax_pack();  // P(0) -> frP
  asm volatile("s_waitcnt vmcnt(4)" ::: "memory");  // tile1 landed
  __builtin_amdgcn_s_barrier();
  __builtin_amdgcn_sched_barrier(0);

  const int NT = Tt / 64;
  for (int t = 1; t < NT; ++t) {
    const int cb = t % 3, pb = (t + 2) % 3;  // pb == (t-1)%3
    __builtin_amdgcn_s_setprio(1);
    qk_phase(cb);   // QK(t)
    pv_phase(pb);   // PV(t-1) — independent, fills MFMA pipe
    __builtin_amdgcn_s_setprio(0);
    __builtin_amdgcn_s_barrier();  // B2: all waves done reading buf[pb]
    __builtin_amdgcn_sched_barrier(0);
    if (t + 2 < NT) stage(pb, (t + 2) * 64);
    softmax_pack();  // P(t) -> frP
    if (t + 1 < NT) {
      if (t + 2 < NT) {
        asm volatile("s_waitcnt vmcnt(4)" ::: "memory");  // tile t+1 landed
      } else {
        asm volatile("s_waitcnt vmcnt(0)" ::: "memory");  // no newer stage
      }
      __builtin_amdgcn_s_barrier();  // B1 for iter t+1
      __builtin_amdgcn_sched_barrier(0);
    }
  }
  __builtin_amdgcn_s_setprio(1);
  pv_phase((NT - 1) % 3);
  __builtin_amdgcn_s_setprio(0);

  // epilogue
#pragma unroll
  for (int r = 0; r < 4; ++r) {
    const float li = 1.f / acc_l[r];
    const int tq = q0 + w * 16 + 4 * g + r;
    unsigned short* d0 = attnoT + ((size_t)b * Tt + tq) * Cc + h * 64 + il;
#pragma unroll
    for (int j = 0; j < 4; ++j) d0[j * 16] = f2bf(acco[j][r] * li);
  }
}

// ---------------------------------------------------------------------------
extern "C" void kernel_launch(void* const* d_in, const int* in_sizes, int n_in,
                              void* d_out, int out_size, void* d_ws, size_t ws_size,
                              hipStream_t stream) {
  const float* x = (const float*)d_in[0];
  const float* gamma = (const float*)d_in[1];
  const float* beta = (const float*)d_in[2];
  const float* w_qkv = (const float*)d_in[3];
  const float* b_qkv = (const float*)d_in[4];
  const float* w_proj = (const float*)d_in[5];
  const float* b_proj = (const float*)d_in[6];
  float* out = (float*)d_out;

  char* p = (char*)d_ws;
  float* stats = (float*)p;                  p += 256 * sizeof(float);
  float* part = (float*)p;                   p += 2048 * sizeof(float);
  unsigned short* hT = (unsigned short*)p;   p += (size_t)Bb * Tt * Cc * 2;
  unsigned short* wq = (unsigned short*)p;   p += (size_t)3 * Cc * Cc * 2;
  unsigned short* wp = (unsigned short*)p;   p += (size_t)Cc * Cc * 2;
  unsigned short* qkvc = (unsigned short*)p; p += (size_t)Bb * 3 * Cc * Tt * 2;
  unsigned short* qkt = (unsigned short*)p;  p += (size_t)Bb * Hh * 2 * Tt * 64 * 2;
  unsigned short* attnoT = (unsigned short*)p;

  const int n4q = 3 * Cc * Cc / 4, n4p = Cc * Cc / 4;

  gn_part<<<dim3(1024), 256, 0, stream>>>(x, part);
  gn_fin<<<dim3(1), 128, 0, stream>>>(part, stats);
  norm_trans<<<dim3(Tt / 64, Cc / 64, Bb), 256, 0, stream>>>(x, stats, gamma, beta, hT);
  cvt_bf16_2<<<dim3((n4q + n4p + 255) / 256), 256, 0, stream>>>(w_qkv, wq, n4q, w_proj, wp, n4p);
  gemm_mfma<0, 128><<<dim3(Tt / 128, (3 * Cc) / 128, Bb), 256, 0, stream>>>(
      wq, hT, b_qkv, nullptr, qkvc, nullptr, qkt, 3 * Cc);
  attn_mfma6<<<dim3(1024), 256, 0, stream>>>(qkt, qkvc, attnoT);
  gemm_mfma<1, 64><<<dim3(Tt / 128, Cc / 64, Bb), 256, 0, stream>>>(
      wp, attnoT, b_proj, x, nullptr, out, nullptr, Cc);
}

// Round 8
// 111.397 us; speedup vs baseline: 1.1208x; 1.1208x over previous
//
#include <hip/hip_runtime.h>
#include <hip/hip_bf16.h>
#include <math.h>
#include <stdint.h>

// Problem constants: B=4, C=512, T=2048, H=8, dh=64, G=32
#define Bb 4
#define Cc 512
#define Tt 2048
#define Hh 8

typedef __attribute__((ext_vector_type(8))) short short8;   // 8 bf16 (4 VGPR) MFMA operand
typedef __attribute__((ext_vector_type(4))) float f32x4;    // MFMA accumulator
typedef __attribute__((ext_vector_type(8))) unsigned short u16x8;

__device__ __forceinline__ unsigned short f2bf(float f) {
  __hip_bfloat16 h = __float2bfloat16(f);
  unsigned short u;
  __builtin_memcpy(&u, &h, 2);
  return u;
}
__device__ __forceinline__ float bf2f(unsigned short u) {
  union { uint32_t i; float f; } v;
  v.i = (uint32_t)u << 16;
  return v.f;
}

__device__ __forceinline__ void async16(const void* g, void* l) {
  __builtin_amdgcn_global_load_lds(
      (const __attribute__((address_space(1))) uint32_t*)g,
      (__attribute__((address_space(3))) uint32_t*)l, 16, 0, 0);
}

// ---------------------------------------------------------------------------
// K1a: partial sums for GroupNorm stats. 1024 blocks; block = 4096 floats.
// ---------------------------------------------------------------------------
__global__ __launch_bounds__(256) void gn_part(const float* __restrict__ x,
                                               float* __restrict__ part) {
  const int blk = blockIdx.x;
  const size_t base = (size_t)blk * 4096;
  const int tid = threadIdx.x;
  float s = 0.f, ss = 0.f;
#pragma unroll
  for (int k = 0; k < 4; ++k) {
    const float4 v = *(const float4*)(x + base + (size_t)(k * 256 + tid) * 4);
    s += v.x + v.y + v.z + v.w;
    ss += v.x * v.x + v.y * v.y + v.z * v.z + v.w * v.w;
  }
#pragma unroll
  for (int off = 32; off >= 1; off >>= 1) {
    s += __shfl_down(s, off);
    ss += __shfl_down(ss, off);
  }
  __shared__ float rs[4], rss[4];
  const int wid = tid >> 6;
  if ((tid & 63) == 0) { rs[wid] = s; rss[wid] = ss; }
  __syncthreads();
  if (tid == 0) {
    part[blk * 2] = rs[0] + rs[1] + rs[2] + rs[3];
    part[blk * 2 + 1] = rss[0] + rss[1] + rss[2] + rss[3];
  }
}

// K1b: finalize per-group mean/rstd (128 groups, 8 partials each).
__global__ __launch_bounds__(128) void gn_fin(const float* __restrict__ part,
                                              float* __restrict__ stats) {
  const int g = threadIdx.x;  // 0..127
  float s = 0.f, ss = 0.f;
#pragma unroll
  for (int c = 0; c < 8; ++c) {
    s += part[(g * 8 + c) * 2];
    ss += part[(g * 8 + c) * 2 + 1];
  }
  const float mean = s / 32768.f;
  const float var = ss / 32768.f - mean * mean;
  stats[g * 2] = mean;
  stats[g * 2 + 1] = rsqrtf(var + 1e-5f);
}

// ---------------------------------------------------------------------------
// K2: normalize + convert + transpose: x fp32 [b][c][t] -> hT bf16 [b][t][c].
// ---------------------------------------------------------------------------
__global__ __launch_bounds__(256) void norm_trans(const float* __restrict__ x,
                                                  const float* __restrict__ stats,
                                                  const float* __restrict__ gamma,
                                                  const float* __restrict__ beta,
                                                  unsigned short* __restrict__ hT) {
  __shared__ unsigned short Tl[64][72];
  const int tid = threadIdx.x;
  const int b = blockIdx.z, c0 = blockIdx.y * 64, t0 = blockIdx.x * 64;
  const int cl = tid >> 2, j16 = (tid & 3) * 16;
  const int c = c0 + cl;
  const int grp = c >> 4;
  const float mean = stats[((size_t)b * 32 + grp) * 2];
  const float rstd = stats[((size_t)b * 32 + grp) * 2 + 1];
  const float ga = gamma[c] * rstd;
  const float be = beta[c] - mean * ga;
  const float* src = x + ((size_t)b * Cc + c) * Tt + t0 + j16;
#pragma unroll
  for (int q = 0; q < 4; ++q) {
    const float4 v = *(const float4*)(src + q * 4);
    Tl[j16 + q * 4 + 0][cl] = f2bf(v.x * ga + be);
    Tl[j16 + q * 4 + 1][cl] = f2bf(v.y * ga + be);
    Tl[j16 + q * 4 + 2][cl] = f2bf(v.z * ga + be);
    Tl[j16 + q * 4 + 3][cl] = f2bf(v.w * ga + be);
  }
  __syncthreads();
  const int tl = tid >> 2, i16 = (tid & 3) * 16;
  unsigned short* dst = hT + ((size_t)b * Tt + t0 + tl) * Cc + c0 + i16;
  *(u16x8*)dst = *(const u16x8*)&Tl[tl][i16];
  *(u16x8*)(dst + 8) = *(const u16x8*)&Tl[tl][i16 + 8];
}

// ---------------------------------------------------------------------------
// K3: fp32 -> bf16 convert, both weight tensors in one launch.
// ---------------------------------------------------------------------------
__global__ __launch_bounds__(256) void cvt_bf16_2(const float* __restrict__ a,
                                                  unsigned short* __restrict__ oa, int n4a,
                                                  const float* __restrict__ bsrc,
                                                  unsigned short* __restrict__ ob, int n4b) {
  const int i = blockIdx.x * 256 + threadIdx.x;
  const float* in;
  unsigned short* out;
  int idx;
  if (i < n4a) {
    in = a; out = oa; idx = i;
  } else if (i < n4a + n4b) {
    in = bsrc; out = ob; idx = i - n4a;
  } else {
    return;
  }
  const float4 v = *(const float4*)(in + (size_t)idx * 4);
  ushort4 o;
  o.x = f2bf(v.x); o.y = f2bf(v.y); o.z = f2bf(v.z); o.w = f2bf(v.w);
  *(ushort4*)(out + (size_t)idx * 4) = o;
}

// ---------------------------------------------------------------------------
// K5: bf16 MFMA GEMM, BM x 128 tile, BK=64 (two 32-col chunks, m97 layout
// each), 4 waves. 8 barrier-pairs instead of 16; 32-MFMA bursts.
// MODE 0 (QKV): V rows -> channel-major bf16 qkvc; Q/K rows -> token-major
//   qkt via per-wave LDS transpose scratch ALIASED onto the dead staging
//   buffers (keeps LDS at 32KB). Q pre-scaled by 0.125*log2e.
// MODE 1 (proj): fp32 out + residual.
// ---------------------------------------------------------------------------
template <int MODE, int BM>
__global__ __launch_bounds__(256) void gemm_mfma(const unsigned short* __restrict__ A,
                                                 const unsigned short* __restrict__ Bt,
                                                 const float* __restrict__ bias,
                                                 const float* __restrict__ res,
                                                 unsigned short* __restrict__ outb,
                                                 float* __restrict__ outf,
                                                 unsigned short* __restrict__ qkt,
                                                 int M) {
  constexpr int NA = BM / 32;  // A-frags per wave
  __shared__ unsigned short SMEM[(BM + 128) * 64];  // Al | Bl (chunked by 32 cols)
  unsigned short* Al = SMEM;
  unsigned short* Bl = SMEM + BM * 64;
  const int tid = threadIdx.x;
  const int n0 = blockIdx.x * 128, m0 = blockIdx.y * BM;
  const size_t z = blockIdx.z;
  const int l = tid & 63, il = l & 15, g = l >> 4;
  const int w = tid >> 6;
  const int wm = (w >> 1) * (BM / 2), wn = (w & 1) * 64;

  const unsigned short* Bz = Bt + z * (size_t)Tt * Cc;
  const unsigned short* Ap = A + (size_t)(m0 + (tid >> 2)) * Cc + (tid & 3) * 8;
  const unsigned short* Bp = Bz + (size_t)(n0 + (tid >> 2)) * Cc + (tid & 3) * 8;
  char* ldsA = (char*)Al + w * 1024;
  char* ldsB = (char*)Bl + w * 1024;

  f32x4 acc[NA][4] = {};
  for (int k0 = 0; k0 < Cc; k0 += 64) {
#pragma unroll
    for (int ks = 0; ks < 2; ++ks) {
      const int ko = k0 + ks * 32;
      async16(Ap + ko, ldsA + ks * (BM * 64));
      if (BM == 128) async16(Ap + (size_t)64 * Cc + ko, ldsA + ks * (BM * 64) + 4096);
      async16(Bp + ko, ldsB + ks * (128 * 64));
      async16(Bp + (size_t)64 * Cc + ko, ldsB + ks * (128 * 64) + 4096);
    }
    __syncthreads();
    __builtin_amdgcn_s_setprio(1);
#pragma unroll
    for (int ks = 0; ks < 2; ++ks) {
      short8 af[NA], bf[4];
#pragma unroll
      for (int i = 0; i < NA; ++i)
        af[i] = *(const short8*)(Al + ks * (BM * 32) + (wm + i * 16 + il) * 32 + g * 8);
#pragma unroll
      for (int j = 0; j < 4; ++j)
        bf[j] = *(const short8*)(Bl + ks * (128 * 32) + (wn + j * 16 + il) * 32 + g * 8);
#pragma unroll
      for (int i = 0; i < NA; ++i)
#pragma unroll
        for (int j = 0; j < 4; ++j)
          acc[i][j] = __builtin_amdgcn_mfma_f32_16x16x32_bf16(af[i], bf[j], acc[i][j], 0, 0, 0);
    }
    __builtin_amdgcn_s_setprio(0);
    __syncthreads();
  }

  if (MODE == 1) {
#pragma unroll
    for (int i = 0; i < NA; ++i) {
#pragma unroll
      for (int r = 0; r < 4; ++r) {
        const int m = m0 + wm + i * 16 + 4 * g + r;
        const float bv = bias[m];
#pragma unroll
        for (int j = 0; j < 4; ++j) {
          const int n = n0 + wn + j * 16 + il;
          const size_t idx = (z * (size_t)M + m) * Tt + n;
          outf[idx] = acc[i][j][r] + bv + res[idx];
        }
      }
    }
  } else {
    const int r0 = m0 + wm;
    const int sec = (r0 % 192) >> 6;  // 0=Q, 1=K, 2=V
    const int hh = r0 / 192;
    if (sec == 2) {
#pragma unroll
      for (int i = 0; i < 4; ++i) {
#pragma unroll
        for (int r = 0; r < 4; ++r) {
          const int m = r0 + i * 16 + 4 * g + r;
          const float bv = bias[m];
#pragma unroll
          for (int j = 0; j < 4; ++j) {
            const int n = n0 + wn + j * 16 + il;
            outb[(z * (size_t)M + m) * Tt + n] = f2bf(acc[i][j][r] + bv);
          }
        }
      }
    } else {
      // Q/K: token-major via per-wave scratch aliased onto dead Al/Bl.
      // Safe: all staging loads + LDS reads drained by final __syncthreads;
      // per-wave regions disjoint; sync below is intra-wave lgkmcnt only.
      unsigned short (*Sc)[32][72] = (unsigned short(*)[32][72])SMEM;
      const float qs = (sec == 0) ? 0.125f * 1.44269504f : 1.0f;
      const size_t obase = ((size_t)(z * (Hh * 2)) + hh * 2 + sec) * Tt;
#pragma unroll
      for (int hf = 0; hf < 2; ++hf) {
#pragma unroll
        for (int i = 0; i < 4; ++i) {
          const int mloc = i * 16 + 4 * g;
          const float b0 = bias[r0 + mloc + 0];
          const float b1 = bias[r0 + mloc + 1];
          const float b2 = bias[r0 + mloc + 2];
          const float b3 = bias[r0 + mloc + 3];
#pragma unroll
          for (int j2 = 0; j2 < 2; ++j2) {
            const int j = hf * 2 + j2;
            ushort4 pkk;
            pkk.x = f2bf((acc[i][j][0] + b0) * qs);
            pkk.y = f2bf((acc[i][j][1] + b1) * qs);
            pkk.z = f2bf((acc[i][j][2] + b2) * qs);
            pkk.w = f2bf((acc[i][j][3] + b3) * qs);
            *(ushort4*)&Sc[w][j2 * 16 + il][mloc] = pkk;
          }
        }
        asm volatile("s_waitcnt lgkmcnt(0)" ::: "memory");
#pragma unroll
        for (int it = 0; it < 4; ++it) {
          const int row = it * 8 + (l >> 3);
          const int mcol = (l & 7) * 8;
          const u16x8 vv = *(const u16x8*)&Sc[w][row][mcol];
          const int tg = n0 + wn + hf * 32 + row;
          *(u16x8*)(qkt + (obase + tg) * 64 + mcol) = vv;
        }
        asm volatile("s_waitcnt lgkmcnt(0)" ::: "memory");
      }
    }
  }
}

// ---------------------------------------------------------------------------
// K6: MFMA flash attention v5 (measured-best structure, R6).
// Per iter: [B1 sync] -> {QK(t) ; PV(t-1)} one MFMA-dense region -> [B2 sync]
// -> stage(t+1) -> softmax(t). 4 waves, QBLK=64, KVBLK=64, 2-buffer
// global_load_lds w/ pre-swizzled source, in-register P via cvt_pk+permlane,
// wave-uniform defer-max (THR=8, log2), l via MFMA ones-trick.
// ---------------------------------------------------------------------------
__global__ __launch_bounds__(256, 4) void attn_mfma5(const unsigned short* __restrict__ qkt,
                                                     const unsigned short* __restrict__ qkvc,
                                                     unsigned short* __restrict__ attnoT) {
  __shared__ unsigned short KVs[2][2][64 * 64];  // [buf][K/V][row*64+col] swizzled

  const int tid = threadIdx.x;
  const int w = tid >> 6, l = tid & 63, il = l & 15, g = l >> 4;

  const int bid = blockIdx.x;
  const int swz = (bid & 7) * 128 + (bid >> 3);
  const int bh = swz >> 5, qt = swz & 31;
  const int b = bh >> 3, h = bh & 7;
  const int q0 = qt * 64;

  const unsigned short* Qb = qkt + (size_t)(bh * 2) * Tt * 64;
  const char* Kb = (const char*)(Qb + (size_t)Tt * 64);
  const char* Vb = (const char*)(qkvc + ((size_t)b * (3 * Cc) + h * 192 + 128) * Tt);

  short8 qf[2];
  {
    const unsigned short* qp = Qb + (size_t)(q0 + w * 16 + il) * 64 + g * 8;
    qf[0] = *(const short8*)qp;
    qf[1] = *(const short8*)(qp + 32);
  }

  union { uint32_t u[4]; short8 v; } ones;
  ones.u[0] = ones.u[1] = ones.u[2] = ones.u[3] = 0x3F803F80u;

  float m_run = 0.f;       // wave-uniform, log2 domain
  f32x4 acco[4] = {};      // O[q=4g+r][d=j*16+il]
  f32x4 acc_l = {};        // l[q=4g+r]
  uint32_t frP[2][4];      // P(t) as PV A-fragments (carried state)

  const int srow = w * 16 + (l >> 3);
  const int scol = ((l & 7) ^ (l >> 3)) << 4;

  auto stage = [&](int buf, int s0) {
    char* kd = (char*)&KVs[buf][0][0] + w * 2048;
    char* vd = (char*)&KVs[buf][1][0] + w * 2048;
    async16(Kb + (size_t)(s0 + srow) * 128 + scol, kd);
    async16(Kb + (size_t)(s0 + srow + 8) * 128 + scol, kd + 1024);
    async16(Vb + (size_t)srow * (Tt * 2) + (size_t)s0 * 2 + scol, vd);
    async16(Vb + (size_t)(srow + 8) * (Tt * 2) + (size_t)s0 * 2 + scol, vd + 1024);
  };

  f32x4 accs[4];
  auto qk_phase = [&](int buf) {
    const float nm = -m_run;
#pragma unroll
    for (int i = 0; i < 4; ++i) {
      accs[i][0] = nm; accs[i][1] = nm; accs[i][2] = nm; accs[i][3] = nm;
    }
    const unsigned short* Kc = &KVs[buf][0][0];
#pragma unroll
    for (int ks = 0; ks < 2; ++ks) {
#pragma unroll
      for (int i = 0; i < 4; ++i) {
        const short8 kf =
            *(const short8*)(Kc + (i * 16 + il) * 64 + ((((ks << 2) + g) ^ (il & 7)) << 3));
        accs[i] = __builtin_amdgcn_mfma_f32_16x16x32_bf16(kf, qf[ks], accs[i], 0, 0, 0);
      }
    }
  };

  auto pv_phase = [&](int buf) {
    const unsigned short* Vc = &KVs[buf][1][0];
#pragma unroll
    for (int ks = 0; ks < 2; ++ks) {
      union { uint32_t u[4]; short8 v; } fu;
      fu.u[0] = frP[ks][0]; fu.u[1] = frP[ks][1];
      fu.u[2] = frP[ks][2]; fu.u[3] = frP[ks][3];
#pragma unroll
      for (int j = 0; j < 4; ++j) {
        const short8 vf =
            *(const short8*)(Vc + (j * 16 + il) * 64 + ((((ks << 2) + g) ^ (il & 7)) << 3));
        acco[j] = __builtin_amdgcn_mfma_f32_16x16x32_bf16(fu.v, vf, acco[j], 0, 0, 0);
      }
      acc_l = __builtin_amdgcn_mfma_f32_16x16x32_bf16(fu.v, ones.v, acc_l, 0, 0, 0);
    }
  };

  auto softmax_pack = [&]() {
    float pmax = fmaxf(fmaxf(fmaxf(accs[0][0], accs[0][1]), accs[0][2]), accs[0][3]);
    pmax = fmaxf(pmax, fmaxf(fmaxf(accs[1][0], accs[1][1]), fmaxf(accs[1][2], accs[1][3])));
    pmax = fmaxf(pmax, fmaxf(fmaxf(accs[2][0], accs[2][1]), fmaxf(accs[2][2], accs[2][3])));
    pmax = fmaxf(pmax, fmaxf(fmaxf(accs[3][0], accs[3][1]), fmaxf(accs[3][2], accs[3][3])));

    uint32_t pk[4][2];
    if (!__all(pmax <= 8.0f)) {
      float mx = pmax;
#pragma unroll
      for (int off = 1; off < 64; off <<= 1) mx = fmaxf(mx, __shfl_xor(mx, off));
      const float alpha = __builtin_amdgcn_exp2f(-mx);
      m_run += mx;
#pragma unroll
      for (int j = 0; j < 4; ++j) acco[j] = acco[j] * alpha;
      acc_l = acc_l * alpha;
#pragma unroll
      for (int i = 0; i < 4; ++i) {
        const float p0 = __builtin_amdgcn_exp2f(accs[i][0] - mx);
        const float p1 = __builtin_amdgcn_exp2f(accs[i][1] - mx);
        const float p2 = __builtin_amdgcn_exp2f(accs[i][2] - mx);
        const float p3 = __builtin_amdgcn_exp2f(accs[i][3] - mx);
        asm("v_cvt_pk_bf16_f32 %0, %1, %2" : "=v"(pk[i][0]) : "v"(p0), "v"(p1));
        asm("v_cvt_pk_bf16_f32 %0, %1, %2" : "=v"(pk[i][1]) : "v"(p2), "v"(p3));
      }
    } else {
#pragma unroll
      for (int i = 0; i < 4; ++i) {
        const float p0 = __builtin_amdgcn_exp2f(accs[i][0]);
        const float p1 = __builtin_amdgcn_exp2f(accs[i][1]);
        const float p2 = __builtin_amdgcn_exp2f(accs[i][2]);
        const float p3 = __builtin_amdgcn_exp2f(accs[i][3]);
        asm("v_cvt_pk_bf16_f32 %0, %1, %2" : "=v"(pk[i][0]) : "v"(p0), "v"(p1));
        asm("v_cvt_pk_bf16_f32 %0, %1, %2" : "=v"(pk[i][1]) : "v"(p2), "v"(p3));
      }
    }
#pragma unroll
    for (int ks = 0; ks < 2; ++ks) {
#pragma unroll
      for (int hh = 0; hh < 2; ++hh) {
        uint32_t a = pk[2 * ks][hh], bq = pk[2 * ks + 1][hh];
        asm("v_permlane32_swap_b32 %0, %1" : "+v"(a), "+v"(bq));
        asm("v_permlane16_swap_b32 %0, %1" : "+v"(a), "+v"(bq));
        frP[ks][hh] = a;
        frP[ks][2 + hh] = bq;
      }
    }
  };

  // ---- prologue: tile 0
  stage(0, 0);
  __syncthreads();           // drain tile-0 loads
  stage(1, 64);              // tile 1 into b1 (no readers yet)
  __builtin_amdgcn_s_setprio(1);
  qk_phase(0);
  __builtin_amdgcn_s_setprio(0);
  softmax_pack();            // P(0) -> frP

  const int NT = Tt / 64;
  for (int t = 1; t < NT; ++t) {
    const int cb = t & 1, pb = cb ^ 1;
    __syncthreads();         // B1: drains stage(t); all waves past PV(t-2)
    __builtin_amdgcn_s_setprio(1);
    qk_phase(cb);            // QK(t)   (accs)
    pv_phase(pb);            // PV(t-1) (frP) — independent, fills MFMA pipe
    __builtin_amdgcn_s_setprio(0);
    __syncthreads();         // B2: all waves done reading b[pb]
    if (t + 1 < NT) stage(pb, (t + 1) * 64);
    softmax_pack();          // P(t) -> frP; covers stage latency
  }
  // final PV for tile NT-1 (buffer (NT-1)&1 = 1, still valid)
  __builtin_amdgcn_s_setprio(1);
  pv_phase(1);
  __builtin_amdgcn_s_setprio(0);

  // epilogue
#pragma unroll
  for (int r = 0; r < 4; ++r) {
    const float li = 1.f / acc_l[r];
    const int tq = q0 + w * 16 + 4 * g + r;
    unsigned short* d0 = attnoT + ((size_t)b * Tt + tq) * Cc + h * 64 + il;
#pragma unroll
    for (int j = 0; j < 4; ++j) d0[j * 16] = f2bf(acco[j][r] * li);
  }
}

// ---------------------------------------------------------------------------
extern "C" void kernel_launch(void* const* d_in, const int* in_sizes, int n_in,
                              void* d_out, int out_size, void* d_ws, size_t ws_size,
                              hipStream_t stream) {
  const float* x = (const float*)d_in[0];
  const float* gamma = (const float*)d_in[1];
  const float* beta = (const float*)d_in[2];
  const float* w_qkv = (const float*)d_in[3];
  const float* b_qkv = (const float*)d_in[4];
  const float* w_proj = (const float*)d_in[5];
  const float* b_proj = (const float*)d_in[6];
  float* out = (float*)d_out;

  char* p = (char*)d_ws;
  float* stats = (float*)p;                  p += 256 * sizeof(float);
  float* part = (float*)p;                   p += 2048 * sizeof(float);
  unsigned short* hT = (unsigned short*)p;   p += (size_t)Bb * Tt * Cc * 2;
  unsigned short* wq = (unsigned short*)p;   p += (size_t)3 * Cc * Cc * 2;
  unsigned short* wp = (unsigned short*)p;   p += (size_t)Cc * Cc * 2;
  unsigned short* qkvc = (unsigned short*)p; p += (size_t)Bb * 3 * Cc * Tt * 2;
  unsigned short* qkt = (unsigned short*)p;  p += (size_t)Bb * Hh * 2 * Tt * 64 * 2;
  unsigned short* attnoT = (unsigned short*)p;

  const int n4q = 3 * Cc * Cc / 4, n4p = Cc * Cc / 4;

  gn_part<<<dim3(1024), 256, 0, stream>>>(x, part);
  gn_fin<<<dim3(1), 128, 0, stream>>>(part, stats);
  norm_trans<<<dim3(Tt / 64, Cc / 64, Bb), 256, 0, stream>>>(x, stats, gamma, beta, hT);
  cvt_bf16_2<<<dim3((n4q + n4p + 255) / 256), 256, 0, stream>>>(w_qkv, wq, n4q, w_proj, wp, n4p);
  gemm_mfma<0, 128><<<dim3(Tt / 128, (3 * Cc) / 128, Bb), 256, 0, stream>>>(
      wq, hT, b_qkv, nullptr, qkvc, nullptr, qkt, 3 * Cc);
  attn_mfma5<<<dim3(1024), 256, 0, stream>>>(qkt, qkvc, attnoT);
  gemm_mfma<1, 64><<<dim3(Tt / 128, Cc / 64, Bb), 256, 0, stream>>>(
      wp, attnoT, b_proj, x, nullptr, out, nullptr, Cc);
}

// Round 9
// 109.377 us; speedup vs baseline: 1.1415x; 1.0185x over previous
//
#include <hip/hip_runtime.h>
#include <hip/hip_bf16.h>
#include <math.h>
#include <stdint.h>

// Problem constants: B=4, C=512, T=2048, H=8, dh=64, G=32
#define Bb 4
#define Cc 512
#define Tt 2048
#define Hh 8

typedef __attribute__((ext_vector_type(8))) short short8;   // 8 bf16 (4 VGPR) MFMA operand
typedef __attribute__((ext_vector_type(4))) float f32x4;    // MFMA accumulator
typedef __attribute__((ext_vector_type(8))) unsigned short u16x8;

__device__ __forceinline__ unsigned short f2bf(float f) {
  __hip_bfloat16 h = __float2bfloat16(f);
  unsigned short u;
  __builtin_memcpy(&u, &h, 2);
  return u;
}
__device__ __forceinline__ float bf2f(unsigned short u) {
  union { uint32_t i; float f; } v;
  v.i = (uint32_t)u << 16;
  return v.f;
}

__device__ __forceinline__ void async16(const void* g, void* l) {
  __builtin_amdgcn_global_load_lds(
      (const __attribute__((address_space(1))) uint32_t*)g,
      (__attribute__((address_space(3))) uint32_t*)l, 16, 0, 0);
}

// ---------------------------------------------------------------------------
// K1: partial sums for GroupNorm stats. 1024 blocks; block = 4096 floats
// (= 2 channels). part[blk] = {sum, sumsq}.
// ---------------------------------------------------------------------------
__global__ __launch_bounds__(256) void gn_part(const float* __restrict__ x,
                                               float* __restrict__ part) {
  const int blk = blockIdx.x;
  const size_t base = (size_t)blk * 4096;
  const int tid = threadIdx.x;
  float s = 0.f, ss = 0.f;
#pragma unroll
  for (int k = 0; k < 4; ++k) {
    const float4 v = *(const float4*)(x + base + (size_t)(k * 256 + tid) * 4);
    s += v.x + v.y + v.z + v.w;
    ss += v.x * v.x + v.y * v.y + v.z * v.z + v.w * v.w;
  }
#pragma unroll
  for (int off = 32; off >= 1; off >>= 1) {
    s += __shfl_down(s, off);
    ss += __shfl_down(ss, off);
  }
  __shared__ float rs[4], rss[4];
  const int wid = tid >> 6;
  if ((tid & 63) == 0) { rs[wid] = s; rss[wid] = ss; }
  __syncthreads();
  if (tid == 0) {
    part[blk * 2] = rs[0] + rs[1] + rs[2] + rs[3];
    part[blk * 2 + 1] = rss[0] + rss[1] + rss[2] + rss[3];
  }
}

// ---------------------------------------------------------------------------
// K2: normalize + convert + transpose: x fp32 [b][c][t] -> hT bf16 [b][t][c].
// Group stats reduced inline from part (8 partials/group, L2-hot).
// ---------------------------------------------------------------------------
__global__ __launch_bounds__(256) void norm_trans(const float* __restrict__ x,
                                                  const float* __restrict__ part,
                                                  const float* __restrict__ gamma,
                                                  const float* __restrict__ beta,
                                                  unsigned short* __restrict__ hT) {
  __shared__ unsigned short Tl[64][72];
  const int tid = threadIdx.x;
  const int b = blockIdx.z, c0 = blockIdx.y * 64, t0 = blockIdx.x * 64;
  const int cl = tid >> 2, j16 = (tid & 3) * 16;
  const int c = c0 + cl;
  const int grp = c >> 4;
  float s = 0.f, ss = 0.f;
#pragma unroll
  for (int i = 0; i < 8; ++i) {
    s += part[(b * 256 + grp * 8 + i) * 2];
    ss += part[(b * 256 + grp * 8 + i) * 2 + 1];
  }
  const float mean = s * (1.f / 32768.f);
  const float rstd = rsqrtf(ss * (1.f / 32768.f) - mean * mean + 1e-5f);
  const float ga = gamma[c] * rstd;
  const float be = beta[c] - mean * ga;
  const float* src = x + ((size_t)b * Cc + c) * Tt + t0 + j16;
#pragma unroll
  for (int q = 0; q < 4; ++q) {
    const float4 v = *(const float4*)(src + q * 4);
    Tl[j16 + q * 4 + 0][cl] = f2bf(v.x * ga + be);
    Tl[j16 + q * 4 + 1][cl] = f2bf(v.y * ga + be);
    Tl[j16 + q * 4 + 2][cl] = f2bf(v.z * ga + be);
    Tl[j16 + q * 4 + 3][cl] = f2bf(v.w * ga + be);
  }
  __syncthreads();
  const int tl = tid >> 2, i16 = (tid & 3) * 16;
  unsigned short* dst = hT + ((size_t)b * Tt + t0 + tl) * Cc + c0 + i16;
  *(u16x8*)dst = *(const u16x8*)&Tl[tl][i16];
  *(u16x8*)(dst + 8) = *(const u16x8*)&Tl[tl][i16 + 8];
}

// ---------------------------------------------------------------------------
// K3: fp32 -> bf16 convert, both weight tensors in one launch.
// ---------------------------------------------------------------------------
__global__ __launch_bounds__(256) void cvt_bf16_2(const float* __restrict__ a,
                                                  unsigned short* __restrict__ oa, int n4a,
                                                  const float* __restrict__ bsrc,
                                                  unsigned short* __restrict__ ob, int n4b) {
  const int i = blockIdx.x * 256 + threadIdx.x;
  const float* in;
  unsigned short* out;
  int idx;
  if (i < n4a) {
    in = a; out = oa; idx = i;
  } else if (i < n4a + n4b) {
    in = bsrc; out = ob; idx = i - n4a;
  } else {
    return;
  }
  const float4 v = *(const float4*)(in + (size_t)idx * 4);
  ushort4 o;
  o.x = f2bf(v.x); o.y = f2bf(v.y); o.z = f2bf(v.z); o.w = f2bf(v.w);
  *(ushort4*)(out + (size_t)idx * 4) = o;
}

// ---------------------------------------------------------------------------
// K5: bf16 MFMA GEMM, BM x 128 tile, BK=64 (two 32-col chunks), 4 waves.
// MODE 0 (QKV): V rows -> channel-major bf16 qkvc; Q/K rows -> token-major
//   qkt via per-wave LDS transpose scratch aliased onto dead staging buffers.
//   Q pre-scaled by 0.125*log2e.
// MODE 1 (proj): fp32 out + residual.
// ---------------------------------------------------------------------------
template <int MODE, int BM>
__global__ __launch_bounds__(256) void gemm_mfma(const unsigned short* __restrict__ A,
                                                 const unsigned short* __restrict__ Bt,
                                                 const float* __restrict__ bias,
                                                 const float* __restrict__ res,
                                                 unsigned short* __restrict__ outb,
                                                 float* __restrict__ outf,
                                                 unsigned short* __restrict__ qkt,
                                                 int M) {
  constexpr int NA = BM / 32;  // A-frags per wave
  __shared__ unsigned short SMEM[(BM + 128) * 64];  // Al | Bl (chunked by 32 cols)
  unsigned short* Al = SMEM;
  unsigned short* Bl = SMEM + BM * 64;
  const int tid = threadIdx.x;
  const int n0 = blockIdx.x * 128, m0 = blockIdx.y * BM;
  const size_t z = blockIdx.z;
  const int l = tid & 63, il = l & 15, g = l >> 4;
  const int w = tid >> 6;
  const int wm = (w >> 1) * (BM / 2), wn = (w & 1) * 64;

  const unsigned short* Bz = Bt + z * (size_t)Tt * Cc;
  const unsigned short* Ap = A + (size_t)(m0 + (tid >> 2)) * Cc + (tid & 3) * 8;
  const unsigned short* Bp = Bz + (size_t)(n0 + (tid >> 2)) * Cc + (tid & 3) * 8;
  char* ldsA = (char*)Al + w * 1024;
  char* ldsB = (char*)Bl + w * 1024;

  f32x4 acc[NA][4] = {};
  for (int k0 = 0; k0 < Cc; k0 += 64) {
#pragma unroll
    for (int ks = 0; ks < 2; ++ks) {
      const int ko = k0 + ks * 32;
      async16(Ap + ko, ldsA + ks * (BM * 64));
      if (BM == 128) async16(Ap + (size_t)64 * Cc + ko, ldsA + ks * (BM * 64) + 4096);
      async16(Bp + ko, ldsB + ks * (128 * 64));
      async16(Bp + (size_t)64 * Cc + ko, ldsB + ks * (128 * 64) + 4096);
    }
    __syncthreads();
    __builtin_amdgcn_s_setprio(1);
#pragma unroll
    for (int ks = 0; ks < 2; ++ks) {
      short8 af[NA], bf[4];
#pragma unroll
      for (int i = 0; i < NA; ++i)
        af[i] = *(const short8*)(Al + ks * (BM * 32) + (wm + i * 16 + il) * 32 + g * 8);
#pragma unroll
      for (int j = 0; j < 4; ++j)
        bf[j] = *(const short8*)(Bl + ks * (128 * 32) + (wn + j * 16 + il) * 32 + g * 8);
#pragma unroll
      for (int i = 0; i < NA; ++i)
#pragma unroll
        for (int j = 0; j < 4; ++j)
          acc[i][j] = __builtin_amdgcn_mfma_f32_16x16x32_bf16(af[i], bf[j], acc[i][j], 0, 0, 0);
    }
    __builtin_amdgcn_s_setprio(0);
    __syncthreads();
  }

  if (MODE == 1) {
#pragma unroll
    for (int i = 0; i < NA; ++i) {
#pragma unroll
      for (int r = 0; r < 4; ++r) {
        const int m = m0 + wm + i * 16 + 4 * g + r;
        const float bv = bias[m];
#pragma unroll
        for (int j = 0; j < 4; ++j) {
          const int n = n0 + wn + j * 16 + il;
          const size_t idx = (z * (size_t)M + m) * Tt + n;
          outf[idx] = acc[i][j][r] + bv + res[idx];
        }
      }
    }
  } else {
    const int r0 = m0 + wm;
    const int sec = (r0 % 192) >> 6;  // 0=Q, 1=K, 2=V
    const int hh = r0 / 192;
    if (sec == 2) {
#pragma unroll
      for (int i = 0; i < 4; ++i) {
#pragma unroll
        for (int r = 0; r < 4; ++r) {
          const int m = r0 + i * 16 + 4 * g + r;
          const float bv = bias[m];
#pragma unroll
          for (int j = 0; j < 4; ++j) {
            const int n = n0 + wn + j * 16 + il;
            outb[(z * (size_t)M + m) * Tt + n] = f2bf(acc[i][j][r] + bv);
          }
        }
      }
    } else {
      // Q/K: token-major via per-wave scratch aliased onto dead Al/Bl.
      unsigned short (*Sc)[32][72] = (unsigned short(*)[32][72])SMEM;
      const float qs = (sec == 0) ? 0.125f * 1.44269504f : 1.0f;
      const size_t obase = ((size_t)(z * (Hh * 2)) + hh * 2 + sec) * Tt;
#pragma unroll
      for (int hf = 0; hf < 2; ++hf) {
#pragma unroll
        for (int i = 0; i < 4; ++i) {
          const int mloc = i * 16 + 4 * g;
          const float b0 = bias[r0 + mloc + 0];
          const float b1 = bias[r0 + mloc + 1];
          const float b2 = bias[r0 + mloc + 2];
          const float b3 = bias[r0 + mloc + 3];
#pragma unroll
          for (int j2 = 0; j2 < 2; ++j2) {
            const int j = hf * 2 + j2;
            ushort4 pkk;
            pkk.x = f2bf((acc[i][j][0] + b0) * qs);
            pkk.y = f2bf((acc[i][j][1] + b1) * qs);
            pkk.z = f2bf((acc[i][j][2] + b2) * qs);
            pkk.w = f2bf((acc[i][j][3] + b3) * qs);
            *(ushort4*)&Sc[w][j2 * 16 + il][mloc] = pkk;
          }
        }
        asm volatile("s_waitcnt lgkmcnt(0)" ::: "memory");
#pragma unroll
        for (int it = 0; it < 4; ++it) {
          const int row = it * 8 + (l >> 3);
          const int mcol = (l & 7) * 8;
          const u16x8 vv = *(const u16x8*)&Sc[w][row][mcol];
          const int tg = n0 + wn + hf * 32 + row;
          *(u16x8*)(qkt + (obase + tg) * 64 + mcol) = vv;
        }
        asm volatile("s_waitcnt lgkmcnt(0)" ::: "memory");
      }
    }
  }
}

// ---------------------------------------------------------------------------
// K6: MFMA flash attention v7 — v5 structure + counted-vmcnt B1 (T4) at
// UNCHANGED occupancy: K triple-buffered, V double-buffered (40 KB LDS =
// exactly 4 blocks/CU), launch_bounds(256,4). Steady state B1 waits
// vmcnt(4) (newest stage stays in flight) instead of a full drain.
// Barriers are single asm blocks w/ memory clobber (no LDS access crosses).
// ---------------------------------------------------------------------------
__global__ __launch_bounds__(256, 4) void attn_mfma7(const unsigned short* __restrict__ qkt,
                                                     const unsigned short* __restrict__ qkvc,
                                                     unsigned short* __restrict__ attnoT) {
  __shared__ unsigned short Kbuf[3][64 * 64];  // 24 KB, swizzled rows
  __shared__ unsigned short Vbuf[2][64 * 64];  // 16 KB, swizzled rows

  const int tid = threadIdx.x;
  const int w = tid >> 6, l = tid & 63, il = l & 15, g = l >> 4;

  const int bid = blockIdx.x;
  const int swz = (bid & 7) * 128 + (bid >> 3);
  const int bh = swz >> 5, qt = swz & 31;
  const int b = bh >> 3, h = bh & 7;
  const int q0 = qt * 64;

  const unsigned short* Qb = qkt + (size_t)(bh * 2) * Tt * 64;
  const char* Kb = (const char*)(Qb + (size_t)Tt * 64);
  const char* Vb = (const char*)(qkvc + ((size_t)b * (3 * Cc) + h * 192 + 128) * Tt);

  short8 qf[2];
  {
    const unsigned short* qp = Qb + (size_t)(q0 + w * 16 + il) * 64 + g * 8;
    qf[0] = *(const short8*)qp;
    qf[1] = *(const short8*)(qp + 32);
  }

  union { uint32_t u[4]; short8 v; } ones;
  ones.u[0] = ones.u[1] = ones.u[2] = ones.u[3] = 0x3F803F80u;

  float m_run = 0.f;       // wave-uniform, log2 domain
  f32x4 acco[4] = {};      // O[q=4g+r][d=j*16+il]
  f32x4 acc_l = {};        // l[q=4g+r]
  uint32_t frP[2][4];      // P(t) as PV A-fragments (carried)

  const int srow = w * 16 + (l >> 3);
  const int scol = ((l & 7) ^ (l >> 3)) << 4;

  auto stageK = [&](int buf, int s0) {  // 2 loads/lane
    char* kd = (char*)&Kbuf[buf][0] + w * 2048;
    async16(Kb + (size_t)(s0 + srow) * 128 + scol, kd);
    async16(Kb + (size_t)(s0 + srow + 8) * 128 + scol, kd + 1024);
  };
  auto stageV = [&](int buf, int s0) {  // 2 loads/lane
    char* vd = (char*)&Vbuf[buf][0] + w * 2048;
    async16(Vb + (size_t)srow * (Tt * 2) + (size_t)s0 * 2 + scol, vd);
    async16(Vb + (size_t)(srow + 8) * (Tt * 2) + (size_t)s0 * 2 + scol, vd + 1024);
  };

  f32x4 accs[4];
  auto qk_phase = [&](const unsigned short* Kc) {
    const float nm = -m_run;
#pragma unroll
    for (int i = 0; i < 4; ++i) {
      accs[i][0] = nm; accs[i][1] = nm; accs[i][2] = nm; accs[i][3] = nm;
    }
#pragma unroll
    for (int ks = 0; ks < 2; ++ks) {
#pragma unroll
      for (int i = 0; i < 4; ++i) {
        const short8 kf =
            *(const short8*)(Kc + (i * 16 + il) * 64 + ((((ks << 2) + g) ^ (il & 7)) << 3));
        accs[i] = __builtin_amdgcn_mfma_f32_16x16x32_bf16(kf, qf[ks], accs[i], 0, 0, 0);
      }
    }
  };

  auto pv_phase = [&](const unsigned short* Vc) {
#pragma unroll
    for (int ks = 0; ks < 2; ++ks) {
      union { uint32_t u[4]; short8 v; } fu;
      fu.u[0] = frP[ks][0]; fu.u[1] = frP[ks][1];
      fu.u[2] = frP[ks][2]; fu.u[3] = frP[ks][3];
#pragma unroll
      for (int j = 0; j < 4; ++j) {
        const short8 vf =
            *(const short8*)(Vc + (j * 16 + il) * 64 + ((((ks << 2) + g) ^ (il & 7)) << 3));
        acco[j] = __builtin_amdgcn_mfma_f32_16x16x32_bf16(fu.v, vf, acco[j], 0, 0, 0);
      }
      acc_l = __builtin_amdgcn_mfma_f32_16x16x32_bf16(fu.v, ones.v, acc_l, 0, 0, 0);
    }
  };

  auto softmax_pack = [&]() {
    float pmax = fmaxf(fmaxf(fmaxf(accs[0][0], accs[0][1]), accs[0][2]), accs[0][3]);
    pmax = fmaxf(pmax, fmaxf(fmaxf(accs[1][0], accs[1][1]), fmaxf(accs[1][2], accs[1][3])));
    pmax = fmaxf(pmax, fmaxf(fmaxf(accs[2][0], accs[2][1]), fmaxf(accs[2][2], accs[2][3])));
    pmax = fmaxf(pmax, fmaxf(fmaxf(accs[3][0], accs[3][1]), fmaxf(accs[3][2], accs[3][3])));

    uint32_t pk[4][2];
    if (!__all(pmax <= 8.0f)) {
      float mx = pmax;
#pragma unroll
      for (int off = 1; off < 64; off <<= 1) mx = fmaxf(mx, __shfl_xor(mx, off));
      const float alpha = __builtin_amdgcn_exp2f(-mx);
      m_run += mx;
#pragma unroll
      for (int j = 0; j < 4; ++j) acco[j] = acco[j] * alpha;
      acc_l = acc_l * alpha;
#pragma unroll
      for (int i = 0; i < 4; ++i) {
        const float p0 = __builtin_amdgcn_exp2f(accs[i][0] - mx);
        const float p1 = __builtin_amdgcn_exp2f(accs[i][1] - mx);
        const float p2 = __builtin_amdgcn_exp2f(accs[i][2] - mx);
        const float p3 = __builtin_amdgcn_exp2f(accs[i][3] - mx);
        asm("v_cvt_pk_bf16_f32 %0, %1, %2" : "=v"(pk[i][0]) : "v"(p0), "v"(p1));
        asm("v_cvt_pk_bf16_f32 %0, %1, %2" : "=v"(pk[i][1]) : "v"(p2), "v"(p3));
      }
    } else {
#pragma unroll
      for (int i = 0; i < 4; ++i) {
        const float p0 = __builtin_amdgcn_exp2f(accs[i][0]);
        const float p1 = __builtin_amdgcn_exp2f(accs[i][1]);
        const float p2 = __builtin_amdgcn_exp2f(accs[i][2]);
        const float p3 = __builtin_amdgcn_exp2f(accs[i][3]);
        asm("v_cvt_pk_bf16_f32 %0, %1, %2" : "=v"(pk[i][0]) : "v"(p0), "v"(p1));
        asm("v_cvt_pk_bf16_f32 %0, %1, %2" : "=v"(pk[i][1]) : "v"(p2), "v"(p3));
      }
    }
#pragma unroll
    for (int ks = 0; ks < 2; ++ks) {
#pragma unroll
      for (int hh = 0; hh < 2; ++hh) {
        uint32_t a = pk[2 * ks][hh], bq = pk[2 * ks + 1][hh];
        asm("v_permlane32_swap_b32 %0, %1" : "+v"(a), "+v"(bq));
        asm("v_permlane16_swap_b32 %0, %1" : "+v"(a), "+v"(bq));
        frP[ks][hh] = a;
        frP[ks][2 + hh] = bq;
      }
    }
  };

  // ---- prologue
  stageK(0, 0);   stageV(0, 0);     // 4 loads
  stageK(1, 64);  stageV(1, 64);    // 4 loads
  asm volatile("s_waitcnt vmcnt(4)\n\ts_barrier" ::: "memory");  // K0,V0 in
  stageK(2, 128);                    // untouched buffer, no barrier needed
  __builtin_amdgcn_s_setprio(1);
  qk_phase(&Kbuf[0][0]);
  __builtin_amdgcn_s_setprio(0);
  softmax_pack();  // P(0) -> frP

  const int NT = Tt / 64;
  for (int t = 1; t < NT; ++t) {
    // B1: need K(t) [staged >=1 iter ago] and V(t-1); newest stage stays in
    // flight. t==1: K2 outstanding (2). t==NT-1: only V(NT-1) (2). else 4.
    if (t == 1 || t == NT - 1) {
      asm volatile("s_waitcnt vmcnt(2)\n\ts_barrier" ::: "memory");
    } else {
      asm volatile("s_waitcnt vmcnt(4)\n\ts_barrier" ::: "memory");
    }
    __builtin_amdgcn_s_setprio(1);
    qk_phase(&Kbuf[t % 3][0]);        // QK(t)
    pv_phase(&Vbuf[(t - 1) & 1][0]);  // PV(t-1) — independent, fills pipe
    __builtin_amdgcn_s_setprio(0);
    asm volatile("s_barrier" ::: "memory");  // B2: buffers reusable
    if (t + 2 < NT) stageK((t + 2) % 3, (t + 2) * 64);
    if (t + 1 < NT) stageV((t + 1) & 1, (t + 1) * 64);
    softmax_pack();  // P(t) -> frP
  }
  // final PV: V(NT-1) staged at t=NT-2, possibly still in flight -> drain
  asm volatile("s_waitcnt vmcnt(0)\n\ts_barrier" ::: "memory");
  __builtin_amdgcn_s_setprio(1);
  pv_phase(&Vbuf[(NT - 1) & 1][0]);
  __builtin_amdgcn_s_setprio(0);

  // epilogue
#pragma unroll
  for (int r = 0; r < 4; ++r) {
    const float li = 1.f / acc_l[r];
    const int tq = q0 + w * 16 + 4 * g + r;
    unsigned short* d0 = attnoT + ((size_t)b * Tt + tq) * Cc + h * 64 + il;
#pragma unroll
    for (int j = 0; j < 4; ++j) d0[j * 16] = f2bf(acco[j][r] * li);
  }
}

// ---------------------------------------------------------------------------
extern "C" void kernel_launch(void* const* d_in, const int* in_sizes, int n_in,
                              void* d_out, int out_size, void* d_ws, size_t ws_size,
                              hipStream_t stream) {
  const float* x = (const float*)d_in[0];
  const float* gamma = (const float*)d_in[1];
  const float* beta = (const float*)d_in[2];
  const float* w_qkv = (const float*)d_in[3];
  const float* b_qkv = (const float*)d_in[4];
  const float* w_proj = (const float*)d_in[5];
  const float* b_proj = (const float*)d_in[6];
  float* out = (float*)d_out;

  char* p = (char*)d_ws;
  float* part = (float*)p;                   p += 2048 * sizeof(float);
  unsigned short* hT = (unsigned short*)p;   p += (size_t)Bb * Tt * Cc * 2;
  unsigned short* wq = (unsigned short*)p;   p += (size_t)3 * Cc * Cc * 2;
  unsigned short* wp = (unsigned short*)p;   p += (size_t)Cc * Cc * 2;
  unsigned short* qkvc = (unsigned short*)p; p += (size_t)Bb * 3 * Cc * Tt * 2;
  unsigned short* qkt = (unsigned short*)p;  p += (size_t)Bb * Hh * 2 * Tt * 64 * 2;
  unsigned short* attnoT = (unsigned short*)p;

  const int n4q = 3 * Cc * Cc / 4, n4p = Cc * Cc / 4;

  gn_part<<<dim3(1024), 256, 0, stream>>>(x, part);
  norm_trans<<<dim3(Tt / 64, Cc / 64, Bb), 256, 0, stream>>>(x, part, gamma, beta, hT);
  cvt_bf16_2<<<dim3((n4q + n4p + 255) / 256), 256, 0, stream>>>(w_qkv, wq, n4q, w_proj, wp, n4p);
  gemm_mfma<0, 128><<<dim3(Tt / 128, (3 * Cc) / 128, Bb), 256, 0, stream>>>(
      wq, hT, b_qkv, nullptr, qkvc, nullptr, qkt, 3 * Cc);
  attn_mfma7<<<dim3(1024), 256, 0, stream>>>(qkt, qkvc, attnoT);
  gemm_mfma<1, 64><<<dim3(Tt / 128, Cc / 64, Bb), 256, 0, stream>>>(
      wp, attnoT, b_proj, x, nullptr, out, nullptr, Cc);
}

// Round 11
// 99.797 us; speedup vs baseline: 1.2511x; 1.0960x over previous
//
#include <hip/hip_runtime.h>
#include <hip/hip_bf16.h>
#include <math.h>
#include <stdint.h>

// Problem constants: B=4, C=512, T=2048, H=8, dh=64, G=32
#define Bb 4
#define Cc 512
#define Tt 2048
#define Hh 8

typedef __attribute__((ext_vector_type(8))) short short8;   // 8 bf16 (4 VGPR) MFMA operand
typedef __attribute__((ext_vector_type(4))) float f32x4;    // MFMA accumulator
typedef __attribute__((ext_vector_type(8))) unsigned short u16x8;

__device__ __forceinline__ unsigned short f2bf(float f) {
  __hip_bfloat16 h = __float2bfloat16(f);
  unsigned short u;
  __builtin_memcpy(&u, &h, 2);
  return u;
}
__device__ __forceinline__ float bf2f(unsigned short u) {
  union { uint32_t i; float f; } v;
  v.i = (uint32_t)u << 16;
  return v.f;
}

__device__ __forceinline__ void async16(const void* g, void* l) {
  __builtin_amdgcn_global_load_lds(
      (const __attribute__((address_space(1))) uint32_t*)g,
      (__attribute__((address_space(3))) uint32_t*)l, 16, 0, 0);
}

// ---------------------------------------------------------------------------
// K1: partial sums for GroupNorm stats. 1024 blocks; block = 4096 floats.
// ---------------------------------------------------------------------------
__global__ __launch_bounds__(256) void gn_part(const float* __restrict__ x,
                                               float* __restrict__ part) {
  const int blk = blockIdx.x;
  const size_t base = (size_t)blk * 4096;
  const int tid = threadIdx.x;
  float s = 0.f, ss = 0.f;
#pragma unroll
  for (int k = 0; k < 4; ++k) {
    const float4 v = *(const float4*)(x + base + (size_t)(k * 256 + tid) * 4);
    s += v.x + v.y + v.z + v.w;
    ss += v.x * v.x + v.y * v.y + v.z * v.z + v.w * v.w;
  }
#pragma unroll
  for (int off = 32; off >= 1; off >>= 1) {
    s += __shfl_down(s, off);
    ss += __shfl_down(ss, off);
  }
  __shared__ float rs[4], rss[4];
  const int wid = tid >> 6;
  if ((tid & 63) == 0) { rs[wid] = s; rss[wid] = ss; }
  __syncthreads();
  if (tid == 0) {
    part[blk * 2] = rs[0] + rs[1] + rs[2] + rs[3];
    part[blk * 2 + 1] = rss[0] + rss[1] + rss[2] + rss[3];
  }
}

// ---------------------------------------------------------------------------
// K2: normalize + convert + transpose: x fp32 [b][c][t] -> hT bf16 [b][t][c].
// Group stats reduced inline from part (8 partials/group, L2-hot).
// ---------------------------------------------------------------------------
__global__ __launch_bounds__(256) void norm_trans(const float* __restrict__ x,
                                                  const float* __restrict__ part,
                                                  const float* __restrict__ gamma,
                                                  const float* __restrict__ beta,
                                                  unsigned short* __restrict__ hT) {
  __shared__ unsigned short Tl[64][72];
  const int tid = threadIdx.x;
  const int b = blockIdx.z, c0 = blockIdx.y * 64, t0 = blockIdx.x * 64;
  const int cl = tid >> 2, j16 = (tid & 3) * 16;
  const int c = c0 + cl;
  const int grp = c >> 4;
  float s = 0.f, ss = 0.f;
#pragma unroll
  for (int i = 0; i < 8; ++i) {
    s += part[(b * 256 + grp * 8 + i) * 2];
    ss += part[(b * 256 + grp * 8 + i) * 2 + 1];
  }
  const float mean = s * (1.f / 32768.f);
  const float rstd = rsqrtf(ss * (1.f / 32768.f) - mean * mean + 1e-5f);
  const float ga = gamma[c] * rstd;
  const float be = beta[c] - mean * ga;
  const float* src = x + ((size_t)b * Cc + c) * Tt + t0 + j16;
#pragma unroll
  for (int q = 0; q < 4; ++q) {
    const float4 v = *(const float4*)(src + q * 4);
    Tl[j16 + q * 4 + 0][cl] = f2bf(v.x * ga + be);
    Tl[j16 + q * 4 + 1][cl] = f2bf(v.y * ga + be);
    Tl[j16 + q * 4 + 2][cl] = f2bf(v.z * ga + be);
    Tl[j16 + q * 4 + 3][cl] = f2bf(v.w * ga + be);
  }
  __syncthreads();
  const int tl = tid >> 2, i16 = (tid & 3) * 16;
  unsigned short* dst = hT + ((size_t)b * Tt + t0 + tl) * Cc + c0 + i16;
  *(u16x8*)dst = *(const u16x8*)&Tl[tl][i16];
  *(u16x8*)(dst + 8) = *(const u16x8*)&Tl[tl][i16 + 8];
}

// ---------------------------------------------------------------------------
// K3: fp32 -> bf16 convert, both weight tensors in one launch.
// ---------------------------------------------------------------------------
__global__ __launch_bounds__(256) void cvt_bf16_2(const float* __restrict__ a,
                                                  unsigned short* __restrict__ oa, int n4a,
                                                  const float* __restrict__ bsrc,
                                                  unsigned short* __restrict__ ob, int n4b) {
  const int i = blockIdx.x * 256 + threadIdx.x;
  const float* in;
  unsigned short* out;
  int idx;
  if (i < n4a) {
    in = a; out = oa; idx = i;
  } else if (i < n4a + n4b) {
    in = bsrc; out = ob; idx = i - n4a;
  } else {
    return;
  }
  const float4 v = *(const float4*)(in + (size_t)idx * 4);
  ushort4 o;
  o.x = f2bf(v.x); o.y = f2bf(v.y); o.z = f2bf(v.z); o.w = f2bf(v.w);
  *(ushort4*)(out + (size_t)idx * 4) = o;
}

// ---------------------------------------------------------------------------
// K5: bf16 MFMA GEMM, BM x 128 tile, BK=64 (two 32-col chunks), 4 waves.
// MODE 0 (QKV): V rows -> channel-major bf16 qkvc; Q/K rows -> token-major
//   qkt via per-wave LDS transpose scratch aliased onto dead staging buffers.
//   Q pre-scaled by 0.125*log2e.
// MODE 1 (proj): fp32 out + residual.
// ---------------------------------------------------------------------------
template <int MODE, int BM>
__global__ __launch_bounds__(256) void gemm_mfma(const unsigned short* __restrict__ A,
                                                 const unsigned short* __restrict__ Bt,
                                                 const float* __restrict__ bias,
                                                 const float* __restrict__ res,
                                                 unsigned short* __restrict__ outb,
                                                 float* __restrict__ outf,
                                                 unsigned short* __restrict__ qkt,
                                                 int M) {
  constexpr int NA = BM / 32;  // A-frags per wave
  __shared__ unsigned short SMEM[(BM + 128) * 64];  // Al | Bl (chunked by 32 cols)
  unsigned short* Al = SMEM;
  unsigned short* Bl = SMEM + BM * 64;
  const int tid = threadIdx.x;
  const int n0 = blockIdx.x * 128, m0 = blockIdx.y * BM;
  const size_t z = blockIdx.z;
  const int l = tid & 63, il = l & 15, g = l >> 4;
  const int w = tid >> 6;
  const int wm = (w >> 1) * (BM / 2), wn = (w & 1) * 64;

  const unsigned short* Bz = Bt + z * (size_t)Tt * Cc;
  const unsigned short* Ap = A + (size_t)(m0 + (tid >> 2)) * Cc + (tid & 3) * 8;
  const unsigned short* Bp = Bz + (size_t)(n0 + (tid >> 2)) * Cc + (tid & 3) * 8;
  char* ldsA = (char*)Al + w * 1024;
  char* ldsB = (char*)Bl + w * 1024;

  f32x4 acc[NA][4] = {};
  for (int k0 = 0; k0 < Cc; k0 += 64) {
#pragma unroll
    for (int ks = 0; ks < 2; ++ks) {
      const int ko = k0 + ks * 32;
      async16(Ap + ko, ldsA + ks * (BM * 64));
      if (BM == 128) async16(Ap + (size_t)64 * Cc + ko, ldsA + ks * (BM * 64) + 4096);
      async16(Bp + ko, ldsB + ks * (128 * 64));
      async16(Bp + (size_t)64 * Cc + ko, ldsB + ks * (128 * 64) + 4096);
    }
    __syncthreads();
    __builtin_amdgcn_s_setprio(1);
#pragma unroll
    for (int ks = 0; ks < 2; ++ks) {
      short8 af[NA], bf[4];
#pragma unroll
      for (int i = 0; i < NA; ++i)
        af[i] = *(const short8*)(Al + ks * (BM * 32) + (wm + i * 16 + il) * 32 + g * 8);
#pragma unroll
      for (int j = 0; j < 4; ++j)
        bf[j] = *(const short8*)(Bl + ks * (128 * 32) + (wn + j * 16 + il) * 32 + g * 8);
#pragma unroll
      for (int i = 0; i < NA; ++i)
#pragma unroll
        for (int j = 0; j < 4; ++j)
          acc[i][j] = __builtin_amdgcn_mfma_f32_16x16x32_bf16(af[i], bf[j], acc[i][j], 0, 0, 0);
    }
    __builtin_amdgcn_s_setprio(0);
    __syncthreads();
  }

  if (MODE == 1) {
#pragma unroll
    for (int i = 0; i < NA; ++i) {
#pragma unroll
      for (int r = 0; r < 4; ++r) {
        const int m = m0 + wm + i * 16 + 4 * g + r;
        const float bv = bias[m];
#pragma unroll
        for (int j = 0; j < 4; ++j) {
          const int n = n0 + wn + j * 16 + il;
          const size_t idx = (z * (size_t)M + m) * Tt + n;
          outf[idx] = acc[i][j][r] + bv + res[idx];
        }
      }
    }
  } else {
    const int r0 = m0 + wm;
    const int sec = (r0 % 192) >> 6;  // 0=Q, 1=K, 2=V
    const int hh = r0 / 192;
    if (sec == 2) {
#pragma unroll
      for (int i = 0; i < 4; ++i) {
#pragma unroll
        for (int r = 0; r < 4; ++r) {
          const int m = r0 + i * 16 + 4 * g + r;
          const float bv = bias[m];
#pragma unroll
          for (int j = 0; j < 4; ++j) {
            const int n = n0 + wn + j * 16 + il;
            outb[(z * (size_t)M + m) * Tt + n] = f2bf(acc[i][j][r] + bv);
          }
        }
      }
    } else {
      // Q/K: token-major via per-wave scratch aliased onto dead Al/Bl.
      unsigned short (*Sc)[32][72] = (unsigned short(*)[32][72])SMEM;
      const float qs = (sec == 0) ? 0.125f * 1.44269504f : 1.0f;
      const size_t obase = ((size_t)(z * (Hh * 2)) + hh * 2 + sec) * Tt;
#pragma unroll
      for (int hf = 0; hf < 2; ++hf) {
#pragma unroll
        for (int i = 0; i < 4; ++i) {
          const int mloc = i * 16 + 4 * g;
          const float b0 = bias[r0 + mloc + 0];
          const float b1 = bias[r0 + mloc + 1];
          const float b2 = bias[r0 + mloc + 2];
          const float b3 = bias[r0 + mloc + 3];
#pragma unroll
          for (int j2 = 0; j2 < 2; ++j2) {
            const int j = hf * 2 + j2;
            ushort4 pkk;
            pkk.x = f2bf((acc[i][j][0] + b0) * qs);
            pkk.y = f2bf((acc[i][j][1] + b1) * qs);
            pkk.z = f2bf((acc[i][j][2] + b2) * qs);
            pkk.w = f2bf((acc[i][j][3] + b3) * qs);
            *(ushort4*)&Sc[w][j2 * 16 + il][mloc] = pkk;
          }
        }
        asm volatile("s_waitcnt lgkmcnt(0)" ::: "memory");
#pragma unroll
        for (int it = 0; it < 4; ++it) {
          const int row = it * 8 + (l >> 3);
          const int mcol = (l & 7) * 8;
          const u16x8 vv = *(const u16x8*)&Sc[w][row][mcol];
          const int tg = n0 + wn + hf * 32 + row;
          *(u16x8*)(qkt + (obase + tg) * 64 + mcol) = vv;
        }
        asm volatile("s_waitcnt lgkmcnt(0)" ::: "memory");
      }
    }
  }
}

// ---------------------------------------------------------------------------
// K6: MFMA flash attention v9 — BISECT of R10's failure.
// Dual q-strips per wave (QBLK=128, kf/vf LDS fragments shared by both
// strips' MFMAs — the LDS-BW lever) but with FULLY INDEPENDENT per-strip
// softmax state: m_run0/m_run1, acc_l0/1, and softmax_one == the exact v5
// (R8-passing) softmax/pack body applied to one strip's state, called twice.
// No cross-strip coupling anywhere. Grid 512, 2 blocks/CU, 32KB LDS.
// ---------------------------------------------------------------------------
__global__ __launch_bounds__(256, 2) void attn_mfma9(const unsigned short* __restrict__ qkt,
                                                     const unsigned short* __restrict__ qkvc,
                                                     unsigned short* __restrict__ attnoT) {
  __shared__ unsigned short KVs[2][2][64 * 64];  // [buf][K/V][row*64+col] swizzled

  const int tid = threadIdx.x;
  const int w = tid >> 6, l = tid & 63, il = l & 15, g = l >> 4;

  // XCD swizzle (512 % 8 == 0 -> bijective)
  const int bid = blockIdx.x;
  const int swz = (bid & 7) * 64 + (bid >> 3);
  const int bh = swz >> 4, qt = swz & 15;
  const int b = bh >> 3, h = bh & 7;
  const int q0 = qt * 128;

  const unsigned short* Qb = qkt + (size_t)(bh * 2) * Tt * 64;
  const char* Kb = (const char*)(Qb + (size_t)Tt * 64);
  const char* Vb = (const char*)(qkvc + ((size_t)b * (3 * Cc) + h * 192 + 128) * Tt);

  // Q fragments for both strips (wave w owns q rows q0+w*32 .. +31)
  short8 qf0[2], qf1[2];
  {
    const unsigned short* qp = Qb + (size_t)(q0 + w * 32 + il) * 64 + g * 8;
    qf0[0] = *(const short8*)qp;
    qf0[1] = *(const short8*)(qp + 32);
    qf1[0] = *(const short8*)(qp + 16 * 64);
    qf1[1] = *(const short8*)(qp + 16 * 64 + 32);
  }

  union { uint32_t u[4]; short8 v; } ones;
  ones.u[0] = ones.u[1] = ones.u[2] = ones.u[3] = 0x3F803F80u;

  float m_run0 = 0.f, m_run1 = 0.f;       // per-strip wave-uniform, log2 domain
  f32x4 acco0[4] = {}, acco1[4] = {};     // O[q=4g+r][d=j*16+il] per strip
  f32x4 acc_l0 = {}, acc_l1 = {};         // l[q=4g+r] per strip
  uint32_t frP0[2][4], frP1[2][4];        // P as PV A-fragments (carried)

  const int srow = w * 16 + (l >> 3);
  const int scol = ((l & 7) ^ (l >> 3)) << 4;

  auto stage = [&](int buf, int s0) {
    char* kd = (char*)&KVs[buf][0][0] + w * 2048;
    char* vd = (char*)&KVs[buf][1][0] + w * 2048;
    async16(Kb + (size_t)(s0 + srow) * 128 + scol, kd);
    async16(Kb + (size_t)(s0 + srow + 8) * 128 + scol, kd + 1024);
    async16(Vb + (size_t)srow * (Tt * 2) + (size_t)s0 * 2 + scol, vd);
    async16(Vb + (size_t)(srow + 8) * (Tt * 2) + (size_t)s0 * 2 + scol, vd + 1024);
  };

  f32x4 accs0[4], accs1[4];
  auto qk_phase = [&](int buf) {
    const float nm0 = -m_run0, nm1 = -m_run1;
#pragma unroll
    for (int i = 0; i < 4; ++i) {
      accs0[i][0] = nm0; accs0[i][1] = nm0; accs0[i][2] = nm0; accs0[i][3] = nm0;
      accs1[i][0] = nm1; accs1[i][1] = nm1; accs1[i][2] = nm1; accs1[i][3] = nm1;
    }
    const unsigned short* Kc = &KVs[buf][0][0];
#pragma unroll
    for (int ks = 0; ks < 2; ++ks) {
#pragma unroll
      for (int i = 0; i < 4; ++i) {
        const short8 kf =
            *(const short8*)(Kc + (i * 16 + il) * 64 + ((((ks << 2) + g) ^ (il & 7)) << 3));
        accs0[i] = __builtin_amdgcn_mfma_f32_16x16x32_bf16(kf, qf0[ks], accs0[i], 0, 0, 0);
        accs1[i] = __builtin_amdgcn_mfma_f32_16x16x32_bf16(kf, qf1[ks], accs1[i], 0, 0, 0);
      }
    }
  };

  auto pv_phase = [&](int buf) {
    const unsigned short* Vc = &KVs[buf][1][0];
#pragma unroll
    for (int ks = 0; ks < 2; ++ks) {
      union { uint32_t u[4]; short8 v; } fu0, fu1;
      fu0.u[0] = frP0[ks][0]; fu0.u[1] = frP0[ks][1];
      fu0.u[2] = frP0[ks][2]; fu0.u[3] = frP0[ks][3];
      fu1.u[0] = frP1[ks][0]; fu1.u[1] = frP1[ks][1];
      fu1.u[2] = frP1[ks][2]; fu1.u[3] = frP1[ks][3];
#pragma unroll
      for (int j = 0; j < 4; ++j) {
        const short8 vf =
            *(const short8*)(Vc + (j * 16 + il) * 64 + ((((ks << 2) + g) ^ (il & 7)) << 3));
        acco0[j] = __builtin_amdgcn_mfma_f32_16x16x32_bf16(fu0.v, vf, acco0[j], 0, 0, 0);
        acco1[j] = __builtin_amdgcn_mfma_f32_16x16x32_bf16(fu1.v, vf, acco1[j], 0, 0, 0);
      }
      acc_l0 = __builtin_amdgcn_mfma_f32_16x16x32_bf16(fu0.v, ones.v, acc_l0, 0, 0, 0);
      acc_l1 = __builtin_amdgcn_mfma_f32_16x16x32_bf16(fu1.v, ones.v, acc_l1, 0, 0, 0);
    }
  };

  // Exact v5 softmax/pack body on one strip's state (no cross-strip coupling).
  auto softmax_one = [&](f32x4 (&accs)[4], f32x4 (&acco)[4], f32x4& acc_l,
                         float& m_run, uint32_t (&frP)[2][4]) {
    float pmax = fmaxf(fmaxf(fmaxf(accs[0][0], accs[0][1]), accs[0][2]), accs[0][3]);
    pmax = fmaxf(pmax, fmaxf(fmaxf(accs[1][0], accs[1][1]), fmaxf(accs[1][2], accs[1][3])));
    pmax = fmaxf(pmax, fmaxf(fmaxf(accs[2][0], accs[2][1]), fmaxf(accs[2][2], accs[2][3])));
    pmax = fmaxf(pmax, fmaxf(fmaxf(accs[3][0], accs[3][1]), fmaxf(accs[3][2], accs[3][3])));

    uint32_t pk[4][2];
    if (!__all(pmax <= 8.0f)) {
      float mx = pmax;
#pragma unroll
      for (int off = 1; off < 64; off <<= 1) mx = fmaxf(mx, __shfl_xor(mx, off));
      const float alpha = __builtin_amdgcn_exp2f(-mx);
      m_run += mx;
#pragma unroll
      for (int j = 0; j < 4; ++j) acco[j] = acco[j] * alpha;
      acc_l = acc_l * alpha;
#pragma unroll
      for (int i = 0; i < 4; ++i) {
        const float p0 = __builtin_amdgcn_exp2f(accs[i][0] - mx);
        const float p1 = __builtin_amdgcn_exp2f(accs[i][1] - mx);
        const float p2 = __builtin_amdgcn_exp2f(accs[i][2] - mx);
        const float p3 = __builtin_amdgcn_exp2f(accs[i][3] - mx);
        asm("v_cvt_pk_bf16_f32 %0, %1, %2" : "=v"(pk[i][0]) : "v"(p0), "v"(p1));
        asm("v_cvt_pk_bf16_f32 %0, %1, %2" : "=v"(pk[i][1]) : "v"(p2), "v"(p3));
      }
    } else {
#pragma unroll
      for (int i = 0; i < 4; ++i) {
        const float p0 = __builtin_amdgcn_exp2f(accs[i][0]);
        const float p1 = __builtin_amdgcn_exp2f(accs[i][1]);
        const float p2 = __builtin_amdgcn_exp2f(accs[i][2]);
        const float p3 = __builtin_amdgcn_exp2f(accs[i][3]);
        asm("v_cvt_pk_bf16_f32 %0, %1, %2" : "=v"(pk[i][0]) : "v"(p0), "v"(p1));
        asm("v_cvt_pk_bf16_f32 %0, %1, %2" : "=v"(pk[i][1]) : "v"(p2), "v"(p3));
      }
    }
#pragma unroll
    for (int ks = 0; ks < 2; ++ks) {
#pragma unroll
      for (int hh = 0; hh < 2; ++hh) {
        uint32_t a = pk[2 * ks][hh], bq = pk[2 * ks + 1][hh];
        asm("v_permlane32_swap_b32 %0, %1" : "+v"(a), "+v"(bq));
        asm("v_permlane16_swap_b32 %0, %1" : "+v"(a), "+v"(bq));
        frP[ks][hh] = a;
        frP[ks][2 + hh] = bq;
      }
    }
  };

  // ---- prologue: tile 0
  stage(0, 0);
  __syncthreads();           // drain tile-0 loads
  stage(1, 64);              // tile 1 into b1 (no readers yet)
  __builtin_amdgcn_s_setprio(1);
  qk_phase(0);
  __builtin_amdgcn_s_setprio(0);
  softmax_one(accs0, acco0, acc_l0, m_run0, frP0);
  softmax_one(accs1, acco1, acc_l1, m_run1, frP1);

  const int NT = Tt / 64;
  for (int t = 1; t < NT; ++t) {
    const int cb = t & 1, pb = cb ^ 1;
    __syncthreads();         // B1: drains stage(t); all waves past PV(t-2)
    __builtin_amdgcn_s_setprio(1);
    qk_phase(cb);            // QK(t)
    pv_phase(pb);            // PV(t-1) — independent, fills MFMA pipe
    __builtin_amdgcn_s_setprio(0);
    __syncthreads();         // B2: all waves done reading b[pb]
    if (t + 1 < NT) stage(pb, (t + 1) * 64);
    softmax_one(accs0, acco0, acc_l0, m_run0, frP0);
    softmax_one(accs1, acco1, acc_l1, m_run1, frP1);
  }
  // final PV for tile NT-1 (buffer 1 still valid)
  __builtin_amdgcn_s_setprio(1);
  pv_phase(1);
  __builtin_amdgcn_s_setprio(0);

  // epilogue: both strips
#pragma unroll
  for (int r = 0; r < 4; ++r) {
    const float li0 = 1.f / acc_l0[r];
    const float li1 = 1.f / acc_l1[r];
    const int tq = q0 + w * 32 + 4 * g + r;
    unsigned short* d0 = attnoT + ((size_t)b * Tt + tq) * Cc + h * 64 + il;
    unsigned short* d1 = attnoT + ((size_t)b * Tt + tq + 16) * Cc + h * 64 + il;
#pragma unroll
    for (int j = 0; j < 4; ++j) {
      d0[j * 16] = f2bf(acco0[j][r] * li0);
      d1[j * 16] = f2bf(acco1[j][r] * li1);
    }
  }
}

// ---------------------------------------------------------------------------
extern "C" void kernel_launch(void* const* d_in, const int* in_sizes, int n_in,
                              void* d_out, int out_size, void* d_ws, size_t ws_size,
                              hipStream_t stream) {
  const float* x = (const float*)d_in[0];
  const float* gamma = (const float*)d_in[1];
  const float* beta = (const float*)d_in[2];
  const float* w_qkv = (const float*)d_in[3];
  const float* b_qkv = (const float*)d_in[4];
  const float* w_proj = (const float*)d_in[5];
  const float* b_proj = (const float*)d_in[6];
  float* out = (float*)d_out;

  char* p = (char*)d_ws;
  float* part = (float*)p;                   p += 2048 * sizeof(float);
  unsigned short* hT = (unsigned short*)p;   p += (size_t)Bb * Tt * Cc * 2;
  unsigned short* wq = (unsigned short*)p;   p += (size_t)3 * Cc * Cc * 2;
  unsigned short* wp = (unsigned short*)p;   p += (size_t)Cc * Cc * 2;
  unsigned short* qkvc = (unsigned short*)p; p += (size_t)Bb * 3 * Cc * Tt * 2;
  unsigned short* qkt = (unsigned short*)p;  p += (size_t)Bb * Hh * 2 * Tt * 64 * 2;
  unsigned short* attnoT = (unsigned short*)p;

  const int n4q = 3 * Cc * Cc / 4, n4p = Cc * Cc / 4;

  gn_part<<<dim3(1024), 256, 0, stream>>>(x, part);
  norm_trans<<<dim3(Tt / 64, Cc / 64, Bb), 256, 0, stream>>>(x, part, gamma, beta, hT);
  cvt_bf16_2<<<dim3((n4q + n4p + 255) / 256), 256, 0, stream>>>(w_qkv, wq, n4q, w_proj, wp, n4p);
  gemm_mfma<0, 128><<<dim3(Tt / 128, (3 * Cc) / 128, Bb), 256, 0, stream>>>(
      wq, hT, b_qkv, nullptr, qkvc, nullptr, qkt, 3 * Cc);
  attn_mfma9<<<dim3(512), 256, 0, stream>>>(qkt, qkvc, attnoT);
  gemm_mfma<1, 64><<<dim3(Tt / 128, Cc / 64, Bb), 256, 0, stream>>>(
      wp, attnoT, b_proj, x, nullptr, out, nullptr, Cc);
}

// Round 12
// 96.684 us; speedup vs baseline: 1.2913x; 1.0322x over previous
//
#include <hip/hip_runtime.h>
#include <hip/hip_bf16.h>
#include <math.h>
#include <stdint.h>

// Problem constants: B=4, C=512, T=2048, H=8, dh=64, G=32
#define Bb 4
#define Cc 512
#define Tt 2048
#define Hh 8

typedef __attribute__((ext_vector_type(8))) short short8;   // 8 bf16 (4 VGPR) MFMA operand
typedef __attribute__((ext_vector_type(4))) float f32x4;    // MFMA accumulator
typedef __attribute__((ext_vector_type(8))) unsigned short u16x8;

__device__ __forceinline__ unsigned short f2bf(float f) {
  __hip_bfloat16 h = __float2bfloat16(f);
  unsigned short u;
  __builtin_memcpy(&u, &h, 2);
  return u;
}
__device__ __forceinline__ float bf2f(unsigned short u) {
  union { uint32_t i; float f; } v;
  v.i = (uint32_t)u << 16;
  return v.f;
}

__device__ __forceinline__ void async16(const void* g, void* l) {
  __builtin_amdgcn_global_load_lds(
      (const __attribute__((address_space(1))) uint32_t*)g,
      (__attribute__((address_space(3))) uint32_t*)l, 16, 0, 0);
}

// ---------------------------------------------------------------------------
// K1: partial sums for GroupNorm stats. 1024 blocks; block = 4096 floats.
// ---------------------------------------------------------------------------
__global__ __launch_bounds__(256) void gn_part(const float* __restrict__ x,
                                               float* __restrict__ part) {
  const int blk = blockIdx.x;
  const size_t base = (size_t)blk * 4096;
  const int tid = threadIdx.x;
  float s = 0.f, ss = 0.f;
#pragma unroll
  for (int k = 0; k < 4; ++k) {
    const float4 v = *(const float4*)(x + base + (size_t)(k * 256 + tid) * 4);
    s += v.x + v.y + v.z + v.w;
    ss += v.x * v.x + v.y * v.y + v.z * v.z + v.w * v.w;
  }
#pragma unroll
  for (int off = 32; off >= 1; off >>= 1) {
    s += __shfl_down(s, off);
    ss += __shfl_down(ss, off);
  }
  __shared__ float rs[4], rss[4];
  const int wid = tid >> 6;
  if ((tid & 63) == 0) { rs[wid] = s; rss[wid] = ss; }
  __syncthreads();
  if (tid == 0) {
    part[blk * 2] = rs[0] + rs[1] + rs[2] + rs[3];
    part[blk * 2 + 1] = rss[0] + rss[1] + rss[2] + rss[3];
  }
}

// ---------------------------------------------------------------------------
// K2: normalize + convert + transpose: x fp32 [b][c][t] -> hT bf16 [b][t][c].
// ---------------------------------------------------------------------------
__global__ __launch_bounds__(256) void norm_trans(const float* __restrict__ x,
                                                  const float* __restrict__ part,
                                                  const float* __restrict__ gamma,
                                                  const float* __restrict__ beta,
                                                  unsigned short* __restrict__ hT) {
  __shared__ unsigned short Tl[64][72];
  const int tid = threadIdx.x;
  const int b = blockIdx.z, c0 = blockIdx.y * 64, t0 = blockIdx.x * 64;
  const int cl = tid >> 2, j16 = (tid & 3) * 16;
  const int c = c0 + cl;
  const int grp = c >> 4;
  float s = 0.f, ss = 0.f;
#pragma unroll
  for (int i = 0; i < 8; ++i) {
    s += part[(b * 256 + grp * 8 + i) * 2];
    ss += part[(b * 256 + grp * 8 + i) * 2 + 1];
  }
  const float mean = s * (1.f / 32768.f);
  const float rstd = rsqrtf(ss * (1.f / 32768.f) - mean * mean + 1e-5f);
  const float ga = gamma[c] * rstd;
  const float be = beta[c] - mean * ga;
  const float* src = x + ((size_t)b * Cc + c) * Tt + t0 + j16;
#pragma unroll
  for (int q = 0; q < 4; ++q) {
    const float4 v = *(const float4*)(src + q * 4);
    Tl[j16 + q * 4 + 0][cl] = f2bf(v.x * ga + be);
    Tl[j16 + q * 4 + 1][cl] = f2bf(v.y * ga + be);
    Tl[j16 + q * 4 + 2][cl] = f2bf(v.z * ga + be);
    Tl[j16 + q * 4 + 3][cl] = f2bf(v.w * ga + be);
  }
  __syncthreads();
  const int tl = tid >> 2, i16 = (tid & 3) * 16;
  unsigned short* dst = hT + ((size_t)b * Tt + t0 + tl) * Cc + c0 + i16;
  *(u16x8*)dst = *(const u16x8*)&Tl[tl][i16];
  *(u16x8*)(dst + 8) = *(const u16x8*)&Tl[tl][i16 + 8];
}

// ---------------------------------------------------------------------------
// K3: fp32 -> bf16 convert, both weight tensors in one launch.
// ---------------------------------------------------------------------------
__global__ __launch_bounds__(256) void cvt_bf16_2(const float* __restrict__ a,
                                                  unsigned short* __restrict__ oa, int n4a,
                                                  const float* __restrict__ bsrc,
                                                  unsigned short* __restrict__ ob, int n4b) {
  const int i = blockIdx.x * 256 + threadIdx.x;
  const float* in;
  unsigned short* out;
  int idx;
  if (i < n4a) {
    in = a; out = oa; idx = i;
  } else if (i < n4a + n4b) {
    in = bsrc; out = ob; idx = i - n4a;
  } else {
    return;
  }
  const float4 v = *(const float4*)(in + (size_t)idx * 4);
  ushort4 o;
  o.x = f2bf(v.x); o.y = f2bf(v.y); o.z = f2bf(v.z); o.w = f2bf(v.w);
  *(ushort4*)(out + (size_t)idx * 4) = o;
}

// ---------------------------------------------------------------------------
// K5: bf16 MFMA GEMM, BM x 128 tile, BK=64 (two 32-col chunks), 4 waves.
// MODE 0 (QKV): V rows -> channel-major bf16 qkvc; Q/K rows -> token-major
//   qkt via per-wave LDS transpose scratch aliased onto dead staging buffers.
//   Q pre-scaled by 0.125*log2e.
// MODE 1 (proj): fp32 out + residual.
// ---------------------------------------------------------------------------
template <int MODE, int BM>
__global__ __launch_bounds__(256) void gemm_mfma(const unsigned short* __restrict__ A,
                                                 const unsigned short* __restrict__ Bt,
                                                 const float* __restrict__ bias,
                                                 const float* __restrict__ res,
                                                 unsigned short* __restrict__ outb,
                                                 float* __restrict__ outf,
                                                 unsigned short* __restrict__ qkt,
                                                 int M) {
  constexpr int NA = BM / 32;  // A-frags per wave
  __shared__ unsigned short SMEM[(BM + 128) * 64];  // Al | Bl (chunked by 32 cols)
  unsigned short* Al = SMEM;
  unsigned short* Bl = SMEM + BM * 64;
  const int tid = threadIdx.x;
  const int n0 = blockIdx.x * 128, m0 = blockIdx.y * BM;
  const size_t z = blockIdx.z;
  const int l = tid & 63, il = l & 15, g = l >> 4;
  const int w = tid >> 6;
  const int wm = (w >> 1) * (BM / 2), wn = (w & 1) * 64;

  const unsigned short* Bz = Bt + z * (size_t)Tt * Cc;
  const unsigned short* Ap = A + (size_t)(m0 + (tid >> 2)) * Cc + (tid & 3) * 8;
  const unsigned short* Bp = Bz + (size_t)(n0 + (tid >> 2)) * Cc + (tid & 3) * 8;
  char* ldsA = (char*)Al + w * 1024;
  char* ldsB = (char*)Bl + w * 1024;

  f32x4 acc[NA][4] = {};
  for (int k0 = 0; k0 < Cc; k0 += 64) {
#pragma unroll
    for (int ks = 0; ks < 2; ++ks) {
      const int ko = k0 + ks * 32;
      async16(Ap + ko, ldsA + ks * (BM * 64));
      if (BM == 128) async16(Ap + (size_t)64 * Cc + ko, ldsA + ks * (BM * 64) + 4096);
      async16(Bp + ko, ldsB + ks * (128 * 64));
      async16(Bp + (size_t)64 * Cc + ko, ldsB + ks * (128 * 64) + 4096);
    }
    __syncthreads();
    __builtin_amdgcn_s_setprio(1);
#pragma unroll
    for (int ks = 0; ks < 2; ++ks) {
      short8 af[NA], bf[4];
#pragma unroll
      for (int i = 0; i < NA; ++i)
        af[i] = *(const short8*)(Al + ks * (BM * 32) + (wm + i * 16 + il) * 32 + g * 8);
#pragma unroll
      for (int j = 0; j < 4; ++j)
        bf[j] = *(const short8*)(Bl + ks * (128 * 32) + (wn + j * 16 + il) * 32 + g * 8);
#pragma unroll
      for (int i = 0; i < NA; ++i)
#pragma unroll
        for (int j = 0; j < 4; ++j)
          acc[i][j] = __builtin_amdgcn_mfma_f32_16x16x32_bf16(af[i], bf[j], acc[i][j], 0, 0, 0);
    }
    __builtin_amdgcn_s_setprio(0);
    __syncthreads();
  }

  if (MODE == 1) {
#pragma unroll
    for (int i = 0; i < NA; ++i) {
#pragma unroll
      for (int r = 0; r < 4; ++r) {
        const int m = m0 + wm + i * 16 + 4 * g + r;
        const float bv = bias[m];
#pragma unroll
        for (int j = 0; j < 4; ++j) {
          const int n = n0 + wn + j * 16 + il;
          const size_t idx = (z * (size_t)M + m) * Tt + n;
          outf[idx] = acc[i][j][r] + bv + res[idx];
        }
      }
    }
  } else {
    const int r0 = m0 + wm;
    const int sec = (r0 % 192) >> 6;  // 0=Q, 1=K, 2=V
    const int hh = r0 / 192;
    if (sec == 2) {
#pragma unroll
      for (int i = 0; i < 4; ++i) {
#pragma unroll
        for (int r = 0; r < 4; ++r) {
          const int m = r0 + i * 16 + 4 * g + r;
          const float bv = bias[m];
#pragma unroll
          for (int j = 0; j < 4; ++j) {
            const int n = n0 + wn + j * 16 + il;
            outb[(z * (size_t)M + m) * Tt + n] = f2bf(acc[i][j][r] + bv);
          }
        }
      }
    } else {
      // Q/K: token-major via per-wave scratch aliased onto dead Al/Bl.
      unsigned short (*Sc)[32][72] = (unsigned short(*)[32][72])SMEM;
      const float qs = (sec == 0) ? 0.125f * 1.44269504f : 1.0f;
      const size_t obase = ((size_t)(z * (Hh * 2)) + hh * 2 + sec) * Tt;
#pragma unroll
      for (int hf = 0; hf < 2; ++hf) {
#pragma unroll
        for (int i = 0; i < 4; ++i) {
          const int mloc = i * 16 + 4 * g;
          const float b0 = bias[r0 + mloc + 0];
          const float b1 = bias[r0 + mloc + 1];
          const float b2 = bias[r0 + mloc + 2];
          const float b3 = bias[r0 + mloc + 3];
#pragma unroll
          for (int j2 = 0; j2 < 2; ++j2) {
            const int j = hf * 2 + j2;
            ushort4 pkk;
            pkk.x = f2bf((acc[i][j][0] + b0) * qs);
            pkk.y = f2bf((acc[i][j][1] + b1) * qs);
            pkk.z = f2bf((acc[i][j][2] + b2) * qs);
            pkk.w = f2bf((acc[i][j][3] + b3) * qs);
            *(ushort4*)&Sc[w][j2 * 16 + il][mloc] = pkk;
          }
        }
        asm volatile("s_waitcnt lgkmcnt(0)" ::: "memory");
#pragma unroll
        for (int it = 0; it < 4; ++it) {
          const int row = it * 8 + (l >> 3);
          const int mcol = (l & 7) * 8;
          const u16x8 vv = *(const u16x8*)&Sc[w][row][mcol];
          const int tg = n0 + wn + hf * 32 + row;
          *(u16x8*)(qkt + (obase + tg) * 64 + mcol) = vv;
        }
        asm volatile("s_waitcnt lgkmcnt(0)" ::: "memory");
      }
    }
  }
}

// ---------------------------------------------------------------------------
// K6: MFMA flash attention v10 — v9 (R11-passing) + cross-tile softmax
// pipelining. Strip0's softmax(t-1) is issued INSIDE the QK(t) MFMA region
// (independent regs -> compiler weaves VALU into MFMA/lgkm gaps); to avoid
// the stale-m C-init hazard, strip0 uses the STANDARD subtract-form softmax
// (accs init 0, p = exp2(s - m_run0)). Strip1 keeps the v9 fast form in the
// post-stage slot (covers stage latency). accs ping-pong A/B, statically
// unrolled by 2 (rule #20). Dual strips still share kf/vf LDS reads.
// ---------------------------------------------------------------------------
__global__ __launch_bounds__(256, 2) void attn_mfma10(const unsigned short* __restrict__ qkt,
                                                      const unsigned short* __restrict__ qkvc,
                                                      unsigned short* __restrict__ attnoT) {
  __shared__ unsigned short KVs[2][2][64 * 64];  // [buf][K/V][row*64+col] swizzled

  const int tid = threadIdx.x;
  const int w = tid >> 6, l = tid & 63, il = l & 15, g = l >> 4;

  // XCD swizzle (512 % 8 == 0 -> bijective)
  const int bid = blockIdx.x;
  const int swz = (bid & 7) * 64 + (bid >> 3);
  const int bh = swz >> 4, qt = swz & 15;
  const int b = bh >> 3, h = bh & 7;
  const int q0 = qt * 128;

  const unsigned short* Qb = qkt + (size_t)(bh * 2) * Tt * 64;
  const char* Kb = (const char*)(Qb + (size_t)Tt * 64);
  const char* Vb = (const char*)(qkvc + ((size_t)b * (3 * Cc) + h * 192 + 128) * Tt);

  short8 qf0[2], qf1[2];
  {
    const unsigned short* qp = Qb + (size_t)(q0 + w * 32 + il) * 64 + g * 8;
    qf0[0] = *(const short8*)qp;
    qf0[1] = *(const short8*)(qp + 32);
    qf1[0] = *(const short8*)(qp + 16 * 64);
    qf1[1] = *(const short8*)(qp + 16 * 64 + 32);
  }

  union { uint32_t u[4]; short8 v; } ones;
  ones.u[0] = ones.u[1] = ones.u[2] = ones.u[3] = 0x3F803F80u;

  float m_run0 = 0.f, m_run1 = 0.f;       // per-strip wave-uniform, log2 domain
  f32x4 acco0[4] = {}, acco1[4] = {};     // O[q=4g+r][d=j*16+il] per strip
  f32x4 acc_l0 = {}, acc_l1 = {};         // l[q=4g+r] per strip
  uint32_t frP0[2][4], frP1[2][4];        // P as PV A-fragments

  // ping-pong score tiles (even tiles -> A, odd -> B); static names (rule #20)
  f32x4 accsA0[4], accsA1[4], accsB0[4], accsB1[4];

  const int srow = w * 16 + (l >> 3);
  const int scol = ((l & 7) ^ (l >> 3)) << 4;

  auto stage = [&](int buf, int s0) {
    char* kd = (char*)&KVs[buf][0][0] + w * 2048;
    char* vd = (char*)&KVs[buf][1][0] + w * 2048;
    async16(Kb + (size_t)(s0 + srow) * 128 + scol, kd);
    async16(Kb + (size_t)(s0 + srow + 8) * 128 + scol, kd + 1024);
    async16(Vb + (size_t)srow * (Tt * 2) + (size_t)s0 * 2 + scol, vd);
    async16(Vb + (size_t)(srow + 8) * (Tt * 2) + (size_t)s0 * 2 + scol, vd + 1024);
  };

  // QK into the given tile set: strip0 init 0 (absolute scores), strip1 init -m_run1.
  auto qk_phase = [&](int buf, f32x4 (&a0)[4], f32x4 (&a1)[4]) {
    const float nm1 = -m_run1;
#pragma unroll
    for (int i = 0; i < 4; ++i) {
      a0[i][0] = 0.f; a0[i][1] = 0.f; a0[i][2] = 0.f; a0[i][3] = 0.f;
      a1[i][0] = nm1; a1[i][1] = nm1; a1[i][2] = nm1; a1[i][3] = nm1;
    }
    const unsigned short* Kc = &KVs[buf][0][0];
#pragma unroll
    for (int ks = 0; ks < 2; ++ks) {
#pragma unroll
      for (int i = 0; i < 4; ++i) {
        const short8 kf =
            *(const short8*)(Kc + (i * 16 + il) * 64 + ((((ks << 2) + g) ^ (il & 7)) << 3));
        a0[i] = __builtin_amdgcn_mfma_f32_16x16x32_bf16(kf, qf0[ks], a0[i], 0, 0, 0);
        a1[i] = __builtin_amdgcn_mfma_f32_16x16x32_bf16(kf, qf1[ks], a1[i], 0, 0, 0);
      }
    }
  };

  auto pv_phase = [&](int buf) {
#pragma unroll
    for (int ks = 0; ks < 2; ++ks) {
      union { uint32_t u[4]; short8 v; } fu0, fu1;
      fu0.u[0] = frP0[ks][0]; fu0.u[1] = frP0[ks][1];
      fu0.u[2] = frP0[ks][2]; fu0.u[3] = frP0[ks][3];
      fu1.u[0] = frP1[ks][0]; fu1.u[1] = frP1[ks][1];
      fu1.u[2] = frP1[ks][2]; fu1.u[3] = frP1[ks][3];
#pragma unroll
      for (int j = 0; j < 4; ++j) {
        const short8 vf =
            *(const short8*)(&KVs[buf][1][0] + (j * 16 + il) * 64 + ((((ks << 2) + g) ^ (il & 7)) << 3));
        acco0[j] = __builtin_amdgcn_mfma_f32_16x16x32_bf16(fu0.v, vf, acco0[j], 0, 0, 0);
        acco1[j] = __builtin_amdgcn_mfma_f32_16x16x32_bf16(fu1.v, vf, acco1[j], 0, 0, 0);
      }
      acc_l0 = __builtin_amdgcn_mfma_f32_16x16x32_bf16(fu0.v, ones.v, acc_l0, 0, 0, 0);
      acc_l1 = __builtin_amdgcn_mfma_f32_16x16x32_bf16(fu1.v, ones.v, acc_l1, 0, 0, 0);
    }
  };

  // strip0: STANDARD subtract-form softmax (absolute scores; R3-proven logic,
  // wave-uniform m). Writes frP0, updates m_run0/acco0/acc_l0.
  auto softmax0 = [&](f32x4 (&accs)[4]) {
    float pmax = fmaxf(fmaxf(fmaxf(accs[0][0], accs[0][1]), accs[0][2]), accs[0][3]);
    pmax = fmaxf(pmax, fmaxf(fmaxf(accs[1][0], accs[1][1]), fmaxf(accs[1][2], accs[1][3])));
    pmax = fmaxf(pmax, fmaxf(fmaxf(accs[2][0], accs[2][1]), fmaxf(accs[2][2], accs[2][3])));
    pmax = fmaxf(pmax, fmaxf(fmaxf(accs[3][0], accs[3][1]), fmaxf(accs[3][2], accs[3][3])));

    if (!__all(pmax <= m_run0 + 8.0f)) {
      float mx = pmax;
#pragma unroll
      for (int off = 1; off < 64; off <<= 1) mx = fmaxf(mx, __shfl_xor(mx, off));
      const float mnew = fmaxf(m_run0, mx);
      const float alpha = __builtin_amdgcn_exp2f(m_run0 - mnew);
      m_run0 = mnew;
#pragma unroll
      for (int j = 0; j < 4; ++j) acco0[j] = acco0[j] * alpha;
      acc_l0 = acc_l0 * alpha;
    }
    const float m0 = m_run0;
    uint32_t pk[4][2];
#pragma unroll
    for (int i = 0; i < 4; ++i) {
      const float p0 = __builtin_amdgcn_exp2f(accs[i][0] - m0);
      const float p1 = __builtin_amdgcn_exp2f(accs[i][1] - m0);
      const float p2 = __builtin_amdgcn_exp2f(accs[i][2] - m0);
      const float p3 = __builtin_amdgcn_exp2f(accs[i][3] - m0);
      asm("v_cvt_pk_bf16_f32 %0, %1, %2" : "=v"(pk[i][0]) : "v"(p0), "v"(p1));
      asm("v_cvt_pk_bf16_f32 %0, %1, %2" : "=v"(pk[i][1]) : "v"(p2), "v"(p3));
    }
#pragma unroll
    for (int ks = 0; ks < 2; ++ks) {
#pragma unroll
      for (int hh = 0; hh < 2; ++hh) {
        uint32_t a = pk[2 * ks][hh], bq = pk[2 * ks + 1][hh];
        asm("v_permlane32_swap_b32 %0, %1" : "+v"(a), "+v"(bq));
        asm("v_permlane16_swap_b32 %0, %1" : "+v"(a), "+v"(bq));
        frP0[ks][hh] = a;
        frP0[ks][2 + hh] = bq;
      }
    }
  };

  // strip1: v9 fast form (accs pre-offset by -m_run1). Writes frP1.
  auto softmax1 = [&](f32x4 (&accs)[4]) {
    float pmax = fmaxf(fmaxf(fmaxf(accs[0][0], accs[0][1]), accs[0][2]), accs[0][3]);
    pmax = fmaxf(pmax, fmaxf(fmaxf(accs[1][0], accs[1][1]), fmaxf(accs[1][2], accs[1][3])));
    pmax = fmaxf(pmax, fmaxf(fmaxf(accs[2][0], accs[2][1]), fmaxf(accs[2][2], accs[2][3])));
    pmax = fmaxf(pmax, fmaxf(fmaxf(accs[3][0], accs[3][1]), fmaxf(accs[3][2], accs[3][3])));

    uint32_t pk[4][2];
    if (!__all(pmax <= 8.0f)) {
      float mx = pmax;
#pragma unroll
      for (int off = 1; off < 64; off <<= 1) mx = fmaxf(mx, __shfl_xor(mx, off));
      const float alpha = __builtin_amdgcn_exp2f(-mx);
      m_run1 += mx;
#pragma unroll
      for (int j = 0; j < 4; ++j) acco1[j] = acco1[j] * alpha;
      acc_l1 = acc_l1 * alpha;
#pragma unroll
      for (int i = 0; i < 4; ++i) {
        const float p0 = __builtin_amdgcn_exp2f(accs[i][0] - mx);
        const float p1 = __builtin_amdgcn_exp2f(accs[i][1] - mx);
        const float p2 = __builtin_amdgcn_exp2f(accs[i][2] - mx);
        const float p3 = __builtin_amdgcn_exp2f(accs[i][3] - mx);
        asm("v_cvt_pk_bf16_f32 %0, %1, %2" : "=v"(pk[i][0]) : "v"(p0), "v"(p1));
        asm("v_cvt_pk_bf16_f32 %0, %1, %2" : "=v"(pk[i][1]) : "v"(p2), "v"(p3));
      }
    } else {
#pragma unroll
      for (int i = 0; i < 4; ++i) {
        const float p0 = __builtin_amdgcn_exp2f(accs[i][0]);
        const float p1 = __builtin_amdgcn_exp2f(accs[i][1]);
        const float p2 = __builtin_amdgcn_exp2f(accs[i][2]);
        const float p3 = __builtin_amdgcn_exp2f(accs[i][3]);
        asm("v_cvt_pk_bf16_f32 %0, %1, %2" : "=v"(pk[i][0]) : "v"(p0), "v"(p1));
        asm("v_cvt_pk_bf16_f32 %0, %1, %2" : "=v"(pk[i][1]) : "v"(p2), "v"(p3));
      }
    }
#pragma unroll
    for (int ks = 0; ks < 2; ++ks) {
#pragma unroll
      for (int hh = 0; hh < 2; ++hh) {
        uint32_t a = pk[2 * ks][hh], bq = pk[2 * ks + 1][hh];
        asm("v_permlane32_swap_b32 %0, %1" : "+v"(a), "+v"(bq));
        asm("v_permlane16_swap_b32 %0, %1" : "+v"(a), "+v"(bq));
        frP1[ks][hh] = a;
        frP1[ks][2 + hh] = bq;
      }
    }
  };

  const int NT = Tt / 64;

  // Iter body: QK(t)->cur ; softmax0(prev tile strip0) woven into QK region;
  // PV(t-1); B2; stage(t+1); softmax1(cur tile strip1).
  auto body = [&](int t, f32x4 (&cur0)[4], f32x4 (&cur1)[4], f32x4 (&prv0)[4]) {
    const int cb = t & 1, pb = cb ^ 1;
    __syncthreads();                       // B1: stage(t) drained
    __builtin_amdgcn_s_setprio(1);
    qk_phase(cb, cur0, cur1);              // 16 MFMAs (tile t)
    softmax0(prv0);                        // VALU, independent -> weaves; frP0(t-1)
    pv_phase(pb);                          // 20 MFMAs (tile t-1)
    __builtin_amdgcn_s_setprio(0);
    __syncthreads();                       // B2: buf[pb] reusable
    if (t + 1 < NT) stage(pb, (t + 1) * 64);
    softmax1(cur1);                        // frP1(t); covers stage latency
  };

  // ---- prologue: tile 0 (-> A)
  stage(0, 0);
  __syncthreads();
  stage(1, 64);
  __builtin_amdgcn_s_setprio(1);
  qk_phase(0, accsA0, accsA1);
  __builtin_amdgcn_s_setprio(0);
  softmax1(accsA1);                        // frP1(0)

  for (int tt = 1; tt < NT; tt += 2) {
    body(tt, accsB0, accsB1, accsA0);      // odd tile -> B, consumes A0
    if (tt + 1 < NT) body(tt + 1, accsA0, accsA1, accsB0);  // even -> A
  }
  // tail: tile NT-1 (= 31, odd -> B). frP1(31) done in its body; finish strip0.
  softmax0(accsB0);                        // frP0(31)
  __builtin_amdgcn_s_setprio(1);
  pv_phase(1);                             // V of tile 31 in buf[1]
  __builtin_amdgcn_s_setprio(0);

  // epilogue: both strips
#pragma unroll
  for (int r = 0; r < 4; ++r) {
    const float li0 = 1.f / acc_l0[r];
    const float li1 = 1.f / acc_l1[r];
    const int tq = q0 + w * 32 + 4 * g + r;
    unsigned short* d0 = attnoT + ((size_t)b * Tt + tq) * Cc + h * 64 + il;
    unsigned short* d1 = attnoT + ((size_t)b * Tt + tq + 16) * Cc + h * 64 + il;
#pragma unroll
    for (int j = 0; j < 4; ++j) {
      d0[j * 16] = f2bf(acco0[j][r] * li0);
      d1[j * 16] = f2bf(acco1[j][r] * li1);
    }
  }
}

// ---------------------------------------------------------------------------
extern "C" void kernel_launch(void* const* d_in, const int* in_sizes, int n_in,
                              void* d_out, int out_size, void* d_ws, size_t ws_size,
                              hipStream_t stream) {
  const float* x = (const float*)d_in[0];
  const float* gamma = (const float*)d_in[1];
  const float* beta = (const float*)d_in[2];
  const float* w_qkv = (const float*)d_in[3];
  const float* b_qkv = (const float*)d_in[4];
  const float* w_proj = (const float*)d_in[5];
  const float* b_proj = (const float*)d_in[6];
  float* out = (float*)d_out;

  char* p = (char*)d_ws;
  float* part = (float*)p;                   p += 2048 * sizeof(float);
  unsigned short* hT = (unsigned short*)p;   p += (size_t)Bb * Tt * Cc * 2;
  unsigned short* wq = (unsigned short*)p;   p += (size_t)3 * Cc * Cc * 2;
  unsigned short* wp = (unsigned short*)p;   p += (size_t)Cc * Cc * 2;
  unsigned short* qkvc = (unsigned short*)p; p += (size_t)Bb * 3 * Cc * Tt * 2;
  unsigned short* qkt = (unsigned short*)p;  p += (size_t)Bb * Hh * 2 * Tt * 64 * 2;
  unsigned short* attnoT = (unsigned short*)p;

  const int n4q = 3 * Cc * Cc / 4, n4p = Cc * Cc / 4;

  gn_part<<<dim3(1024), 256, 0, stream>>>(x, part);
  norm_trans<<<dim3(Tt / 64, Cc / 64, Bb), 256, 0, stream>>>(x, part, gamma, beta, hT);
  cvt_bf16_2<<<dim3((n4q + n4p + 255) / 256), 256, 0, stream>>>(w_qkv, wq, n4q, w_proj, wp, n4p);
  gemm_mfma<0, 128><<<dim3(Tt / 128, (3 * Cc) / 128, Bb), 256, 0, stream>>>(
      wq, hT, b_qkv, nullptr, qkvc, nullptr, qkt, 3 * Cc);
  attn_mfma10<<<dim3(512), 256, 0, stream>>>(qkt, qkvc, attnoT);
  gemm_mfma<1, 64><<<dim3(Tt / 128, Cc / 64, Bb), 256, 0, stream>>>(
      wp, attnoT, b_proj, x, nullptr, out, nullptr, Cc);
}

// Round 14
// 92.817 us; speedup vs baseline: 1.3451x; 1.0417x over previous
//
#include <hip/hip_runtime.h>
#include <hip/hip_bf16.h>
#include <math.h>
#include <stdint.h>

// Problem constants: B=4, C=512, T=2048, H=8, dh=64, G=32
#define Bb 4
#define Cc 512
#define Tt 2048
#define Hh 8

typedef __attribute__((ext_vector_type(8))) short short8;   // 8 bf16 (4 VGPR) MFMA operand
typedef __attribute__((ext_vector_type(4))) float f32x4;    // MFMA accumulator
typedef __attribute__((ext_vector_type(8))) unsigned short u16x8;

__device__ __forceinline__ unsigned short f2bf(float f) {
  __hip_bfloat16 h = __float2bfloat16(f);
  unsigned short u;
  __builtin_memcpy(&u, &h, 2);
  return u;
}
__device__ __forceinline__ float bf2f(unsigned short u) {
  union { uint32_t i; float f; } v;
  v.i = (uint32_t)u << 16;
  return v.f;
}

__device__ __forceinline__ void async16(const void* g, void* l) {
  __builtin_amdgcn_global_load_lds(
      (const __attribute__((address_space(1))) uint32_t*)g,
      (__attribute__((address_space(3))) uint32_t*)l, 16, 0, 0);
}

// ---------------------------------------------------------------------------
// K1: partial sums for GroupNorm stats. 1024 blocks; block = 4096 floats.
// ---------------------------------------------------------------------------
__global__ __launch_bounds__(256) void gn_part(const float* __restrict__ x,
                                               float* __restrict__ part) {
  const int blk = blockIdx.x;
  const size_t base = (size_t)blk * 4096;
  const int tid = threadIdx.x;
  float s = 0.f, ss = 0.f;
#pragma unroll
  for (int k = 0; k < 4; ++k) {
    const float4 v = *(const float4*)(x + base + (size_t)(k * 256 + tid) * 4);
    s += v.x + v.y + v.z + v.w;
    ss += v.x * v.x + v.y * v.y + v.z * v.z + v.w * v.w;
  }
#pragma unroll
  for (int off = 32; off >= 1; off >>= 1) {
    s += __shfl_down(s, off);
    ss += __shfl_down(ss, off);
  }
  __shared__ float rs[4], rss[4];
  const int wid = tid >> 6;
  if ((tid & 63) == 0) { rs[wid] = s; rss[wid] = ss; }
  __syncthreads();
  if (tid == 0) {
    part[blk * 2] = rs[0] + rs[1] + rs[2] + rs[3];
    part[blk * 2 + 1] = rss[0] + rss[1] + rss[2] + rss[3];
  }
}

// ---------------------------------------------------------------------------
// K2: normalize + convert + transpose: x fp32 [b][c][t] -> hT bf16 [b][t][c].
// ---------------------------------------------------------------------------
__global__ __launch_bounds__(256) void norm_trans(const float* __restrict__ x,
                                                  const float* __restrict__ part,
                                                  const float* __restrict__ gamma,
                                                  const float* __restrict__ beta,
                                                  unsigned short* __restrict__ hT) {
  __shared__ unsigned short Tl[64][72];
  const int tid = threadIdx.x;
  const int b = blockIdx.z, c0 = blockIdx.y * 64, t0 = blockIdx.x * 64;
  const int cl = tid >> 2, j16 = (tid & 3) * 16;
  const int c = c0 + cl;
  const int grp = c >> 4;
  float s = 0.f, ss = 0.f;
#pragma unroll
  for (int i = 0; i < 8; ++i) {
    s += part[(b * 256 + grp * 8 + i) * 2];
    ss += part[(b * 256 + grp * 8 + i) * 2 + 1];
  }
  const float mean = s * (1.f / 32768.f);
  const float rstd = rsqrtf(ss * (1.f / 32768.f) - mean * mean + 1e-5f);
  const float ga = gamma[c] * rstd;
  const float be = beta[c] - mean * ga;
  const float* src = x + ((size_t)b * Cc + c) * Tt + t0 + j16;
#pragma unroll
  for (int q = 0; q < 4; ++q) {
    const float4 v = *(const float4*)(src + q * 4);
    Tl[j16 + q * 4 + 0][cl] = f2bf(v.x * ga + be);
    Tl[j16 + q * 4 + 1][cl] = f2bf(v.y * ga + be);
    Tl[j16 + q * 4 + 2][cl] = f2bf(v.z * ga + be);
    Tl[j16 + q * 4 + 3][cl] = f2bf(v.w * ga + be);
  }
  __syncthreads();
  const int tl = tid >> 2, i16 = (tid & 3) * 16;
  unsigned short* dst = hT + ((size_t)b * Tt + t0 + tl) * Cc + c0 + i16;
  *(u16x8*)dst = *(const u16x8*)&Tl[tl][i16];
  *(u16x8*)(dst + 8) = *(const u16x8*)&Tl[tl][i16 + 8];
}

// ---------------------------------------------------------------------------
// K3: fp32 -> bf16 convert, both weight tensors in one launch.
// ---------------------------------------------------------------------------
__global__ __launch_bounds__(256) void cvt_bf16_2(const float* __restrict__ a,
                                                  unsigned short* __restrict__ oa, int n4a,
                                                  const float* __restrict__ bsrc,
                                                  unsigned short* __restrict__ ob, int n4b) {
  const int i = blockIdx.x * 256 + threadIdx.x;
  const float* in;
  unsigned short* out;
  int idx;
  if (i < n4a) {
    in = a; out = oa; idx = i;
  } else if (i < n4a + n4b) {
    in = bsrc; out = ob; idx = i - n4a;
  } else {
    return;
  }
  const float4 v = *(const float4*)(in + (size_t)idx * 4);
  ushort4 o;
  o.x = f2bf(v.x); o.y = f2bf(v.y); o.z = f2bf(v.z); o.w = f2bf(v.w);
  *(ushort4*)(out + (size_t)idx * 4) = o;
}

// ---------------------------------------------------------------------------
// K5: bf16 MFMA GEMM, BM x 128 tile, BK=32 per buffer, DOUBLE-BUFFERED
// (T3 minimum 2-phase): stage(k+1) into buf^1 overlaps compute(k) on buf;
// one __syncthreads per iter both drains the stage loads and releases the
// computed buffer. LDS total unchanged vs single-buffer BK=64 (QKV 32KB ->
// 3 blocks/CU preserved).
// MODE 0 (QKV): V rows -> channel-major bf16 qkvc; Q/K rows -> token-major
//   qkt via per-wave LDS transpose scratch aliased onto dead staging LDS.
//   Q pre-scaled by 0.125*log2e.
// MODE 1 (proj): fp32 out + residual.
// ---------------------------------------------------------------------------
template <int MODE, int BM>
__global__ __launch_bounds__(256) void gemm_mfma(const unsigned short* __restrict__ A,
                                                 const unsigned short* __restrict__ Bt,
                                                 const float* __restrict__ bias,
                                                 const float* __restrict__ res,
                                                 unsigned short* __restrict__ outb,
                                                 float* __restrict__ outf,
                                                 unsigned short* __restrict__ qkt,
                                                 int M) {
  constexpr int NA = BM / 32;  // A-frags per wave
  constexpr int BUFSZ = (BM + 128) * 32;  // shorts per buffer (A | B)
  __shared__ unsigned short SMEM[2][BUFSZ];
  const int tid = threadIdx.x;
  const int n0 = blockIdx.x * 128, m0 = blockIdx.y * BM;
  const size_t z = blockIdx.z;
  const int l = tid & 63, il = l & 15, g = l >> 4;
  const int w = tid >> 6;
  const int wm = (w >> 1) * (BM / 2), wn = (w & 1) * 64;

  const unsigned short* Bz = Bt + z * (size_t)Tt * Cc;
  const unsigned short* Ap = A + (size_t)(m0 + (tid >> 2)) * Cc + (tid & 3) * 8;
  const unsigned short* Bp = Bz + (size_t)(n0 + (tid >> 2)) * Cc + (tid & 3) * 8;

  f32x4 acc[NA][4] = {};

  auto stageg = [&](int buf, int k0) {
    char* ldsA = (char*)&SMEM[buf][0] + w * 1024;
    char* ldsB = (char*)&SMEM[buf][BM * 32] + w * 1024;
    async16(Ap + k0, ldsA);
    if (BM == 128) async16(Ap + (size_t)64 * Cc + k0, ldsA + 4096);
    async16(Bp + k0, ldsB);
    async16(Bp + (size_t)64 * Cc + k0, ldsB + 4096);
  };

  auto compute = [&](int buf) {
    const unsigned short* Al = &SMEM[buf][0];
    const unsigned short* Bl = &SMEM[buf][BM * 32];
    short8 af[NA], bf[4];
#pragma unroll
    for (int i = 0; i < NA; ++i)
      af[i] = *(const short8*)(Al + (wm + i * 16 + il) * 32 + g * 8);
#pragma unroll
    for (int j = 0; j < 4; ++j)
      bf[j] = *(const short8*)(Bl + (wn + j * 16 + il) * 32 + g * 8);
    __builtin_amdgcn_s_setprio(1);
#pragma unroll
    for (int i = 0; i < NA; ++i)
#pragma unroll
      for (int j = 0; j < 4; ++j)
        acc[i][j] = __builtin_amdgcn_mfma_f32_16x16x32_bf16(af[i], bf[j], acc[i][j], 0, 0, 0);
    __builtin_amdgcn_s_setprio(0);
  };

  // T3 2-phase: stage next chunk before computing current; one sync/iter.
  stageg(0, 0);
  __syncthreads();
  int buf = 0;
  for (int k0 = 0; k0 < Cc; k0 += 32) {
    if (k0 + 32 < Cc) stageg(buf ^ 1, k0 + 32);
    compute(buf);
    __syncthreads();  // drains stage loads; releases computed buffer
    buf ^= 1;
  }

  if (MODE == 1) {
#pragma unroll
    for (int i = 0; i < NA; ++i) {
#pragma unroll
      for (int r = 0; r < 4; ++r) {
        const int m = m0 + wm + i * 16 + 4 * g + r;
        const float bv = bias[m];
#pragma unroll
        for (int j = 0; j < 4; ++j) {
          const int n = n0 + wn + j * 16 + il;
          const size_t idx = (z * (size_t)M + m) * Tt + n;
          outf[idx] = acc[i][j][r] + bv + res[idx];
        }
      }
    }
  } else {
    const int r0 = m0 + wm;
    const int sec = (r0 % 192) >> 6;  // 0=Q, 1=K, 2=V
    const int hh = r0 / 192;
    if (sec == 2) {
#pragma unroll
      for (int i = 0; i < 4; ++i) {
#pragma unroll
        for (int r = 0; r < 4; ++r) {
          const int m = r0 + i * 16 + 4 * g + r;
          const float bv = bias[m];
#pragma unroll
          for (int j = 0; j < 4; ++j) {
            const int n = n0 + wn + j * 16 + il;
            outb[(z * (size_t)M + m) * Tt + n] = f2bf(acc[i][j][r] + bv);
          }
        }
      }
    } else {
      // Q/K: token-major via per-wave scratch aliased onto dead staging LDS.
      // Safe: final k-loop __syncthreads drained all loads and all waves are
      // past their last LDS reads; per-wave regions disjoint; syncs below are
      // intra-wave lgkmcnt only.
      unsigned short (*Sc)[32][72] = (unsigned short(*)[32][72])&SMEM[0][0];
      const float qs = (sec == 0) ? 0.125f * 1.44269504f : 1.0f;
      const size_t obase = ((size_t)(z * (Hh * 2)) + hh * 2 + sec) * Tt;
#pragma unroll
      for (int hf = 0; hf < 2; ++hf) {
#pragma unroll
        for (int i = 0; i < 4; ++i) {
          const int mloc = i * 16 + 4 * g;
          const float b0 = bias[r0 + mloc + 0];
          const float b1 = bias[r0 + mloc + 1];
          const float b2 = bias[r0 + mloc + 2];
          const float b3 = bias[r0 + mloc + 3];
#pragma unroll
          for (int j2 = 0; j2 < 2; ++j2) {
            const int j = hf * 2 + j2;
            ushort4 pkk;
            pkk.x = f2bf((acc[i][j][0] + b0) * qs);
            pkk.y = f2bf((acc[i][j][1] + b1) * qs);
            pkk.z = f2bf((acc[i][j][2] + b2) * qs);
            pkk.w = f2bf((acc[i][j][3] + b3) * qs);
            *(ushort4*)&Sc[w][j2 * 16 + il][mloc] = pkk;
          }
        }
        asm volatile("s_waitcnt lgkmcnt(0)" ::: "memory");
#pragma unroll
        for (int it = 0; it < 4; ++it) {
          const int row = it * 8 + (l >> 3);
          const int mcol = (l & 7) * 8;
          const u16x8 vv = *(const u16x8*)&Sc[w][row][mcol];
          const int tg = n0 + wn + hf * 32 + row;
          *(u16x8*)(qkt + (obase + tg) * 64 + mcol) = vv;
        }
        asm volatile("s_waitcnt lgkmcnt(0)" ::: "memory");
      }
    }
  }
}

// ---------------------------------------------------------------------------
// K6: MFMA flash attention v10 — EXACT R12-passing kernel (96.7 µs config).
// Dual q-strips per wave (QBLK=128, shared kf/vf LDS reads), cross-tile
// softmax pipelining (strip0's softmax(t-1) woven into QK(t) MFMA region,
// standard subtract form; strip1 fast form post-stage), 2-buffer K/V,
// two __syncthreads per iter. Grid 512, XCD-swizzled, launch_bounds(256,2).
// ---------------------------------------------------------------------------
__global__ __launch_bounds__(256, 2) void attn_mfma10(const unsigned short* __restrict__ qkt,
                                                      const unsigned short* __restrict__ qkvc,
                                                      unsigned short* __restrict__ attnoT) {
  __shared__ unsigned short KVs[2][2][64 * 64];  // [buf][K/V][row*64+col] swizzled

  const int tid = threadIdx.x;
  const int w = tid >> 6, l = tid & 63, il = l & 15, g = l >> 4;

  // XCD swizzle (512 % 8 == 0 -> bijective)
  const int bid = blockIdx.x;
  const int swz = (bid & 7) * 64 + (bid >> 3);
  const int bh = swz >> 4, qt = swz & 15;
  const int b = bh >> 3, h = bh & 7;
  const int q0 = qt * 128;

  const unsigned short* Qb = qkt + (size_t)(bh * 2) * Tt * 64;
  const char* Kb = (const char*)(Qb + (size_t)Tt * 64);
  const char* Vb = (const char*)(qkvc + ((size_t)b * (3 * Cc) + h * 192 + 128) * Tt);

  short8 qf0[2], qf1[2];
  {
    const unsigned short* qp = Qb + (size_t)(q0 + w * 32 + il) * 64 + g * 8;
    qf0[0] = *(const short8*)qp;
    qf0[1] = *(const short8*)(qp + 32);
    qf1[0] = *(const short8*)(qp + 16 * 64);
    qf1[1] = *(const short8*)(qp + 16 * 64 + 32);
  }

  union { uint32_t u[4]; short8 v; } ones;
  ones.u[0] = ones.u[1] = ones.u[2] = ones.u[3] = 0x3F803F80u;

  float m_run0 = 0.f, m_run1 = 0.f;       // per-strip wave-uniform, log2 domain
  f32x4 acco0[4] = {}, acco1[4] = {};     // O[q=4g+r][d=j*16+il] per strip
  f32x4 acc_l0 = {}, acc_l1 = {};         // l[q=4g+r] per strip
  uint32_t frP0[2][4], frP1[2][4];        // P as PV A-fragments

  // ping-pong score tiles (even tiles -> A, odd -> B); static names (rule #20)
  f32x4 accsA0[4], accsA1[4], accsB0[4], accsB1[4];

  const int srow = w * 16 + (l >> 3);
  const int scol = ((l & 7) ^ (l >> 3)) << 4;

  auto stage = [&](int buf, int s0) {
    char* kd = (char*)&KVs[buf][0][0] + w * 2048;
    char* vd = (char*)&KVs[buf][1][0] + w * 2048;
    async16(Kb + (size_t)(s0 + srow) * 128 + scol, kd);
    async16(Kb + (size_t)(s0 + srow + 8) * 128 + scol, kd + 1024);
    async16(Vb + (size_t)srow * (Tt * 2) + (size_t)s0 * 2 + scol, vd);
    async16(Vb + (size_t)(srow + 8) * (Tt * 2) + (size_t)s0 * 2 + scol, vd + 1024);
  };

  // QK into the given tile set: strip0 init 0 (absolute scores), strip1 init -m_run1.
  auto qk_phase = [&](int buf, f32x4 (&a0)[4], f32x4 (&a1)[4]) {
    const float nm1 = -m_run1;
#pragma unroll
    for (int i = 0; i < 4; ++i) {
      a0[i][0] = 0.f; a0[i][1] = 0.f; a0[i][2] = 0.f; a0[i][3] = 0.f;
      a1[i][0] = nm1; a1[i][1] = nm1; a1[i][2] = nm1; a1[i][3] = nm1;
    }
    const unsigned short* Kc = &KVs[buf][0][0];
#pragma unroll
    for (int ks = 0; ks < 2; ++ks) {
#pragma unroll
      for (int i = 0; i < 4; ++i) {
        const short8 kf =
            *(const short8*)(Kc + (i * 16 + il) * 64 + ((((ks << 2) + g) ^ (il & 7)) << 3));
        a0[i] = __builtin_amdgcn_mfma_f32_16x16x32_bf16(kf, qf0[ks], a0[i], 0, 0, 0);
        a1[i] = __builtin_amdgcn_mfma_f32_16x16x32_bf16(kf, qf1[ks], a1[i], 0, 0, 0);
      }
    }
  };

  auto pv_phase = [&](int buf) {
#pragma unroll
    for (int ks = 0; ks < 2; ++ks) {
      union { uint32_t u[4]; short8 v; } fu0, fu1;
      fu0.u[0] = frP0[ks][0]; fu0.u[1] = frP0[ks][1];
      fu0.u[2] = frP0[ks][2]; fu0.u[3] = frP0[ks][3];
      fu1.u[0] = frP1[ks][0]; fu1.u[1] = frP1[ks][1];
      fu1.u[2] = frP1[ks][2]; fu1.u[3] = frP1[ks][3];
#pragma unroll
      for (int j = 0; j < 4; ++j) {
        const short8 vf =
            *(const short8*)(&KVs[buf][1][0] + (j * 16 + il) * 64 + ((((ks << 2) + g) ^ (il & 7)) << 3));
        acco0[j] = __builtin_amdgcn_mfma_f32_16x16x32_bf16(fu0.v, vf, acco0[j], 0, 0, 0);
        acco1[j] = __builtin_amdgcn_mfma_f32_16x16x32_bf16(fu1.v, vf, acco1[j], 0, 0, 0);
      }
      acc_l0 = __builtin_amdgcn_mfma_f32_16x16x32_bf16(fu0.v, ones.v, acc_l0, 0, 0, 0);
      acc_l1 = __builtin_amdgcn_mfma_f32_16x16x32_bf16(fu1.v, ones.v, acc_l1, 0, 0, 0);
    }
  };

  // strip0: STANDARD subtract-form softmax (absolute scores).
  auto softmax0 = [&](f32x4 (&accs)[4]) {
    float pmax = fmaxf(fmaxf(fmaxf(accs[0][0], accs[0][1]), accs[0][2]), accs[0][3]);
    pmax = fmaxf(pmax, fmaxf(fmaxf(accs[1][0], accs[1][1]), fmaxf(accs[1][2], accs[1][3])));
    pmax = fmaxf(pmax, fmaxf(fmaxf(accs[2][0], accs[2][1]), fmaxf(accs[2][2], accs[2][3])));
    pmax = fmaxf(pmax, fmaxf(fmaxf(accs[3][0], accs[3][1]), fmaxf(accs[3][2], accs[3][3])));

    if (!__all(pmax <= m_run0 + 8.0f)) {
      float mx = pmax;
#pragma unroll
      for (int off = 1; off < 64; off <<= 1) mx = fmaxf(mx, __shfl_xor(mx, off));
      const float mnew = fmaxf(m_run0, mx);
      const float alpha = __builtin_amdgcn_exp2f(m_run0 - mnew);
      m_run0 = mnew;
#pragma unroll
      for (int j = 0; j < 4; ++j) acco0[j] = acco0[j] * alpha;
      acc_l0 = acc_l0 * alpha;
    }
    const float m0 = m_run0;
    uint32_t pk[4][2];
#pragma unroll
    for (int i = 0; i < 4; ++i) {
      const float p0 = __builtin_amdgcn_exp2f(accs[i][0] - m0);
      const float p1 = __builtin_amdgcn_exp2f(accs[i][1] - m0);
      const float p2 = __builtin_amdgcn_exp2f(accs[i][2] - m0);
      const float p3 = __builtin_amdgcn_exp2f(accs[i][3] - m0);
      asm("v_cvt_pk_bf16_f32 %0, %1, %2" : "=v"(pk[i][0]) : "v"(p0), "v"(p1));
      asm("v_cvt_pk_bf16_f32 %0, %1, %2" : "=v"(pk[i][1]) : "v"(p2), "v"(p3));
    }
#pragma unroll
    for (int ks = 0; ks < 2; ++ks) {
#pragma unroll
      for (int hh = 0; hh < 2; ++hh) {
        uint32_t a = pk[2 * ks][hh], bq = pk[2 * ks + 1][hh];
        asm("v_permlane32_swap_b32 %0, %1" : "+v"(a), "+v"(bq));
        asm("v_permlane16_swap_b32 %0, %1" : "+v"(a), "+v"(bq));
        frP0[ks][hh] = a;
        frP0[ks][2 + hh] = bq;
      }
    }
  };

  // strip1: fast form (accs pre-offset by -m_run1).
  auto softmax1 = [&](f32x4 (&accs)[4]) {
    float pmax = fmaxf(fmaxf(fmaxf(accs[0][0], accs[0][1]), accs[0][2]), accs[0][3]);
    pmax = fmaxf(pmax, fmaxf(fmaxf(accs[1][0], accs[1][1]), fmaxf(accs[1][2], accs[1][3])));
    pmax = fmaxf(pmax, fmaxf(fmaxf(accs[2][0], accs[2][1]), fmaxf(accs[2][2], accs[2][3])));
    pmax = fmaxf(pmax, fmaxf(fmaxf(accs[3][0], accs[3][1]), fmaxf(accs[3][2], accs[3][3])));

    uint32_t pk[4][2];
    if (!__all(pmax <= 8.0f)) {
      float mx = pmax;
#pragma unroll
      for (int off = 1; off < 64; off <<= 1) mx = fmaxf(mx, __shfl_xor(mx, off));
      const float alpha = __builtin_amdgcn_exp2f(-mx);
      m_run1 += mx;
#pragma unroll
      for (int j = 0; j < 4; ++j) acco1[j] = acco1[j] * alpha;
      acc_l1 = acc_l1 * alpha;
#pragma unroll
      for (int i = 0; i < 4; ++i) {
        const float p0 = __builtin_amdgcn_exp2f(accs[i][0] - mx);
        const float p1 = __builtin_amdgcn_exp2f(accs[i][1] - mx);
        const float p2 = __builtin_amdgcn_exp2f(accs[i][2] - mx);
        const float p3 = __builtin_amdgcn_exp2f(accs[i][3] - mx);
        asm("v_cvt_pk_bf16_f32 %0, %1, %2" : "=v"(pk[i][0]) : "v"(p0), "v"(p1));
        asm("v_cvt_pk_bf16_f32 %0, %1, %2" : "=v"(pk[i][1]) : "v"(p2), "v"(p3));
      }
    } else {
#pragma unroll
      for (int i = 0; i < 4; ++i) {
        const float p0 = __builtin_amdgcn_exp2f(accs[i][0]);
        const float p1 = __builtin_amdgcn_exp2f(accs[i][1]);
        const float p2 = __builtin_amdgcn_exp2f(accs[i][2]);
        const float p3 = __builtin_amdgcn_exp2f(accs[i][3]);
        asm("v_cvt_pk_bf16_f32 %0, %1, %2" : "=v"(pk[i][0]) : "v"(p0), "v"(p1));
        asm("v_cvt_pk_bf16_f32 %0, %1, %2" : "=v"(pk[i][1]) : "v"(p2), "v"(p3));
      }
    }
#pragma unroll
    for (int ks = 0; ks < 2; ++ks) {
#pragma unroll
      for (int hh = 0; hh < 2; ++hh) {
        uint32_t a = pk[2 * ks][hh], bq = pk[2 * ks + 1][hh];
        asm("v_permlane32_swap_b32 %0, %1" : "+v"(a), "+v"(bq));
        asm("v_permlane16_swap_b32 %0, %1" : "+v"(a), "+v"(bq));
        frP1[ks][hh] = a;
        frP1[ks][2 + hh] = bq;
      }
    }
  };

  const int NT = Tt / 64;

  // Iter body: QK(t)->cur ; softmax0(prev tile strip0) woven into QK region;
  // PV(t-1); B2; stage(t+1); softmax1(cur tile strip1).
  auto body = [&](int t, f32x4 (&cur0)[4], f32x4 (&cur1)[4], f32x4 (&prv0)[4]) {
    const int cb = t & 1, pb = cb ^ 1;
    __syncthreads();                       // B1: stage(t) drained
    __builtin_amdgcn_s_setprio(1);
    qk_phase(cb, cur0, cur1);              // 16 MFMAs (tile t)
    softmax0(prv0);                        // VALU, independent -> weaves; frP0(t-1)
    pv_phase(pb);                          // 20 MFMAs (tile t-1)
    __builtin_amdgcn_s_setprio(0);
    __syncthreads();                       // B2: buf[pb] reusable
    if (t + 1 < NT) stage(pb, (t + 1) * 64);
    softmax1(cur1);                        // frP1(t); covers stage latency
  };

  // ---- prologue: tile 0 (-> A)
  stage(0, 0);
  __syncthreads();
  stage(1, 64);
  __builtin_amdgcn_s_setprio(1);
  qk_phase(0, accsA0, accsA1);
  __builtin_amdgcn_s_setprio(0);
  softmax1(accsA1);                        // frP1(0)

  for (int tt = 1; tt < NT; tt += 2) {
    body(tt, accsB0, accsB1, accsA0);      // odd tile -> B, consumes A0
    if (tt + 1 < NT) body(tt + 1, accsA0, accsA1, accsB0);  // even -> A
  }
  // tail: tile NT-1 (= 31, odd -> B). frP1(31) done in its body; finish strip0.
  softmax0(accsB0);                        // frP0(31)
  __builtin_amdgcn_s_setprio(1);
  pv_phase(1);                             // V of tile 31 in buf[1]
  __builtin_amdgcn_s_setprio(0);

  // epilogue: both strips
#pragma unroll
  for (int r = 0; r < 4; ++r) {
    const float li0 = 1.f / acc_l0[r];
    const float li1 = 1.f / acc_l1[r];
    const int tq = q0 + w * 32 + 4 * g + r;
    unsigned short* d0 = attnoT + ((size_t)b * Tt + tq) * Cc + h * 64 + il;
    unsigned short* d1 = attnoT + ((size_t)b * Tt + tq + 16) * Cc + h * 64 + il;
#pragma unroll
    for (int j = 0; j < 4; ++j) {
      d0[j * 16] = f2bf(acco0[j][r] * li0);
      d1[j * 16] = f2bf(acco1[j][r] * li1);
    }
  }
}

// ---------------------------------------------------------------------------
extern "C" void kernel_launch(void* const* d_in, const int* in_sizes, int n_in,
                              void* d_out, int out_size, void* d_ws, size_t ws_size,
                              hipStream_t stream) {
  const float* x = (const float*)d_in[0];
  const float* gamma = (const float*)d_in[1];
  const float* beta = (const float*)d_in[2];
  const float* w_qkv = (const float*)d_in[3];
  const float* b_qkv = (const float*)d_in[4];
  const float* w_proj = (const float*)d_in[5];
  const float* b_proj = (const float*)d_in[6];
  float* out = (float*)d_out;

  char* p = (char*)d_ws;
  float* part = (float*)p;                   p += 2048 * sizeof(float);
  unsigned short* hT = (unsigned short*)p;   p += (size_t)Bb * Tt * Cc * 2;
  unsigned short* wq = (unsigned short*)p;   p += (size_t)3 * Cc * Cc * 2;
  unsigned short* wp = (unsigned short*)p;   p += (size_t)Cc * Cc * 2;
  unsigned short* qkvc = (unsigned short*)p; p += (size_t)Bb * 3 * Cc * Tt * 2;
  unsigned short* qkt = (unsigned short*)p;  p += (size_t)Bb * Hh * 2 * Tt * 64 * 2;
  unsigned short* attnoT = (unsigned short*)p;

  const int n4q = 3 * Cc * Cc / 4, n4p = Cc * Cc / 4;

  gn_part<<<dim3(1024), 256, 0, stream>>>(x, part);
  norm_trans<<<dim3(Tt / 64, Cc / 64, Bb), 256, 0, stream>>>(x, part, gamma, beta, hT);
  cvt_bf16_2<<<dim3((n4q + n4p + 255) / 256), 256, 0, stream>>>(w_qkv, wq, n4q, w_proj, wp, n4p);
  gemm_mfma<0, 128><<<dim3(Tt / 128, (3 * Cc) / 128, Bb), 256, 0, stream>>>(
      wq, hT, b_qkv, nullptr, qkvc, nullptr, qkt, 3 * Cc);
  attn_mfma10<<<dim3(512), 256, 0, stream>>>(qkt, qkvc, attnoT);
  gemm_mfma<1, 64><<<dim3(Tt / 128, Cc / 64, Bb), 256, 0, stream>>>(
      wp, attnoT, b_proj, x, nullptr, out, nullptr, Cc);
}

// Round 15
// 91.248 us; speedup vs baseline: 1.3683x; 1.0172x over previous
//
#include <hip/hip_runtime.h>
#include <hip/hip_bf16.h>
#include <math.h>
#include <stdint.h>

// Problem constants: B=4, C=512, T=2048, H=8, dh=64, G=32
#define Bb 4
#define Cc 512
#define Tt 2048
#define Hh 8

typedef __attribute__((ext_vector_type(8))) short short8;   // 8 bf16 (4 VGPR) MFMA operand
typedef __attribute__((ext_vector_type(4))) float f32x4;    // MFMA accumulator
typedef __attribute__((ext_vector_type(8))) unsigned short u16x8;

__device__ __forceinline__ unsigned short f2bf(float f) {
  __hip_bfloat16 h = __float2bfloat16(f);
  unsigned short u;
  __builtin_memcpy(&u, &h, 2);
  return u;
}
__device__ __forceinline__ float bf2f(unsigned short u) {
  union { uint32_t i; float f; } v;
  v.i = (uint32_t)u << 16;
  return v.f;
}

__device__ __forceinline__ void async16(const void* g, void* l) {
  __builtin_amdgcn_global_load_lds(
      (const __attribute__((address_space(1))) uint32_t*)g,
      (__attribute__((address_space(3))) uint32_t*)l, 16, 0, 0);
}

// ---------------------------------------------------------------------------
// K1: fused GroupNorm partial sums + weight fp32->bf16 convert.
// Blocks [0,1024): gn_part (block = 4096 floats of x).
// Blocks [1024,2048): cvt of w_qkv|w_proj (1024 blocks x 256 float4 exactly).
// Branch is block-uniform.
// ---------------------------------------------------------------------------
__global__ __launch_bounds__(256) void gn_cvt(const float* __restrict__ x,
                                              float* __restrict__ part,
                                              const float* __restrict__ wq_f,
                                              unsigned short* __restrict__ wq_b,
                                              int n4q,
                                              const float* __restrict__ wp_f,
                                              unsigned short* __restrict__ wp_b) {
  const int blk = blockIdx.x;
  const int tid = threadIdx.x;
  if (blk < 1024) {
    const size_t base = (size_t)blk * 4096;
    float s = 0.f, ss = 0.f;
#pragma unroll
    for (int k = 0; k < 4; ++k) {
      const float4 v = *(const float4*)(x + base + (size_t)(k * 256 + tid) * 4);
      s += v.x + v.y + v.z + v.w;
      ss += v.x * v.x + v.y * v.y + v.z * v.z + v.w * v.w;
    }
#pragma unroll
    for (int off = 32; off >= 1; off >>= 1) {
      s += __shfl_down(s, off);
      ss += __shfl_down(ss, off);
    }
    __shared__ float rs[4], rss[4];
    const int wid = tid >> 6;
    if ((tid & 63) == 0) { rs[wid] = s; rss[wid] = ss; }
    __syncthreads();
    if (tid == 0) {
      part[blk * 2] = rs[0] + rs[1] + rs[2] + rs[3];
      part[blk * 2 + 1] = rss[0] + rss[1] + rss[2] + rss[3];
    }
  } else {
    const int i = (blk - 1024) * 256 + tid;
    const float* in;
    unsigned short* out;
    int idx;
    if (i < n4q) {
      in = wq_f; out = wq_b; idx = i;
    } else {
      in = wp_f; out = wp_b; idx = i - n4q;
    }
    const float4 v = *(const float4*)(in + (size_t)idx * 4);
    ushort4 o;
    o.x = f2bf(v.x); o.y = f2bf(v.y); o.z = f2bf(v.z); o.w = f2bf(v.w);
    *(ushort4*)(out + (size_t)idx * 4) = o;
  }
}

// ---------------------------------------------------------------------------
// K2: normalize + convert + transpose: x fp32 [b][c][t] -> hT bf16 [b][t][c].
// Group stats reduced inline from part (8 partials/group, L2-hot).
// ---------------------------------------------------------------------------
__global__ __launch_bounds__(256) void norm_trans(const float* __restrict__ x,
                                                  const float* __restrict__ part,
                                                  const float* __restrict__ gamma,
                                                  const float* __restrict__ beta,
                                                  unsigned short* __restrict__ hT) {
  __shared__ unsigned short Tl[64][72];
  const int tid = threadIdx.x;
  const int b = blockIdx.z, c0 = blockIdx.y * 64, t0 = blockIdx.x * 64;
  const int cl = tid >> 2, j16 = (tid & 3) * 16;
  const int c = c0 + cl;
  const int grp = c >> 4;
  float s = 0.f, ss = 0.f;
#pragma unroll
  for (int i = 0; i < 8; ++i) {
    s += part[(b * 256 + grp * 8 + i) * 2];
    ss += part[(b * 256 + grp * 8 + i) * 2 + 1];
  }
  const float mean = s * (1.f / 32768.f);
  const float rstd = rsqrtf(ss * (1.f / 32768.f) - mean * mean + 1e-5f);
  const float ga = gamma[c] * rstd;
  const float be = beta[c] - mean * ga;
  const float* src = x + ((size_t)b * Cc + c) * Tt + t0 + j16;
#pragma unroll
  for (int q = 0; q < 4; ++q) {
    const float4 v = *(const float4*)(src + q * 4);
    Tl[j16 + q * 4 + 0][cl] = f2bf(v.x * ga + be);
    Tl[j16 + q * 4 + 1][cl] = f2bf(v.y * ga + be);
    Tl[j16 + q * 4 + 2][cl] = f2bf(v.z * ga + be);
    Tl[j16 + q * 4 + 3][cl] = f2bf(v.w * ga + be);
  }
  __syncthreads();
  const int tl = tid >> 2, i16 = (tid & 3) * 16;
  unsigned short* dst = hT + ((size_t)b * Tt + t0 + tl) * Cc + c0 + i16;
  *(u16x8*)dst = *(const u16x8*)&Tl[tl][i16];
  *(u16x8*)(dst + 8) = *(const u16x8*)&Tl[tl][i16 + 8];
}

// ---------------------------------------------------------------------------
// K5: bf16 MFMA GEMM, BM x 128 tile, BK=32 per buffer, DOUBLE-BUFFERED
// (T3 minimum 2-phase). LDS unchanged vs single-buffer BK=64.
// MODE 0 (QKV): V rows -> channel-major bf16 qkvc; Q/K rows -> token-major
//   qkt via per-wave LDS transpose scratch aliased onto dead staging LDS.
//   Q pre-scaled by 0.125*log2e.
// MODE 1 (proj): fp32 out + residual.
// ---------------------------------------------------------------------------
template <int MODE, int BM>
__global__ __launch_bounds__(256) void gemm_mfma(const unsigned short* __restrict__ A,
                                                 const unsigned short* __restrict__ Bt,
                                                 const float* __restrict__ bias,
                                                 const float* __restrict__ res,
                                                 unsigned short* __restrict__ outb,
                                                 float* __restrict__ outf,
                                                 unsigned short* __restrict__ qkt,
                                                 int M) {
  constexpr int NA = BM / 32;  // A-frags per wave
  constexpr int BUFSZ = (BM + 128) * 32;  // shorts per buffer (A | B)
  __shared__ unsigned short SMEM[2][BUFSZ];
  const int tid = threadIdx.x;
  const int n0 = blockIdx.x * 128, m0 = blockIdx.y * BM;
  const size_t z = blockIdx.z;
  const int l = tid & 63, il = l & 15, g = l >> 4;
  const int w = tid >> 6;
  const int wm = (w >> 1) * (BM / 2), wn = (w & 1) * 64;

  const unsigned short* Bz = Bt + z * (size_t)Tt * Cc;
  const unsigned short* Ap = A + (size_t)(m0 + (tid >> 2)) * Cc + (tid & 3) * 8;
  const unsigned short* Bp = Bz + (size_t)(n0 + (tid >> 2)) * Cc + (tid & 3) * 8;

  f32x4 acc[NA][4] = {};

  auto stageg = [&](int buf, int k0) {
    char* ldsA = (char*)&SMEM[buf][0] + w * 1024;
    char* ldsB = (char*)&SMEM[buf][BM * 32] + w * 1024;
    async16(Ap + k0, ldsA);
    if (BM == 128) async16(Ap + (size_t)64 * Cc + k0, ldsA + 4096);
    async16(Bp + k0, ldsB);
    async16(Bp + (size_t)64 * Cc + k0, ldsB + 4096);
  };

  auto compute = [&](int buf) {
    const unsigned short* Al = &SMEM[buf][0];
    const unsigned short* Bl = &SMEM[buf][BM * 32];
    short8 af[NA], bf[4];
#pragma unroll
    for (int i = 0; i < NA; ++i)
      af[i] = *(const short8*)(Al + (wm + i * 16 + il) * 32 + g * 8);
#pragma unroll
    for (int j = 0; j < 4; ++j)
      bf[j] = *(const short8*)(Bl + (wn + j * 16 + il) * 32 + g * 8);
    __builtin_amdgcn_s_setprio(1);
#pragma unroll
    for (int i = 0; i < NA; ++i)
#pragma unroll
      for (int j = 0; j < 4; ++j)
        acc[i][j] = __builtin_amdgcn_mfma_f32_16x16x32_bf16(af[i], bf[j], acc[i][j], 0, 0, 0);
    __builtin_amdgcn_s_setprio(0);
  };

  // T3 2-phase: stage next chunk before computing current; one sync/iter.
  stageg(0, 0);
  __syncthreads();
  int buf = 0;
  for (int k0 = 0; k0 < Cc; k0 += 32) {
    if (k0 + 32 < Cc) stageg(buf ^ 1, k0 + 32);
    compute(buf);
    __syncthreads();  // drains stage loads; releases computed buffer
    buf ^= 1;
  }

  if (MODE == 1) {
#pragma unroll
    for (int i = 0; i < NA; ++i) {
#pragma unroll
      for (int r = 0; r < 4; ++r) {
        const int m = m0 + wm + i * 16 + 4 * g + r;
        const float bv = bias[m];
#pragma unroll
        for (int j = 0; j < 4; ++j) {
          const int n = n0 + wn + j * 16 + il;
          const size_t idx = (z * (size_t)M + m) * Tt + n;
          outf[idx] = acc[i][j][r] + bv + res[idx];
        }
      }
    }
  } else {
    const int r0 = m0 + wm;
    const int sec = (r0 % 192) >> 6;  // 0=Q, 1=K, 2=V
    const int hh = r0 / 192;
    if (sec == 2) {
#pragma unroll
      for (int i = 0; i < 4; ++i) {
#pragma unroll
        for (int r = 0; r < 4; ++r) {
          const int m = r0 + i * 16 + 4 * g + r;
          const float bv = bias[m];
#pragma unroll
          for (int j = 0; j < 4; ++j) {
            const int n = n0 + wn + j * 16 + il;
            outb[(z * (size_t)M + m) * Tt + n] = f2bf(acc[i][j][r] + bv);
          }
        }
      }
    } else {
      // Q/K: token-major via per-wave scratch aliased onto dead staging LDS.
      unsigned short (*Sc)[32][72] = (unsigned short(*)[32][72])&SMEM[0][0];
      const float qs = (sec == 0) ? 0.125f * 1.44269504f : 1.0f;
      const size_t obase = ((size_t)(z * (Hh * 2)) + hh * 2 + sec) * Tt;
#pragma unroll
      for (int hf = 0; hf < 2; ++hf) {
#pragma unroll
        for (int i = 0; i < 4; ++i) {
          const int mloc = i * 16 + 4 * g;
          const float b0 = bias[r0 + mloc + 0];
          const float b1 = bias[r0 + mloc + 1];
          const float b2 = bias[r0 + mloc + 2];
          const float b3 = bias[r0 + mloc + 3];
#pragma unroll
          for (int j2 = 0; j2 < 2; ++j2) {
            const int j = hf * 2 + j2;
            ushort4 pkk;
            pkk.x = f2bf((acc[i][j][0] + b0) * qs);
            pkk.y = f2bf((acc[i][j][1] + b1) * qs);
            pkk.z = f2bf((acc[i][j][2] + b2) * qs);
            pkk.w = f2bf((acc[i][j][3] + b3) * qs);
            *(ushort4*)&Sc[w][j2 * 16 + il][mloc] = pkk;
          }
        }
        asm volatile("s_waitcnt lgkmcnt(0)" ::: "memory");
#pragma unroll
        for (int it = 0; it < 4; ++it) {
          const int row = it * 8 + (l >> 3);
          const int mcol = (l & 7) * 8;
          const u16x8 vv = *(const u16x8*)&Sc[w][row][mcol];
          const int tg = n0 + wn + hf * 32 + row;
          *(u16x8*)(qkt + (obase + tg) * 64 + mcol) = vv;
        }
        asm volatile("s_waitcnt lgkmcnt(0)" ::: "memory");
      }
    }
  }
}

// ---------------------------------------------------------------------------
// K6: MFMA flash attention v10 — EXACT R12/R14-passing kernel.
// Dual q-strips per wave (QBLK=128, shared kf/vf LDS reads), cross-tile
// softmax pipelining (strip0's softmax(t-1) woven into QK(t) MFMA region,
// standard subtract form; strip1 fast form post-stage), 2-buffer K/V,
// two __syncthreads per iter. Grid 512, XCD-swizzled, launch_bounds(256,2).
// ---------------------------------------------------------------------------
__global__ __launch_bounds__(256, 2) void attn_mfma10(const unsigned short* __restrict__ qkt,
                                                      const unsigned short* __restrict__ qkvc,
                                                      unsigned short* __restrict__ attnoT) {
  __shared__ unsigned short KVs[2][2][64 * 64];  // [buf][K/V][row*64+col] swizzled

  const int tid = threadIdx.x;
  const int w = tid >> 6, l = tid & 63, il = l & 15, g = l >> 4;

  // XCD swizzle (512 % 8 == 0 -> bijective)
  const int bid = blockIdx.x;
  const int swz = (bid & 7) * 64 + (bid >> 3);
  const int bh = swz >> 4, qt = swz & 15;
  const int b = bh >> 3, h = bh & 7;
  const int q0 = qt * 128;

  const unsigned short* Qb = qkt + (size_t)(bh * 2) * Tt * 64;
  const char* Kb = (const char*)(Qb + (size_t)Tt * 64);
  const char* Vb = (const char*)(qkvc + ((size_t)b * (3 * Cc) + h * 192 + 128) * Tt);

  short8 qf0[2], qf1[2];
  {
    const unsigned short* qp = Qb + (size_t)(q0 + w * 32 + il) * 64 + g * 8;
    qf0[0] = *(const short8*)qp;
    qf0[1] = *(const short8*)(qp + 32);
    qf1[0] = *(const short8*)(qp + 16 * 64);
    qf1[1] = *(const short8*)(qp + 16 * 64 + 32);
  }

  union { uint32_t u[4]; short8 v; } ones;
  ones.u[0] = ones.u[1] = ones.u[2] = ones.u[3] = 0x3F803F80u;

  float m_run0 = 0.f, m_run1 = 0.f;       // per-strip wave-uniform, log2 domain
  f32x4 acco0[4] = {}, acco1[4] = {};     // O[q=4g+r][d=j*16+il] per strip
  f32x4 acc_l0 = {}, acc_l1 = {};         // l[q=4g+r] per strip
  uint32_t frP0[2][4], frP1[2][4];        // P as PV A-fragments

  // ping-pong score tiles (even tiles -> A, odd -> B); static names (rule #20)
  f32x4 accsA0[4], accsA1[4], accsB0[4], accsB1[4];

  const int srow = w * 16 + (l >> 3);
  const int scol = ((l & 7) ^ (l >> 3)) << 4;

  auto stage = [&](int buf, int s0) {
    char* kd = (char*)&KVs[buf][0][0] + w * 2048;
    char* vd = (char*)&KVs[buf][1][0] + w * 2048;
    async16(Kb + (size_t)(s0 + srow) * 128 + scol, kd);
    async16(Kb + (size_t)(s0 + srow + 8) * 128 + scol, kd + 1024);
    async16(Vb + (size_t)srow * (Tt * 2) + (size_t)s0 * 2 + scol, vd);
    async16(Vb + (size_t)(srow + 8) * (Tt * 2) + (size_t)s0 * 2 + scol, vd + 1024);
  };

  // QK into the given tile set: strip0 init 0 (absolute scores), strip1 init -m_run1.
  auto qk_phase = [&](int buf, f32x4 (&a0)[4], f32x4 (&a1)[4]) {
    const float nm1 = -m_run1;
#pragma unroll
    for (int i = 0; i < 4; ++i) {
      a0[i][0] = 0.f; a0[i][1] = 0.f; a0[i][2] = 0.f; a0[i][3] = 0.f;
      a1[i][0] = nm1; a1[i][1] = nm1; a1[i][2] = nm1; a1[i][3] = nm1;
    }
    const unsigned short* Kc = &KVs[buf][0][0];
#pragma unroll
    for (int ks = 0; ks < 2; ++ks) {
#pragma unroll
      for (int i = 0; i < 4; ++i) {
        const short8 kf =
            *(const short8*)(Kc + (i * 16 + il) * 64 + ((((ks << 2) + g) ^ (il & 7)) << 3));
        a0[i] = __builtin_amdgcn_mfma_f32_16x16x32_bf16(kf, qf0[ks], a0[i], 0, 0, 0);
        a1[i] = __builtin_amdgcn_mfma_f32_16x16x32_bf16(kf, qf1[ks], a1[i], 0, 0, 0);
      }
    }
  };

  auto pv_phase = [&](int buf) {
#pragma unroll
    for (int ks = 0; ks < 2; ++ks) {
      union { uint32_t u[4]; short8 v; } fu0, fu1;
      fu0.u[0] = frP0[ks][0]; fu0.u[1] = frP0[ks][1];
      fu0.u[2] = frP0[ks][2]; fu0.u[3] = frP0[ks][3];
      fu1.u[0] = frP1[ks][0]; fu1.u[1] = frP1[ks][1];
      fu1.u[2] = frP1[ks][2]; fu1.u[3] = frP1[ks][3];
#pragma unroll
      for (int j = 0; j < 4; ++j) {
        const short8 vf =
            *(const short8*)(&KVs[buf][1][0] + (j * 16 + il) * 64 + ((((ks << 2) + g) ^ (il & 7)) << 3));
        acco0[j] = __builtin_amdgcn_mfma_f32_16x16x32_bf16(fu0.v, vf, acco0[j], 0, 0, 0);
        acco1[j] = __builtin_amdgcn_mfma_f32_16x16x32_bf16(fu1.v, vf, acco1[j], 0, 0, 0);
      }
      acc_l0 = __builtin_amdgcn_mfma_f32_16x16x32_bf16(fu0.v, ones.v, acc_l0, 0, 0, 0);
      acc_l1 = __builtin_amdgcn_mfma_f32_16x16x32_bf16(fu1.v, ones.v, acc_l1, 0, 0, 0);
    }
  };

  // strip0: STANDARD subtract-form softmax (absolute scores).
  auto softmax0 = [&](f32x4 (&accs)[4]) {
    float pmax = fmaxf(fmaxf(fmaxf(accs[0][0], accs[0][1]), accs[0][2]), accs[0][3]);
    pmax = fmaxf(pmax, fmaxf(fmaxf(accs[1][0], accs[1][1]), fmaxf(accs[1][2], accs[1][3])));
    pmax = fmaxf(pmax, fmaxf(fmaxf(accs[2][0], accs[2][1]), fmaxf(accs[2][2], accs[2][3])));
    pmax = fmaxf(pmax, fmaxf(fmaxf(accs[3][0], accs[3][1]), fmaxf(accs[3][2], accs[3][3])));

    if (!__all(pmax <= m_run0 + 8.0f)) {
      float mx = pmax;
#pragma unroll
      for (int off = 1; off < 64; off <<= 1) mx = fmaxf(mx, __shfl_xor(mx, off));
      const float mnew = fmaxf(m_run0, mx);
      const float alpha = __builtin_amdgcn_exp2f(m_run0 - mnew);
      m_run0 = mnew;
#pragma unroll
      for (int j = 0; j < 4; ++j) acco0[j] = acco0[j] * alpha;
      acc_l0 = acc_l0 * alpha;
    }
    const float m0 = m_run0;
    uint32_t pk[4][2];
#pragma unroll
    for (int i = 0; i < 4; ++i) {
      const float p0 = __builtin_amdgcn_exp2f(accs[i][0] - m0);
      const float p1 = __builtin_amdgcn_exp2f(accs[i][1] - m0);
      const float p2 = __builtin_amdgcn_exp2f(accs[i][2] - m0);
      const float p3 = __builtin_amdgcn_exp2f(accs[i][3] - m0);
      asm("v_cvt_pk_bf16_f32 %0, %1, %2" : "=v"(pk[i][0]) : "v"(p0), "v"(p1));
      asm("v_cvt_pk_bf16_f32 %0, %1, %2" : "=v"(pk[i][1]) : "v"(p2), "v"(p3));
    }
#pragma unroll
    for (int ks = 0; ks < 2; ++ks) {
#pragma unroll
      for (int hh = 0; hh < 2; ++hh) {
        uint32_t a = pk[2 * ks][hh], bq = pk[2 * ks + 1][hh];
        asm("v_permlane32_swap_b32 %0, %1" : "+v"(a), "+v"(bq));
        asm("v_permlane16_swap_b32 %0, %1" : "+v"(a), "+v"(bq));
        frP0[ks][hh] = a;
        frP0[ks][2 + hh] = bq;
      }
    }
  };

  // strip1: fast form (accs pre-offset by -m_run1).
  auto softmax1 = [&](f32x4 (&accs)[4]) {
    float pmax = fmaxf(fmaxf(fmaxf(accs[0][0], accs[0][1]), accs[0][2]), accs[0][3]);
    pmax = fmaxf(pmax, fmaxf(fmaxf(accs[1][0], accs[1][1]), fmaxf(accs[1][2], accs[1][3])));
    pmax = fmaxf(pmax, fmaxf(fmaxf(accs[2][0], accs[2][1]), fmaxf(accs[2][2], accs[2][3])));
    pmax = fmaxf(pmax, fmaxf(fmaxf(accs[3][0], accs[3][1]), fmaxf(accs[3][2], accs[3][3])));

    uint32_t pk[4][2];
    if (!__all(pmax <= 8.0f)) {
      float mx = pmax;
#pragma unroll
      for (int off = 1; off < 64; off <<= 1) mx = fmaxf(mx, __shfl_xor(mx, off));
      const float alpha = __builtin_amdgcn_exp2f(-mx);
      m_run1 += mx;
#pragma unroll
      for (int j = 0; j < 4; ++j) acco1[j] = acco1[j] * alpha;
      acc_l1 = acc_l1 * alpha;
#pragma unroll
      for (int i = 0; i < 4; ++i) {
        const float p0 = __builtin_amdgcn_exp2f(accs[i][0] - mx);
        const float p1 = __builtin_amdgcn_exp2f(accs[i][1] - mx);
        const float p2 = __builtin_amdgcn_exp2f(accs[i][2] - mx);
        const float p3 = __builtin_amdgcn_exp2f(accs[i][3] - mx);
        asm("v_cvt_pk_bf16_f32 %0, %1, %2" : "=v"(pk[i][0]) : "v"(p0), "v"(p1));
        asm("v_cvt_pk_bf16_f32 %0, %1, %2" : "=v"(pk[i][1]) : "v"(p2), "v"(p3));
      }
    } else {
#pragma unroll
      for (int i = 0; i < 4; ++i) {
        const float p0 = __builtin_amdgcn_exp2f(accs[i][0]);
        const float p1 = __builtin_amdgcn_exp2f(accs[i][1]);
        const float p2 = __builtin_amdgcn_exp2f(accs[i][2]);
        const float p3 = __builtin_amdgcn_exp2f(accs[i][3]);
        asm("v_cvt_pk_bf16_f32 %0, %1, %2" : "=v"(pk[i][0]) : "v"(p0), "v"(p1));
        asm("v_cvt_pk_bf16_f32 %0, %1, %2" : "=v"(pk[i][1]) : "v"(p2), "v"(p3));
      }
    }
#pragma unroll
    for (int ks = 0; ks < 2; ++ks) {
#pragma unroll
      for (int hh = 0; hh < 2; ++hh) {
        uint32_t a = pk[2 * ks][hh], bq = pk[2 * ks + 1][hh];
        asm("v_permlane32_swap_b32 %0, %1" : "+v"(a), "+v"(bq));
        asm("v_permlane16_swap_b32 %0, %1" : "+v"(a), "+v"(bq));
        frP1[ks][hh] = a;
        frP1[ks][2 + hh] = bq;
      }
    }
  };

  const int NT = Tt / 64;

  // Iter body: QK(t)->cur ; softmax0(prev tile strip0) woven into QK region;
  // PV(t-1); B2; stage(t+1); softmax1(cur tile strip1).
  auto body = [&](int t, f32x4 (&cur0)[4], f32x4 (&cur1)[4], f32x4 (&prv0)[4]) {
    const int cb = t & 1, pb = cb ^ 1;
    __syncthreads();                       // B1: stage(t) drained
    __builtin_amdgcn_s_setprio(1);
    qk_phase(cb, cur0, cur1);              // 16 MFMAs (tile t)
    softmax0(prv0);                        // VALU, independent -> weaves; frP0(t-1)
    pv_phase(pb);                          // 20 MFMAs (tile t-1)
    __builtin_amdgcn_s_setprio(0);
    __syncthreads();                       // B2: buf[pb] reusable
    if (t + 1 < NT) stage(pb, (t + 1) * 64);
    softmax1(cur1);                        // frP1(t); covers stage latency
  };

  // ---- prologue: tile 0 (-> A)
  stage(0, 0);
  __syncthreads();
  stage(1, 64);
  __builtin_amdgcn_s_setprio(1);
  qk_phase(0, accsA0, accsA1);
  __builtin_amdgcn_s_setprio(0);
  softmax1(accsA1);                        // frP1(0)

  for (int tt = 1; tt < NT; tt += 2) {
    body(tt, accsB0, accsB1, accsA0);      // odd tile -> B, consumes A0
    if (tt + 1 < NT) body(tt + 1, accsA0, accsA1, accsB0);  // even -> A
  }
  // tail: tile NT-1 (= 31, odd -> B). frP1(31) done in its body; finish strip0.
  softmax0(accsB0);                        // frP0(31)
  __builtin_amdgcn_s_setprio(1);
  pv_phase(1);                             // V of tile 31 in buf[1]
  __builtin_amdgcn_s_setprio(0);

  // epilogue: both strips
#pragma unroll
  for (int r = 0; r < 4; ++r) {
    const float li0 = 1.f / acc_l0[r];
    const float li1 = 1.f / acc_l1[r];
    const int tq = q0 + w * 32 + 4 * g + r;
    unsigned short* d0 = attnoT + ((size_t)b * Tt + tq) * Cc + h * 64 + il;
    unsigned short* d1 = attnoT + ((size_t)b * Tt + tq + 16) * Cc + h * 64 + il;
#pragma unroll
    for (int j = 0; j < 4; ++j) {
      d0[j * 16] = f2bf(acco0[j][r] * li0);
      d1[j * 16] = f2bf(acco1[j][r] * li1);
    }
  }
}

// ---------------------------------------------------------------------------
extern "C" void kernel_launch(void* const* d_in, const int* in_sizes, int n_in,
                              void* d_out, int out_size, void* d_ws, size_t ws_size,
                              hipStream_t stream) {
  const float* x = (const float*)d_in[0];
  const float* gamma = (const float*)d_in[1];
  const float* beta = (const float*)d_in[2];
  const float* w_qkv = (const float*)d_in[3];
  const float* b_qkv = (const float*)d_in[4];
  const float* w_proj = (const float*)d_in[5];
  const float* b_proj = (const float*)d_in[6];
  float* out = (float*)d_out;

  char* p = (char*)d_ws;
  float* part = (float*)p;                   p += 2048 * sizeof(float);
  unsigned short* hT = (unsigned short*)p;   p += (size_t)Bb * Tt * Cc * 2;
  unsigned short* wq = (unsigned short*)p;   p += (size_t)3 * Cc * Cc * 2;
  unsigned short* wp = (unsigned short*)p;   p += (size_t)Cc * Cc * 2;
  unsigned short* qkvc = (unsigned short*)p; p += (size_t)Bb * 3 * Cc * Tt * 2;
  unsigned short* qkt = (unsigned short*)p;  p += (size_t)Bb * Hh * 2 * Tt * 64 * 2;
  unsigned short* attnoT = (unsigned short*)p;

  const int n4q = 3 * Cc * Cc / 4;  // 196608; cvt blocks: (n4q + n4p)/256 = 1024

  gn_cvt<<<dim3(2048), 256, 0, stream>>>(x, part, w_qkv, wq, n4q, w_proj, wp);
  norm_trans<<<dim3(Tt / 64, Cc / 64, Bb), 256, 0, stream>>>(x, part, gamma, beta, hT);
  gemm_mfma<0, 128><<<dim3(Tt / 128, (3 * Cc) / 128, Bb), 256, 0, stream>>>(
      wq, hT, b_qkv, nullptr, qkvc, nullptr, qkt, 3 * Cc);
  attn_mfma10<<<dim3(512), 256, 0, stream>>>(qkt, qkvc, attnoT);
  gemm_mfma<1, 64><<<dim3(Tt / 128, Cc / 64, Bb), 256, 0, stream>>>(
      wp, attnoT, b_proj, x, nullptr, out, nullptr, Cc);
}

// Round 17
// 90.696 us; speedup vs baseline: 1.3766x; 1.0061x over previous
//
#include <hip/hip_runtime.h>
#include <hip/hip_bf16.h>
#include <math.h>
#include <stdint.h>

// Problem constants: B=4, C=512, T=2048, H=8, dh=64, G=32
#define Bb 4
#define Cc 512
#define Tt 2048
#define Hh 8

typedef __attribute__((ext_vector_type(8))) short short8;   // 8 bf16 (4 VGPR) MFMA operand
typedef __attribute__((ext_vector_type(4))) float f32x4;    // MFMA accumulator
typedef __attribute__((ext_vector_type(8))) unsigned short u16x8;

__device__ __forceinline__ unsigned short f2bf(float f) {
  __hip_bfloat16 h = __float2bfloat16(f);
  unsigned short u;
  __builtin_memcpy(&u, &h, 2);
  return u;
}
__device__ __forceinline__ float bf2f(unsigned short u) {
  union { uint32_t i; float f; } v;
  v.i = (uint32_t)u << 16;
  return v.f;
}

__device__ __forceinline__ void async16(const void* g, void* l) {
  __builtin_amdgcn_global_load_lds(
      (const __attribute__((address_space(1))) uint32_t*)g,
      (__attribute__((address_space(3))) uint32_t*)l, 16, 0, 0);
}

// ---------------------------------------------------------------------------
// K1: fused GroupNorm partial sums + weight fp32->bf16 convert.
// Blocks [0,1024): gn_part. Blocks [1024,2048): weight cvt. Block-uniform.
// ---------------------------------------------------------------------------
__global__ __launch_bounds__(256) void gn_cvt(const float* __restrict__ x,
                                              float* __restrict__ part,
                                              const float* __restrict__ wq_f,
                                              unsigned short* __restrict__ wq_b,
                                              int n4q,
                                              const float* __restrict__ wp_f,
                                              unsigned short* __restrict__ wp_b) {
  const int blk = blockIdx.x;
  const int tid = threadIdx.x;
  if (blk < 1024) {
    const size_t base = (size_t)blk * 4096;
    float s = 0.f, ss = 0.f;
#pragma unroll
    for (int k = 0; k < 4; ++k) {
      const float4 v = *(const float4*)(x + base + (size_t)(k * 256 + tid) * 4);
      s += v.x + v.y + v.z + v.w;
      ss += v.x * v.x + v.y * v.y + v.z * v.z + v.w * v.w;
    }
#pragma unroll
    for (int off = 32; off >= 1; off >>= 1) {
      s += __shfl_down(s, off);
      ss += __shfl_down(ss, off);
    }
    __shared__ float rs[4], rss[4];
    const int wid = tid >> 6;
    if ((tid & 63) == 0) { rs[wid] = s; rss[wid] = ss; }
    __syncthreads();
    if (tid == 0) {
      part[blk * 2] = rs[0] + rs[1] + rs[2] + rs[3];
      part[blk * 2 + 1] = rss[0] + rss[1] + rss[2] + rss[3];
    }
  } else {
    const int i = (blk - 1024) * 256 + tid;
    const float* in;
    unsigned short* out;
    int idx;
    if (i < n4q) {
      in = wq_f; out = wq_b; idx = i;
    } else {
      in = wp_f; out = wp_b; idx = i - n4q;
    }
    const float4 v = *(const float4*)(in + (size_t)idx * 4);
    ushort4 o;
    o.x = f2bf(v.x); o.y = f2bf(v.y); o.z = f2bf(v.z); o.w = f2bf(v.w);
    *(ushort4*)(out + (size_t)idx * 4) = o;
  }
}

// ---------------------------------------------------------------------------
// K2: normalize + convert + transpose: x fp32 [b][c][t] -> hT bf16 [b][t][c].
// ---------------------------------------------------------------------------
__global__ __launch_bounds__(256) void norm_trans(const float* __restrict__ x,
                                                  const float* __restrict__ part,
                                                  const float* __restrict__ gamma,
                                                  const float* __restrict__ beta,
                                                  unsigned short* __restrict__ hT) {
  __shared__ unsigned short Tl[64][72];
  const int tid = threadIdx.x;
  const int b = blockIdx.z, c0 = blockIdx.y * 64, t0 = blockIdx.x * 64;
  const int cl = tid >> 2, j16 = (tid & 3) * 16;
  const int c = c0 + cl;
  const int grp = c >> 4;
  float s = 0.f, ss = 0.f;
#pragma unroll
  for (int i = 0; i < 8; ++i) {
    s += part[(b * 256 + grp * 8 + i) * 2];
    ss += part[(b * 256 + grp * 8 + i) * 2 + 1];
  }
  const float mean = s * (1.f / 32768.f);
  const float rstd = rsqrtf(ss * (1.f / 32768.f) - mean * mean + 1e-5f);
  const float ga = gamma[c] * rstd;
  const float be = beta[c] - mean * ga;
  const float* src = x + ((size_t)b * Cc + c) * Tt + t0 + j16;
#pragma unroll
  for (int q = 0; q < 4; ++q) {
    const float4 v = *(const float4*)(src + q * 4);
    Tl[j16 + q * 4 + 0][cl] = f2bf(v.x * ga + be);
    Tl[j16 + q * 4 + 1][cl] = f2bf(v.y * ga + be);
    Tl[j16 + q * 4 + 2][cl] = f2bf(v.z * ga + be);
    Tl[j16 + q * 4 + 3][cl] = f2bf(v.w * ga + be);
  }
  __syncthreads();
  const int tl = tid >> 2, i16 = (tid & 3) * 16;
  unsigned short* dst = hT + ((size_t)b * Tt + t0 + tl) * Cc + c0 + i16;
  *(u16x8*)dst = *(const u16x8*)&Tl[tl][i16];
  *(u16x8*)(dst + 8) = *(const u16x8*)&Tl[tl][i16 + 8];
}

// ---------------------------------------------------------------------------
// K5: bf16 MFMA GEMM, BM x 128 tile, BK=32 per buffer, DOUBLE-BUFFERED
// (T3 minimum 2-phase). MODE 0 (QKV): V rows channel-major; Q/K token-major
// via per-wave scratch aliased onto dead staging LDS; Q pre-scaled by
// 0.125*log2e. MODE 1 (proj): fp32 out + residual.
// ---------------------------------------------------------------------------
template <int MODE, int BM>
__global__ __launch_bounds__(256) void gemm_mfma(const unsigned short* __restrict__ A,
                                                 const unsigned short* __restrict__ Bt,
                                                 const float* __restrict__ bias,
                                                 const float* __restrict__ res,
                                                 unsigned short* __restrict__ outb,
                                                 float* __restrict__ outf,
                                                 unsigned short* __restrict__ qkt,
                                                 int M) {
  constexpr int NA = BM / 32;  // A-frags per wave
  constexpr int BUFSZ = (BM + 128) * 32;  // shorts per buffer (A | B)
  __shared__ unsigned short SMEM[2][BUFSZ];
  const int tid = threadIdx.x;
  const int n0 = blockIdx.x * 128, m0 = blockIdx.y * BM;
  const size_t z = blockIdx.z;
  const int l = tid & 63, il = l & 15, g = l >> 4;
  const int w = tid >> 6;
  const int wm = (w >> 1) * (BM / 2), wn = (w & 1) * 64;

  const unsigned short* Bz = Bt + z * (size_t)Tt * Cc;
  const unsigned short* Ap = A + (size_t)(m0 + (tid >> 2)) * Cc + (tid & 3) * 8;
  const unsigned short* Bp = Bz + (size_t)(n0 + (tid >> 2)) * Cc + (tid & 3) * 8;

  f32x4 acc[NA][4] = {};

  auto stageg = [&](int buf, int k0) {
    char* ldsA = (char*)&SMEM[buf][0] + w * 1024;
    char* ldsB = (char*)&SMEM[buf][BM * 32] + w * 1024;
    async16(Ap + k0, ldsA);
    if (BM == 128) async16(Ap + (size_t)64 * Cc + k0, ldsA + 4096);
    async16(Bp + k0, ldsB);
    async16(Bp + (size_t)64 * Cc + k0, ldsB + 4096);
  };

  auto compute = [&](int buf) {
    const unsigned short* Al = &SMEM[buf][0];
    const unsigned short* Bl = &SMEM[buf][BM * 32];
    short8 af[NA], bf[4];
#pragma unroll
    for (int i = 0; i < NA; ++i)
      af[i] = *(const short8*)(Al + (wm + i * 16 + il) * 32 + g * 8);
#pragma unroll
    for (int j = 0; j < 4; ++j)
      bf[j] = *(const short8*)(Bl + (wn + j * 16 + il) * 32 + g * 8);
    __builtin_amdgcn_s_setprio(1);
#pragma unroll
    for (int i = 0; i < NA; ++i)
#pragma unroll
      for (int j = 0; j < 4; ++j)
        acc[i][j] = __builtin_amdgcn_mfma_f32_16x16x32_bf16(af[i], bf[j], acc[i][j], 0, 0, 0);
    __builtin_amdgcn_s_setprio(0);
  };

  // T3 2-phase: stage next chunk before computing current; one sync/iter.
  stageg(0, 0);
  __syncthreads();
  int buf = 0;
  for (int k0 = 0; k0 < Cc; k0 += 32) {
    if (k0 + 32 < Cc) stageg(buf ^ 1, k0 + 32);
    compute(buf);
    __syncthreads();  // drains stage loads; releases computed buffer
    buf ^= 1;
  }

  if (MODE == 1) {
#pragma unroll
    for (int i = 0; i < NA; ++i) {
#pragma unroll
      for (int r = 0; r < 4; ++r) {
        const int m = m0 + wm + i * 16 + 4 * g + r;
        const float bv = bias[m];
#pragma unroll
        for (int j = 0; j < 4; ++j) {
          const int n = n0 + wn + j * 16 + il;
          const size_t idx = (z * (size_t)M + m) * Tt + n;
          outf[idx] = acc[i][j][r] + bv + res[idx];
        }
      }
    }
  } else {
    const int r0 = m0 + wm;
    const int sec = (r0 % 192) >> 6;  // 0=Q, 1=K, 2=V
    const int hh = r0 / 192;
    if (sec == 2) {
#pragma unroll
      for (int i = 0; i < 4; ++i) {
#pragma unroll
        for (int r = 0; r < 4; ++r) {
          const int m = r0 + i * 16 + 4 * g + r;
          const float bv = bias[m];
#pragma unroll
          for (int j = 0; j < 4; ++j) {
            const int n = n0 + wn + j * 16 + il;
            outb[(z * (size_t)M + m) * Tt + n] = f2bf(acc[i][j][r] + bv);
          }
        }
      }
    } else {
      // Q/K: token-major via per-wave scratch aliased onto dead staging LDS.
      unsigned short (*Sc)[32][72] = (unsigned short(*)[32][72])&SMEM[0][0];
      const float qs = (sec == 0) ? 0.125f * 1.44269504f : 1.0f;
      const size_t obase = ((size_t)(z * (Hh * 2)) + hh * 2 + sec) * Tt;
#pragma unroll
      for (int hf = 0; hf < 2; ++hf) {
#pragma unroll
        for (int i = 0; i < 4; ++i) {
          const int mloc = i * 16 + 4 * g;
          const float b0 = bias[r0 + mloc + 0];
          const float b1 = bias[r0 + mloc + 1];
          const float b2 = bias[r0 + mloc + 2];
          const float b3 = bias[r0 + mloc + 3];
#pragma unroll
          for (int j2 = 0; j2 < 2; ++j2) {
            const int j = hf * 2 + j2;
            ushort4 pkk;
            pkk.x = f2bf((acc[i][j][0] + b0) * qs);
            pkk.y = f2bf((acc[i][j][1] + b1) * qs);
            pkk.z = f2bf((acc[i][j][2] + b2) * qs);
            pkk.w = f2bf((acc[i][j][3] + b3) * qs);
            *(ushort4*)&Sc[w][j2 * 16 + il][mloc] = pkk;
          }
        }
        asm volatile("s_waitcnt lgkmcnt(0)" ::: "memory");
#pragma unroll
        for (int it = 0; it < 4; ++it) {
          const int row = it * 8 + (l >> 3);
          const int mcol = (l & 7) * 8;
          const u16x8 vv = *(const u16x8*)&Sc[w][row][mcol];
          const int tg = n0 + wn + hf * 32 + row;
          *(u16x8*)(qkt + (obase + tg) * 64 + mcol) = vv;
        }
        asm volatile("s_waitcnt lgkmcnt(0)" ::: "memory");
      }
    }
  }
}

// ---------------------------------------------------------------------------
// K6: MFMA flash attention v10 — EXACT R12/R14/R15-passing kernel.
// Dual q-strips per wave (QBLK=128, shared kf/vf LDS reads), cross-tile
// softmax pipelining (strip0's softmax(t-1) woven into QK(t) MFMA region,
// standard subtract form; strip1 fast form post-stage), 2-buffer K/V,
// two __syncthreads per iter. Grid 512, XCD-swizzled, launch_bounds(256,2).
// NOTE: three restructure attempts (shared-coupling R10, 3-buffer
// single-barrier R13, paired-tile 4-buffer R16) all failed numerically with
// formally-sound barrier arguments — this exact structure is load-bearing.
// ---------------------------------------------------------------------------
__global__ __launch_bounds__(256, 2) void attn_mfma10(const unsigned short* __restrict__ qkt,
                                                      const unsigned short* __restrict__ qkvc,
                                                      unsigned short* __restrict__ attnoT) {
  __shared__ unsigned short KVs[2][2][64 * 64];  // [buf][K/V][row*64+col] swizzled

  const int tid = threadIdx.x;
  const int w = tid >> 6, l = tid & 63, il = l & 15, g = l >> 4;

  // XCD swizzle (512 % 8 == 0 -> bijective)
  const int bid = blockIdx.x;
  const int swz = (bid & 7) * 64 + (bid >> 3);
  const int bh = swz >> 4, qt = swz & 15;
  const int b = bh >> 3, h = bh & 7;
  const int q0 = qt * 128;

  const unsigned short* Qb = qkt + (size_t)(bh * 2) * Tt * 64;
  const char* Kb = (const char*)(Qb + (size_t)Tt * 64);
  const char* Vb = (const char*)(qkvc + ((size_t)b * (3 * Cc) + h * 192 + 128) * Tt);

  short8 qf0[2], qf1[2];
  {
    const unsigned short* qp = Qb + (size_t)(q0 + w * 32 + il) * 64 + g * 8;
    qf0[0] = *(const short8*)qp;
    qf0[1] = *(const short8*)(qp + 32);
    qf1[0] = *(const short8*)(qp + 16 * 64);
    qf1[1] = *(const short8*)(qp + 16 * 64 + 32);
  }

  union { uint32_t u[4]; short8 v; } ones;
  ones.u[0] = ones.u[1] = ones.u[2] = ones.u[3] = 0x3F803F80u;

  float m_run0 = 0.f, m_run1 = 0.f;       // per-strip wave-uniform, log2 domain
  f32x4 acco0[4] = {}, acco1[4] = {};     // O[q=4g+r][d=j*16+il] per strip
  f32x4 acc_l0 = {}, acc_l1 = {};         // l[q=4g+r] per strip
  uint32_t frP0[2][4], frP1[2][4];        // P as PV A-fragments

  // ping-pong score tiles (even tiles -> A, odd -> B); static names (rule #20)
  f32x4 accsA0[4], accsA1[4], accsB0[4], accsB1[4];

  const int srow = w * 16 + (l >> 3);
  const int scol = ((l & 7) ^ (l >> 3)) << 4;

  auto stage = [&](int buf, int s0) {
    char* kd = (char*)&KVs[buf][0][0] + w * 2048;
    char* vd = (char*)&KVs[buf][1][0] + w * 2048;
    async16(Kb + (size_t)(s0 + srow) * 128 + scol, kd);
    async16(Kb + (size_t)(s0 + srow + 8) * 128 + scol, kd + 1024);
    async16(Vb + (size_t)srow * (Tt * 2) + (size_t)s0 * 2 + scol, vd);
    async16(Vb + (size_t)(srow + 8) * (Tt * 2) + (size_t)s0 * 2 + scol, vd + 1024);
  };

  // QK into the given tile set: strip0 init 0 (absolute scores), strip1 init -m_run1.
  auto qk_phase = [&](int buf, f32x4 (&a0)[4], f32x4 (&a1)[4]) {
    const float nm1 = -m_run1;
#pragma unroll
    for (int i = 0; i < 4; ++i) {
      a0[i][0] = 0.f; a0[i][1] = 0.f; a0[i][2] = 0.f; a0[i][3] = 0.f;
      a1[i][0] = nm1; a1[i][1] = nm1; a1[i][2] = nm1; a1[i][3] = nm1;
    }
    const unsigned short* Kc = &KVs[buf][0][0];
#pragma unroll
    for (int ks = 0; ks < 2; ++ks) {
#pragma unroll
      for (int i = 0; i < 4; ++i) {
        const short8 kf =
            *(const short8*)(Kc + (i * 16 + il) * 64 + ((((ks << 2) + g) ^ (il & 7)) << 3));
        a0[i] = __builtin_amdgcn_mfma_f32_16x16x32_bf16(kf, qf0[ks], a0[i], 0, 0, 0);
        a1[i] = __builtin_amdgcn_mfma_f32_16x16x32_bf16(kf, qf1[ks], a1[i], 0, 0, 0);
      }
    }
  };

  auto pv_phase = [&](int buf) {
#pragma unroll
    for (int ks = 0; ks < 2; ++ks) {
      union { uint32_t u[4]; short8 v; } fu0, fu1;
      fu0.u[0] = frP0[ks][0]; fu0.u[1] = frP0[ks][1];
      fu0.u[2] = frP0[ks][2]; fu0.u[3] = frP0[ks][3];
      fu1.u[0] = frP1[ks][0]; fu1.u[1] = frP1[ks][1];
      fu1.u[2] = frP1[ks][2]; fu1.u[3] = frP1[ks][3];
#pragma unroll
      for (int j = 0; j < 4; ++j) {
        const short8 vf =
            *(const short8*)(&KVs[buf][1][0] + (j * 16 + il) * 64 + ((((ks << 2) + g) ^ (il & 7)) << 3));
        acco0[j] = __builtin_amdgcn_mfma_f32_16x16x32_bf16(fu0.v, vf, acco0[j], 0, 0, 0);
        acco1[j] = __builtin_amdgcn_mfma_f32_16x16x32_bf16(fu1.v, vf, acco1[j], 0, 0, 0);
      }
      acc_l0 = __builtin_amdgcn_mfma_f32_16x16x32_bf16(fu0.v, ones.v, acc_l0, 0, 0, 0);
      acc_l1 = __builtin_amdgcn_mfma_f32_16x16x32_bf16(fu1.v, ones.v, acc_l1, 0, 0, 0);
    }
  };

  // strip0: STANDARD subtract-form softmax (absolute scores).
  auto softmax0 = [&](f32x4 (&accs)[4]) {
    float pmax = fmaxf(fmaxf(fmaxf(accs[0][0], accs[0][1]), accs[0][2]), accs[0][3]);
    pmax = fmaxf(pmax, fmaxf(fmaxf(accs[1][0], accs[1][1]), fmaxf(accs[1][2], accs[1][3])));
    pmax = fmaxf(pmax, fmaxf(fmaxf(accs[2][0], accs[2][1]), fmaxf(accs[2][2], accs[2][3])));
    pmax = fmaxf(pmax, fmaxf(fmaxf(accs[3][0], accs[3][1]), fmaxf(accs[3][2], accs[3][3])));

    if (!__all(pmax <= m_run0 + 8.0f)) {
      float mx = pmax;
#pragma unroll
      for (int off = 1; off < 64; off <<= 1) mx = fmaxf(mx, __shfl_xor(mx, off));
      const float mnew = fmaxf(m_run0, mx);
      const float alpha = __builtin_amdgcn_exp2f(m_run0 - mnew);
      m_run0 = mnew;
#pragma unroll
      for (int j = 0; j < 4; ++j) acco0[j] = acco0[j] * alpha;
      acc_l0 = acc_l0 * alpha;
    }
    const float m0 = m_run0;
    uint32_t pk[4][2];
#pragma unroll
    for (int i = 0; i < 4; ++i) {
      const float p0 = __builtin_amdgcn_exp2f(accs[i][0] - m0);
      const float p1 = __builtin_amdgcn_exp2f(accs[i][1] - m0);
      const float p2 = __builtin_amdgcn_exp2f(accs[i][2] - m0);
      const float p3 = __builtin_amdgcn_exp2f(accs[i][3] - m0);
      asm("v_cvt_pk_bf16_f32 %0, %1, %2" : "=v"(pk[i][0]) : "v"(p0), "v"(p1));
      asm("v_cvt_pk_bf16_f32 %0, %1, %2" : "=v"(pk[i][1]) : "v"(p2), "v"(p3));
    }
#pragma unroll
    for (int ks = 0; ks < 2; ++ks) {
#pragma unroll
      for (int hh = 0; hh < 2; ++hh) {
        uint32_t a = pk[2 * ks][hh], bq = pk[2 * ks + 1][hh];
        asm("v_permlane32_swap_b32 %0, %1" : "+v"(a), "+v"(bq));
        asm("v_permlane16_swap_b32 %0, %1" : "+v"(a), "+v"(bq));
        frP0[ks][hh] = a;
        frP0[ks][2 + hh] = bq;
      }
    }
  };

  // strip1: fast form (accs pre-offset by -m_run1).
  auto softmax1 = [&](f32x4 (&accs)[4]) {
    float pmax = fmaxf(fmaxf(fmaxf(accs[0][0], accs[0][1]), accs[0][2]), accs[0][3]);
    pmax = fmaxf(pmax, fmaxf(fmaxf(accs[1][0], accs[1][1]), fmaxf(accs[1][2], accs[1][3])));
    pmax = fmaxf(pmax, fmaxf(fmaxf(accs[2][0], accs[2][1]), fmaxf(accs[2][2], accs[2][3])));
    pmax = fmaxf(pmax, fmaxf(fmaxf(accs[3][0], accs[3][1]), fmaxf(accs[3][2], accs[3][3])));

    uint32_t pk[4][2];
    if (!__all(pmax <= 8.0f)) {
      float mx = pmax;
#pragma unroll
      for (int off = 1; off < 64; off <<= 1) mx = fmaxf(mx, __shfl_xor(mx, off));
      const float alpha = __builtin_amdgcn_exp2f(-mx);
      m_run1 += mx;
#pragma unroll
      for (int j = 0; j < 4; ++j) acco1[j] = acco1[j] * alpha;
      acc_l1 = acc_l1 * alpha;
#pragma unroll
      for (int i = 0; i < 4; ++i) {
        const float p0 = __builtin_amdgcn_exp2f(accs[i][0] - mx);
        const float p1 = __builtin_amdgcn_exp2f(accs[i][1] - mx);
        const float p2 = __builtin_amdgcn_exp2f(accs[i][2] - mx);
        const float p3 = __builtin_amdgcn_exp2f(accs[i][3] - mx);
        asm("v_cvt_pk_bf16_f32 %0, %1, %2" : "=v"(pk[i][0]) : "v"(p0), "v"(p1));
        asm("v_cvt_pk_bf16_f32 %0, %1, %2" : "=v"(pk[i][1]) : "v"(p2), "v"(p3));
      }
    } else {
#pragma unroll
      for (int i = 0; i < 4; ++i) {
        const float p0 = __builtin_amdgcn_exp2f(accs[i][0]);
        const float p1 = __builtin_amdgcn_exp2f(accs[i][1]);
        const float p2 = __builtin_amdgcn_exp2f(accs[i][2]);
        const float p3 = __builtin_amdgcn_exp2f(accs[i][3]);
        asm("v_cvt_pk_bf16_f32 %0, %1, %2" : "=v"(pk[i][0]) : "v"(p0), "v"(p1));
        asm("v_cvt_pk_bf16_f32 %0, %1, %2" : "=v"(pk[i][1]) : "v"(p2), "v"(p3));
      }
    }
#pragma unroll
    for (int ks = 0; ks < 2; ++ks) {
#pragma unroll
      for (int hh = 0; hh < 2; ++hh) {
        uint32_t a = pk[2 * ks][hh], bq = pk[2 * ks + 1][hh];
        asm("v_permlane32_swap_b32 %0, %1" : "+v"(a), "+v"(bq));
        asm("v_permlane16_swap_b32 %0, %1" : "+v"(a), "+v"(bq));
        frP1[ks][hh] = a;
        frP1[ks][2 + hh] = bq;
      }
    }
  };

  const int NT = Tt / 64;

  // Iter body: QK(t)->cur ; softmax0(prev tile strip0) woven into QK region;
  // PV(t-1); B2; stage(t+1); softmax1(cur tile strip1).
  auto body = [&](int t, f32x4 (&cur0)[4], f32x4 (&cur1)[4], f32x4 (&prv0)[4]) {
    const int cb = t & 1, pb = cb ^ 1;
    __syncthreads();                       // B1: stage(t) drained
    __builtin_amdgcn_s_setprio(1);
    qk_phase(cb, cur0, cur1);              // 16 MFMAs (tile t)
    softmax0(prv0);                        // VALU, independent -> weaves; frP0(t-1)
    pv_phase(pb);                          // 20 MFMAs (tile t-1)
    __builtin_amdgcn_s_setprio(0);
    __syncthreads();                       // B2: buf[pb] reusable
    if (t + 1 < NT) stage(pb, (t + 1) * 64);
    softmax1(cur1);                        // frP1(t); covers stage latency
  };

  // ---- prologue: tile 0 (-> A)
  stage(0, 0);
  __syncthreads();
  stage(1, 64);
  __builtin_amdgcn_s_setprio(1);
  qk_phase(0, accsA0, accsA1);
  __builtin_amdgcn_s_setprio(0);
  softmax1(accsA1);                        // frP1(0)

  for (int tt = 1; tt < NT; tt += 2) {
    body(tt, accsB0, accsB1, accsA0);      // odd tile -> B, consumes A0
    if (tt + 1 < NT) body(tt + 1, accsA0, accsA1, accsB0);  // even -> A
  }
  // tail: tile NT-1 (= 31, odd -> B). frP1(31) done in its body; finish strip0.
  softmax0(accsB0);                        // frP0(31)
  __builtin_amdgcn_s_setprio(1);
  pv_phase(1);                             // V of tile 31 in buf[1]
  __builtin_amdgcn_s_setprio(0);

  // epilogue: both strips
#pragma unroll
  for (int r = 0; r < 4; ++r) {
    const float li0 = 1.f / acc_l0[r];
    const float li1 = 1.f / acc_l1[r];
    const int tq = q0 + w * 32 + 4 * g + r;
    unsigned short* d0 = attnoT + ((size_t)b * Tt + tq) * Cc + h * 64 + il;
    unsigned short* d1 = attnoT + ((size_t)b * Tt + tq + 16) * Cc + h * 64 + il;
#pragma unroll
    for (int j = 0; j < 4; ++j) {
      d0[j * 16] = f2bf(acco0[j][r] * li0);
      d1[j * 16] = f2bf(acco1[j][r] * li1);
    }
  }
}

// ---------------------------------------------------------------------------
extern "C" void kernel_launch(void* const* d_in, const int* in_sizes, int n_in,
                              void* d_out, int out_size, void* d_ws, size_t ws_size,
                              hipStream_t stream) {
  const float* x = (const float*)d_in[0];
  const float* gamma = (const float*)d_in[1];
  const float* beta = (const float*)d_in[2];
  const float* w_qkv = (const float*)d_in[3];
  const float* b_qkv = (const float*)d_in[4];
  const float* w_proj = (const float*)d_in[5];
  const float* b_proj = (const float*)d_in[6];
  float* out = (float*)d_out;

  char* p = (char*)d_ws;
  float* part = (float*)p;                   p += 2048 * sizeof(float);
  unsigned short* hT = (unsigned short*)p;   p += (size_t)Bb * Tt * Cc * 2;
  unsigned short* wq = (unsigned short*)p;   p += (size_t)3 * Cc * Cc * 2;
  unsigned short* wp = (unsigned short*)p;   p += (size_t)Cc * Cc * 2;
  unsigned short* qkvc = (unsigned short*)p; p += (size_t)Bb * 3 * Cc * Tt * 2;
  unsigned short* qkt = (unsigned short*)p;  p += (size_t)Bb * Hh * 2 * Tt * 64 * 2;
  unsigned short* attnoT = (unsigned short*)p;

  const int n4q = 3 * Cc * Cc / 4;  // cvt blocks: (n4q + n4p)/256 = 1024

  gn_cvt<<<dim3(2048), 256, 0, stream>>>(x, part, w_qkv, wq, n4q, w_proj, wp);
  norm_trans<<<dim3(Tt / 64, Cc / 64, Bb), 256, 0, stream>>>(x, part, gamma, beta, hT);
  gemm_mfma<0, 128><<<dim3(Tt / 128, (3 * Cc) / 128, Bb), 256, 0, stream>>>(
      wq, hT, b_qkv, nullptr, qkvc, nullptr, qkt, 3 * Cc);
  attn_mfma10<<<dim3(512), 256, 0, stream>>>(qkt, qkvc, attnoT);
  gemm_mfma<1, 64><<<dim3(Tt / 128, Cc / 64, Bb), 256, 0, stream>>>(
      wp, attnoT, b_proj, x, nullptr, out, nullptr, Cc);
}